// Round 5
// baseline (226.770 us; speedup 1.0000x reference)
//
#include <hip/hip_runtime.h>
#include <hip/hip_bf16.h>
#include <math.h>

#define NPIX   16384
#define BATCH  8
#define BN_EPS 1e-5f
#define EPS_V  1e-6f

typedef __attribute__((ext_vector_type(8))) short bf16x8;
typedef __attribute__((ext_vector_type(4))) float f32x4;

// ---- workspace layout (float offsets) ----
// common
#define OFF_K     ((size_t)0)          // fallback: Kbuf. mfma path: wxbr (reuse)
#define OFF_W1F   ((size_t)2097152)    // 128*32   = 4096
#define OFF_WKT   ((size_t)2101248)    // 128*16   = 2048
#define OFF_WVT   ((size_t)2103296)    // 128*128  = 16384
#define OFF_BF    ((size_t)2119680)    // 4*32     = 128
#define OFF_PART  ((size_t)2119808)    // 512*2192 = 1122304
#define OFF_STATS ((size_t)3242112)    // 8*2192   = 17536
#define BASE_END  ((size_t)3259648)
// new (bf16-MFMA) path extras
#define OFF_WBT   BASE_END             // 3*9*4*2*64*8 ushort = 55296 floats
#define OFF_XT    ((size_t)3314976)    // 8*4*16384*32 ushort = 8388608 floats
#define OFF_WVB   ((size_t)11703584)   // 4*8*64*8 ushort = 8192 floats
#define NEW_END   ((size_t)11711776)
// old (fp32) fallback extras
#define OFF_W24T  BASE_END             // 3*128*9*32 = 110592

__device__ inline unsigned short f2bf(float f) {
  union { float f; unsigned int u; } v; v.f = f;
  unsigned int r = (v.u + 0x7FFFu + ((v.u >> 16) & 1u)) >> 16;
  return (unsigned short)r;
}

// ---------------- prep_common ----------------
__global__ void prep_common_kernel(const float* __restrict__ w1,
                                   const float* __restrict__ bns, const float* __restrict__ bnb,
                                   const float* __restrict__ bnm, const float* __restrict__ bnv,
                                   const float* __restrict__ wk, const float* __restrict__ wv,
                                   float* __restrict__ w1f, float* __restrict__ wkt,
                                   float* __restrict__ wvt, float* __restrict__ bf) {
  int tid = blockIdx.x * blockDim.x + threadIdx.x;
  int nt  = gridDim.x * blockDim.x;
  for (int i = tid; i < 128; i += nt) {
    float inv = bns[i] * rsqrtf(bnv[i] + BN_EPS);
    bf[i] = bnb[i] - bnm[i] * inv;
  }
  for (int i = tid; i < 4096; i += nt) {          // w1f[c][o]
    int c = i >> 5, o = i & 31;
    float inv = bns[o] * rsqrtf(bnv[o] + BN_EPS);
    w1f[i] = w1[o * 128 + c] * inv;
  }
  for (int i = tid; i < 2048; i += nt) {          // wkt[c][m]
    int c = i >> 4, m = i & 15;
    wkt[i] = wk[m * 128 + c];
  }
  for (int i = tid; i < 16384; i += nt) {         // wvt[c][o]
    int c = i >> 7, o = i & 127;
    wvt[i] = wv[o * 128 + c];
  }
}

// ---------------- prep_convb: MFMA-fragment-ordered bf16 weights ----------------
// wbtr[br][tap][q][pair][lane(64)][e(8)] : W[oc=pair*16+(lane&15)][c=q*32+(lane>>4)*8+e]
// wvbr[q][f(8)][lane][e]                 : WV[oc=f*16+(lane&15)][c]
// wxbr[q][tile(3)][lane][e]              : tile0/1 = w1f oc=tile*16+l15; tile2 = wk m=l15
__global__ void prep_convb_kernel(const float* __restrict__ w1,
                                  const float* __restrict__ w2, const float* __restrict__ w3,
                                  const float* __restrict__ w4,
                                  const float* __restrict__ bns, const float* __restrict__ bnv,
                                  const float* __restrict__ wk, const float* __restrict__ wv,
                                  unsigned short* __restrict__ wbtr,
                                  unsigned short* __restrict__ wvbr,
                                  unsigned short* __restrict__ wxbr) {
  int tid = blockIdx.x * blockDim.x + threadIdx.x;
  int nt  = gridDim.x * blockDim.x;
  for (int i = tid; i < 16384; i += nt) {
    int e = i & 7, lane = (i >> 3) & 63, f = (i >> 9) & 7, q = i >> 12;
    int oc = f * 16 + (lane & 15);
    int c  = q * 32 + (lane >> 4) * 8 + e;
    wvbr[i] = f2bf(wv[oc * 128 + c]);
  }
  for (int i = tid; i < 6144; i += nt) {
    int e = i & 7, lane = (i >> 3) & 63, ct = i >> 9;
    int tile = ct % 3, q = ct / 3;
    int c = q * 32 + (lane >> 4) * 8 + e;
    float val;
    if (tile < 2) {
      int oc = tile * 16 + (lane & 15);
      val = w1[oc * 128 + c] * (bns[oc] * rsqrtf(bnv[oc] + BN_EPS));
    } else {
      val = wk[(lane & 15) * 128 + c];
    }
    wxbr[i] = f2bf(val);
  }
  for (int i = tid; i < 110592; i += nt) {
    int br = i / 36864;
    int r  = i - br * 36864;
    int tap  = r >> 12;
    int r2   = r & 4095;
    int q    = r2 >> 10;
    int r3   = r2 & 1023;
    int pair = r3 >> 9;
    int r4   = r3 & 511;
    int lane = r4 >> 3, e = r4 & 7;
    int oc = pair * 16 + (lane & 15);
    int c  = q * 32 + (lane >> 4) * 8 + e;
    const float* w = (br == 0) ? w2 : ((br == 1) ? w3 : w4);
    int bo = (br + 1) * 32 + oc;
    float inv = bns[bo] * rsqrtf(bnv[bo] + BN_EPS);
    wbtr[i] = f2bf(w[(oc * 128 + c) * 9 + tap] * inv);
  }
}

// ---------------- prep_convf (fallback) ----------------
__global__ void prep_convf_kernel(const float* __restrict__ w2, const float* __restrict__ w3,
                                  const float* __restrict__ w4,
                                  const float* __restrict__ bns, const float* __restrict__ bnv,
                                  float* __restrict__ w24t) {
  int tid = blockIdx.x * blockDim.x + threadIdx.x;
  int nt  = gridDim.x * blockDim.x;
  for (int i = tid; i < 110592; i += nt) {
    int br  = i / 36864;
    int rem = i - br * 36864;
    int c   = rem / 288;
    int k   = (rem % 288) >> 5;
    int o   = rem & 31;
    const float* w = (br == 0) ? w2 : ((br == 1) ? w3 : w4);
    int bo = (br + 1) * 32 + o;
    float inv = bns[bo] * rsqrtf(bnv[bo] + BN_EPS);
    w24t[i] = w[(o * 128 + c) * 9 + k] * inv;
  }
}

// ---------------- a0: transpose x -> xt bf16, quarter-major [b][q][px][32c] ----------------
__global__ __launch_bounds__(256) void a0_kernel(const float* __restrict__ x,
                                                 unsigned short* __restrict__ xt) {
  __shared__ unsigned short Ts[64][132];
  int t   = threadIdx.x;
  int b   = blockIdx.y;
  int px0 = blockIdx.x * 64;
  const float* xb = x + (size_t)b * 128 * NPIX;
  int p = t & 63, cq = t >> 6;
#pragma unroll 8
  for (int i = 0; i < 32; ++i) {
    int c = cq * 32 + i;
    Ts[p][c] = f2bf(xb[(size_t)c * NPIX + px0 + p]);
  }
  __syncthreads();
  int pw = t >> 2, cg = t & 3;   // cg == quarter
  unsigned short* dst = xt + ((size_t)(b * 4 + cg) * 16384 + px0 + pw) * 32;
#pragma unroll
  for (int k = 0; k < 8; ++k) {
    uint2 v = *(const uint2*)(&Ts[pw][cg * 32 + k * 4]);
    *(uint2*)(dst + k * 4) = v;
  }
}

// ---------------- a1 (fallback only) ----------------
__global__ __launch_bounds__(256) void a1_kernel(const float* __restrict__ x,
                                                 const float* __restrict__ w1f,
                                                 const float* __restrict__ wkt,
                                                 const float* __restrict__ bfp,
                                                 const float* __restrict__ bk,
                                                 float* __restrict__ out,
                                                 float* __restrict__ Kbuf) {
  __shared__ float lw1[128 * 32];
  __shared__ float lwk[128 * 16];
  __shared__ float lbf[32];
  int t = threadIdx.x;
  for (int i = t; i < 4096; i += 256) lw1[i] = w1f[i];
  for (int i = t; i < 2048; i += 256) lwk[i] = wkt[i];
  if (t < 32) lbf[t] = bfp[t];
  __syncthreads();

  int b  = blockIdx.y;
  int px = blockIdx.x * 256 + t;
  const float* xb = x + (size_t)b * 128 * NPIX;

  float acc[48];
#pragma unroll
  for (int i = 0; i < 48; ++i) acc[i] = 0.f;

  for (int c = 0; c < 128; ++c) {
    float xv = xb[(size_t)c * NPIX + px];
    const float4* w1p = (const float4*)(lw1 + c * 32);
#pragma unroll
    for (int j = 0; j < 8; ++j) {
      float4 w = w1p[j];
      acc[j*4+0] = fmaf(w.x, xv, acc[j*4+0]);
      acc[j*4+1] = fmaf(w.y, xv, acc[j*4+1]);
      acc[j*4+2] = fmaf(w.z, xv, acc[j*4+2]);
      acc[j*4+3] = fmaf(w.w, xv, acc[j*4+3]);
    }
    const float4* wkp = (const float4*)(lwk + c * 16);
#pragma unroll
    for (int j = 0; j < 4; ++j) {
      float4 w = wkp[j];
      acc[32+j*4+0] = fmaf(w.x, xv, acc[32+j*4+0]);
      acc[32+j*4+1] = fmaf(w.y, xv, acc[32+j*4+1]);
      acc[32+j*4+2] = fmaf(w.z, xv, acc[32+j*4+2]);
      acc[32+j*4+3] = fmaf(w.w, xv, acc[32+j*4+3]);
    }
  }
#pragma unroll
  for (int o = 0; o < 32; ++o)
    out[((size_t)(b * 128 + o)) * NPIX + px] = fmaxf(acc[o] + lbf[o], 0.f);
#pragma unroll
  for (int m = 0; m < 16; ++m)
    Kbuf[((size_t)(b * 16 + m)) * NPIX + px] = acc[32 + m] + bk[m];
}

// ---------------- a2m v4: LDS-staged conv + async stage (T14) ----------------
__global__ __launch_bounds__(256) void a2m_kernel(const unsigned short* __restrict__ xt,
                                                  const unsigned short* __restrict__ wbtr,
                                                  const float* __restrict__ bfp,
                                                  float* __restrict__ out) {
  __shared__ uint4 sxv[3073];                 // 48KB staged + 16B zero page
  unsigned short* sx = (unsigned short*)sxv;
  int t    = threadIdx.x;
  int wave = t >> 6, lane = t & 63;
  int l15  = lane & 15, cg = lane >> 4;
  int idx  = blockIdx.x;
  int b    = idx & 7;                         // batch -> XCD
  int rest = idx >> 3;
  int h2   = rest & 63;
  int br   = rest >> 6;
  int d    = 6 * (br + 1);
  int h0   = h2 * 2;
  int j    = wave >> 1;                       // row of the pair
  int p0   = (wave & 1) * 64;                 // px half

  if (t == 0) sxv[3072] = make_uint4(0u, 0u, 0u, 0u);

  const unsigned short* wb = wbtr + (size_t)br * 36864;

  f32x4 acc[2][4];
#pragma unroll
  for (int i = 0; i < 2; ++i)
#pragma unroll
    for (int n = 0; n < 4; ++n) acc[i][n] = (f32x4){0.f, 0.f, 0.f, 0.f};

  int pxb[3], xorv[3];
#pragma unroll
  for (int kw = 0; kw < 3; ++kw) {
    pxb[kw]  = p0 + l15 + (kw - 1) * d;
    xorv[kw] = (cg ^ ((pxb[kw] >> 1) & 3)) << 4;
  }

  // per-slot source rows (q-independent)
  int srow[6];
  bool sval[6];
#pragma unroll
  for (int slot = 0; slot < 6; ++slot) {
    srow[slot] = h0 + (slot & 1) + ((slot >> 1) - 1) * d;
    sval[slot] = ((unsigned)srow[slot] < 128u);
  }

  uint4 stv[12];
  // preload q=0
  {
    const unsigned short* slab = xt + (size_t)(b * 4 + 0) * 524288;
#pragma unroll
    for (int k = 0; k < 12; ++k) {
      int slot = k >> 1;
      int su   = ((k & 1) << 8) + t;
      stv[k] = sval[slot] ? *(const uint4*)(slab + (size_t)srow[slot] * 4096 + su * 8)
                          : make_uint4(0u, 0u, 0u, 0u);
    }
  }

  for (int q = 0; q < 4; ++q) {
    __syncthreads();                            // prior compute done reading LDS
#pragma unroll
    for (int k = 0; k < 12; ++k) {
      int slot = k >> 1;
      int su   = ((k & 1) << 8) + t;
      int px   = su >> 2, cgs = su & 3;
      int phys = slot * 4096 + px * 32 + ((cgs ^ ((px >> 1) & 3)) << 3);
      *(uint4*)(sx + phys) = stv[k];
    }
    __syncthreads();                            // staged visible
    if (q < 3) {                                // T14: issue next-q loads early
      const unsigned short* slab = xt + (size_t)(b * 4 + q + 1) * 524288;
#pragma unroll
      for (int k = 0; k < 12; ++k) {
        int slot = k >> 1;
        int su   = ((k & 1) << 8) + t;
        stv[k] = sval[slot] ? *(const uint4*)(slab + (size_t)srow[slot] * 4096 + su * 8)
                            : make_uint4(0u, 0u, 0u, 0u);
      }
    }
    // ---- compute q: 9 taps x 32c ----
#pragma unroll
    for (int kh = 0; kh < 3; ++kh) {
      int slot  = kh * 2 + j;
      int sbase = slot * 8192;                  // byte
      bf16x8 a[3][2];
#pragma unroll
      for (int kw = 0; kw < 3; ++kw) {
        int tap = kh * 3 + kw;
        const unsigned short* wt = wb + ((((size_t)tap * 4 + q) * 2) << 9);
        a[kw][0] = *(const bf16x8*)(wt + lane * 8);
        a[kw][1] = *(const bf16x8*)(wt + 512 + lane * 8);
      }
#pragma unroll
      for (int kw = 0; kw < 3; ++kw) {
        int base = sbase + pxb[kw] * 64 + xorv[kw];
#pragma unroll
        for (int nf = 0; nf < 4; ++nf) {
          int px   = pxb[kw] + nf * 16;
          int addr = ((unsigned)px < 128u) ? (base + nf * 1024) : 49152;
          bf16x8 bv = *(const bf16x8*)((const char*)sx + addr);
          acc[0][nf] = __builtin_amdgcn_mfma_f32_16x16x32_bf16(a[kw][0], bv, acc[0][nf], 0, 0, 0);
          acc[1][nf] = __builtin_amdgcn_mfma_f32_16x16x32_bf16(a[kw][1], bv, acc[1][nf], 0, 0, 0);
        }
      }
    }
  }

  int ocb = (br + 1) * 32;
  int pxw = (h0 + j) * 128 + p0;
#pragma unroll
  for (int mf = 0; mf < 2; ++mf) {
#pragma unroll
    for (int r = 0; r < 4; ++r) {
      int oc = mf * 16 + cg * 4 + r;
      float bias = bfp[ocb + oc];
      float* op = out + ((size_t)(b * 128 + ocb + oc)) * NPIX + pxw + l15;
#pragma unroll
      for (int nf = 0; nf < 4; ++nf)
        op[nf * 16] = fmaxf(acc[mf][nf][r] + bias, 0.f);
    }
  }
}

// ---------------- a2f (fallback) ----------------
__global__ __launch_bounds__(256) void a2f_kernel(const float* __restrict__ x,
                                                  const float* __restrict__ w24t,
                                                  const float* __restrict__ bfp,
                                                  float* __restrict__ out) {
  int t  = threadIdx.x;
  int og = t & 3;
  int pg = (t >> 2) & 15;
  int r  = t >> 6;
  int br = blockIdx.z;
  int b  = blockIdx.y;
  int h  = blockIdx.x * 4 + r;
  int d  = 6 * (br + 1);

  const float* wt = w24t + (size_t)br * 36864;
  const float* bf = bfp + (br + 1) * 32;
  const float* xb = x + (size_t)b * 128 * NPIX;
  int w0 = pg << 3;

  float acc[8][8];
#pragma unroll
  for (int p = 0; p < 8; ++p)
#pragma unroll
    for (int o = 0; o < 8; ++o) acc[p][o] = 0.f;

  for (int c = 0; c < 128; ++c) {
    const float* xc = xb + (size_t)c * NPIX;
    const float* wc = wt + c * 288;
#pragma unroll
    for (int kh = 0; kh < 3; ++kh) {
      int row = h + (kh - 1) * d;
      if ((unsigned)row >= 128u) continue;
      const float* xr = xc + row * 128;
#pragma unroll
      for (int kw = 0; kw < 3; ++kw) {
        int wb = w0 + (kw - 1) * d;
        float xv[8];
        if (wb >= 0 && wb <= 120) {
          const float2* p2 = (const float2*)(xr + wb);
#pragma unroll
          for (int jj = 0; jj < 4; ++jj) {
            float2 v = p2[jj];
            xv[2*jj] = v.x; xv[2*jj+1] = v.y;
          }
        } else {
#pragma unroll
          for (int jj = 0; jj < 8; ++jj) {
            int ww = wb + jj;
            xv[jj] = ((unsigned)ww < 128u) ? xr[ww] : 0.f;
          }
        }
        const float4* wp = (const float4*)(wc + (kh * 3 + kw) * 32 + og * 8);
        float4 wa = wp[0], wbv = wp[1];
        float wr[8] = {wa.x, wa.y, wa.z, wa.w, wbv.x, wbv.y, wbv.z, wbv.w};
#pragma unroll
        for (int p = 0; p < 8; ++p)
#pragma unroll
          for (int o = 0; o < 8; ++o)
            acc[p][o] = fmaf(xv[p], wr[o], acc[p][o]);
      }
    }
  }

  int chbase = (br + 1) * 32 + og * 8;
  int n = h * 128 + w0;
#pragma unroll
  for (int o = 0; o < 8; ++o) {
    float bias = bf[og * 8 + o];
    float* op = out + ((size_t)(b * 128 + chbase + o)) * NPIX + n;
    float4 v0 = make_float4(fmaxf(acc[0][o] + bias, 0.f), fmaxf(acc[1][o] + bias, 0.f),
                            fmaxf(acc[2][o] + bias, 0.f), fmaxf(acc[3][o] + bias, 0.f));
    float4 v1 = make_float4(fmaxf(acc[4][o] + bias, 0.f), fmaxf(acc[5][o] + bias, 0.f),
                            fmaxf(acc[6][o] + bias, 0.f), fmaxf(acc[7][o] + bias, 0.f));
    ((float4*)op)[0] = v0;
    ((float4*)op)[1] = v1;
  }
}

// ---------------- cm v4: fused branch1 + K + V (MFMA) + attention stats ----------------
__global__ __launch_bounds__(256) void cm_kernel(const unsigned short* __restrict__ xt,
                                                 const unsigned short* __restrict__ wvbr,
                                                 const unsigned short* __restrict__ wxbr,
                                                 const float* __restrict__ bv,
                                                 const float* __restrict__ bfp,
                                                 const float* __restrict__ bk,
                                                 float* __restrict__ out,
                                                 float* __restrict__ part) {
  __shared__ __align__(16) unsigned short Vl[128 * 136];   // bf16 [oc][px]
  __shared__ __align__(16) unsigned short knl[16 * 136];   // bf16 [m][px]
  int t    = threadIdx.x;
  int b    = blockIdx.y;
  int blk  = blockIdx.x;
  int wave = t >> 6, lane = t & 63;
  int l15  = lane & 15, cg = lane >> 4;
  int ocb  = wave * 32;

  float bvr[2][4];
#pragma unroll
  for (int mf = 0; mf < 2; ++mf)
#pragma unroll
    for (int r = 0; r < 4; ++r) bvr[mf][r] = bv[ocb + mf * 16 + cg * 4 + r];

  // extra-tile bias: wave0/1 -> branch1 (bfp[0..32)), wave2 -> bk
  float xb4[4];
#pragma unroll
  for (int r = 0; r < 4; ++r) xb4[r] = 0.f;
  if (wave == 0) {
#pragma unroll
    for (int r = 0; r < 4; ++r) xb4[r] = bfp[cg * 4 + r];
  } else if (wave == 1) {
#pragma unroll
    for (int r = 0; r < 4; ++r) xb4[r] = bfp[16 + cg * 4 + r];
  } else if (wave == 2) {
#pragma unroll
    for (int r = 0; r < 4; ++r) xb4[r] = bk[cg * 4 + r];
  }

  float kr[4] = {0.f, 0.f, 0.f, 0.f};
  float sv[2][4];
#pragma unroll
  for (int mf = 0; mf < 2; ++mf)
#pragma unroll
    for (int r = 0; r < 4; ++r) sv[mf][r] = 0.f;
  f32x4 am[2];
  am[0] = (f32x4){0.f,0.f,0.f,0.f};
  am[1] = (f32x4){0.f,0.f,0.f,0.f};

  for (int tile = blk; tile < 128; tile += 64) {
    __syncthreads();   // prior phase-3 reads done
    int pbase = tile << 7;

    // phase 2: [V(128) | b1(32) | K(16)] = W @ xt^T via MFMA
    f32x4 vacc[2][8];
    f32x4 xacc[8];
#pragma unroll
    for (int i = 0; i < 2; ++i)
#pragma unroll
      for (int n = 0; n < 8; ++n) vacc[i][n] = (f32x4){0.f,0.f,0.f,0.f};
#pragma unroll
    for (int n = 0; n < 8; ++n) xacc[n] = (f32x4){0.f,0.f,0.f,0.f};

#pragma unroll
    for (int cc = 0; cc < 4; ++cc) {
      const unsigned short* xq = xt + ((size_t)(b * 4 + cc) * 16384 + pbase) * 32;
      bf16x8 a0 = *(const bf16x8*)(wvbr + ((cc * 8 + wave * 2 + 0) << 9) + lane * 8);
      bf16x8 a1 = *(const bf16x8*)(wvbr + ((cc * 8 + wave * 2 + 1) << 9) + lane * 8);
      bf16x8 ax = *(const bf16x8*)(wxbr + (((cc * 3 + (wave & 3)) % 12) << 9) + lane * 8);
      if (wave < 3) ax = *(const bf16x8*)(wxbr + ((cc * 3 + wave) << 9) + lane * 8);
#pragma unroll
      for (int nf = 0; nf < 8; ++nf) {
        bf16x8 bx = *(const bf16x8*)(xq + (size_t)(nf * 16 + l15) * 32 + cg * 8);
        vacc[0][nf] = __builtin_amdgcn_mfma_f32_16x16x32_bf16(a0, bx, vacc[0][nf], 0, 0, 0);
        vacc[1][nf] = __builtin_amdgcn_mfma_f32_16x16x32_bf16(a1, bx, vacc[1][nf], 0, 0, 0);
        if (wave < 3)
          xacc[nf] = __builtin_amdgcn_mfma_f32_16x16x32_bf16(ax, bx, xacc[nf], 0, 0, 0);
      }
    }

    // V: vsum partial (fp32) + Vl bf16 (bias included)
#pragma unroll
    for (int mf = 0; mf < 2; ++mf) {
#pragma unroll
      for (int r = 0; r < 4; ++r) {
        float s = 0.f;
#pragma unroll
        for (int nf = 0; nf < 8; ++nf) s += vacc[mf][nf][r];
        sv[mf][r] += s;
        int c = ocb + mf * 16 + cg * 4 + r;
#pragma unroll
        for (int nf = 0; nf < 8; ++nf)
          Vl[c * 136 + nf * 16 + l15] = f2bf(vacc[mf][nf][r] + bvr[mf][r]);
      }
    }

    // branch1 out (waves 0,1): bias+relu, fp32, channels 0..31
    if (wave < 2) {
#pragma unroll
      for (int r = 0; r < 4; ++r) {
        int oc = wave * 16 + cg * 4 + r;
        float* op = out + ((size_t)(b * 128 + oc)) * NPIX + pbase + l15;
#pragma unroll
        for (int nf = 0; nf < 8; ++nf)
          op[nf * 16] = fmaxf(xacc[nf][r] + xb4[r], 0.f);
      }
    } else if (wave == 2) {
      // K -> Kn -> knl (bf16) + ksum
#pragma unroll
      for (int nf = 0; nf < 8; ++nf) {
        float kq[4]; float s2 = 0.f;
#pragma unroll
        for (int r = 0; r < 4; ++r) {
          kq[r] = xacc[nf][r] + xb4[r];
          s2 = fmaf(kq[r], kq[r], s2);
        }
        s2 += __shfl_xor(s2, 16);
        s2 += __shfl_xor(s2, 32);
        float inv = rsqrtf(s2);
#pragma unroll
        for (int r = 0; r < 4; ++r) {
          float kn = kq[r] * inv;
          knl[(cg * 4 + r) * 136 + nf * 16 + l15] = f2bf(kn);
          kr[r] += kn;
        }
      }
    }
    __syncthreads();

    // phase 3: mat[m][c] += Kn · V^T via MFMA
#pragma unroll
    for (int ks = 0; ks < 4; ++ks) {
      bf16x8 af = *(const bf16x8*)(knl + l15 * 136 + ks * 32 + cg * 8);
      bf16x8 b0 = *(const bf16x8*)(Vl + (size_t)(ocb + l15) * 136 + ks * 32 + cg * 8);
      bf16x8 b1 = *(const bf16x8*)(Vl + (size_t)(ocb + 16 + l15) * 136 + ks * 32 + cg * 8);
      am[0] = __builtin_amdgcn_mfma_f32_16x16x32_bf16(af, b0, am[0], 0, 0, 0);
      am[1] = __builtin_amdgcn_mfma_f32_16x16x32_bf16(af, b1, am[1], 0, 0, 0);
    }
  }

  // ---- write partials ----
  int blkid = b * 64 + blk;
  float* pp = part + (size_t)blkid * 2192;
#pragma unroll
  for (int nf2 = 0; nf2 < 2; ++nf2)
#pragma unroll
    for (int r = 0; r < 4; ++r)
      pp[(cg * 4 + r) * 128 + ocb + nf2 * 16 + l15] = am[nf2][r];
  // vsum: reduce over l15
#pragma unroll
  for (int off = 1; off < 16; off <<= 1) {
#pragma unroll
    for (int mf = 0; mf < 2; ++mf)
#pragma unroll
      for (int r = 0; r < 4; ++r)
        sv[mf][r] += __shfl_xor(sv[mf][r], off);
  }
  if (l15 == 0) {
#pragma unroll
    for (int mf = 0; mf < 2; ++mf)
#pragma unroll
      for (int r = 0; r < 4; ++r) {
        int c = ocb + mf * 16 + cg * 4 + r;
        pp[2048 + c] = sv[mf][r] + 256.f * bv[c];
      }
  }
  // ksum (wave 2)
  if (wave == 2) {
#pragma unroll
    for (int off = 1; off < 16; off <<= 1) {
#pragma unroll
      for (int r = 0; r < 4; ++r)
        kr[r] += __shfl_xor(kr[r], off);
    }
    if (l15 == 0) {
#pragma unroll
      for (int r = 0; r < 4; ++r)
        pp[2048 + 128 + cg * 4 + r] = kr[r];
    }
  }
}

// ---------------- cf (fallback) ----------------
__global__ __launch_bounds__(256) void cf_kernel(const float* __restrict__ x,
                                                 const float* __restrict__ bv,
                                                 const float* __restrict__ Kbuf,
                                                 const float* __restrict__ wvt,
                                                 float* __restrict__ part) {
  __shared__ float Vl[128 * 129];
  __shared__ float knl[16 * 132];
  int t   = threadIdx.x;
  int b   = blockIdx.y;
  int blk = blockIdx.x;
  const float* Kb = Kbuf + (size_t)b * 16 * NPIX;
  const float* xb = x + (size_t)b * 128 * NPIX;

  int m_own = t & 15;
  int c0    = (t >> 4) << 3;
  int pxg   = t & 15;

  float bvr[8];
#pragma unroll
  for (int jj = 0; jj < 8; ++jj) bvr[jj] = bv[c0 + jj];

  float macc[8] = {0,0,0,0,0,0,0,0};
  float vs[8]   = {0,0,0,0,0,0,0,0};
  float ksum[16];
#pragma unroll
  for (int m = 0; m < 16; ++m) ksum[m] = 0.f;

  for (int tile = blk; tile < 128; tile += 64) {
    __syncthreads();
    int pbase = tile << 7;

    if (t < 128) {
      float kv[16]; float ss = 0.f;
#pragma unroll
      for (int m = 0; m < 16; ++m) {
        kv[m] = Kb[(size_t)m * NPIX + pbase + t];
        ss = fmaf(kv[m], kv[m], ss);
      }
      float inv = rsqrtf(ss);
#pragma unroll
      for (int m = 0; m < 16; ++m) {
        float kn = kv[m] * inv;
        knl[m * 132 + t] = kn;
        ksum[m] += kn;
      }
    }

    float v[8][8];
#pragma unroll
    for (int i = 0; i < 8; ++i)
#pragma unroll
      for (int jj = 0; jj < 8; ++jj) v[i][jj] = 0.f;
    int px0 = pbase + (pxg << 3);
    for (int k = 0; k < 128; ++k) {
      const float4* xp = (const float4*)(xb + (size_t)k * NPIX + px0);
      float4 xa = xp[0], xc4 = xp[1];
      const float4* wp = (const float4*)(wvt + k * 128 + c0);
      float4 wa = wp[0], wc4 = wp[1];
      float xv[8] = {xa.x, xa.y, xa.z, xa.w, xc4.x, xc4.y, xc4.z, xc4.w};
      float wr[8] = {wa.x, wa.y, wa.z, wa.w, wc4.x, wc4.y, wc4.z, wc4.w};
#pragma unroll
      for (int i = 0; i < 8; ++i)
#pragma unroll
        for (int jj = 0; jj < 8; ++jj)
          v[i][jj] = fmaf(wr[i], xv[jj], v[i][jj]);
    }
#pragma unroll
    for (int i = 0; i < 8; ++i)
#pragma unroll
      for (int jj = 0; jj < 8; ++jj)
        Vl[(c0 + i) * 129 + (pxg << 3) + jj] = v[i][jj] + bvr[i];
    __syncthreads();

    for (int px = 0; px < 128; ++px) {
      float knv = knl[m_own * 132 + px];
      float vv[8];
#pragma unroll
      for (int jj = 0; jj < 8; ++jj) vv[jj] = Vl[(c0 + jj) * 129 + px];
#pragma unroll
      for (int jj = 0; jj < 8; ++jj) macc[jj] = fmaf(knv, vv[jj], macc[jj]);
      if (m_own == 0) {
#pragma unroll
        for (int jj = 0; jj < 8; ++jj) vs[jj] += vv[jj];
      }
    }
  }

  int blkid = b * 64 + blk;
  float* pp = part + (size_t)blkid * 2192;
#pragma unroll
  for (int jj = 0; jj < 8; ++jj) pp[m_own * 128 + c0 + jj] = macc[jj];
  if (m_own == 0) {
#pragma unroll
    for (int jj = 0; jj < 8; ++jj) pp[2048 + c0 + jj] = vs[jj];
  }
  __syncthreads();
  if (t < 128) {
#pragma unroll
    for (int m = 0; m < 16; ++m) knl[m * 132 + t] = ksum[m];
  }
  __syncthreads();
  if (t < 16) {
    float s = 0.f;
    for (int i = 0; i < 128; ++i) s += knl[t * 132 + i];
    pp[2048 + 128 + t] = s;
  }
}

// ---------------- reduce ----------------
__global__ void reduce_kernel(const float* __restrict__ part, float* __restrict__ stats) {
  int b = blockIdx.x, t = threadIdx.x;
  const float* pp = part + (size_t)b * 64 * 2192;
  float* st = stats + (size_t)b * 2192;
  for (int e = t; e < 2192; e += 256) {
    float s = 0.f;
    for (int g = 0; g < 64; ++g) s += pp[(size_t)g * 2192 + e];
    st[e] = s;
  }
}

// ---------------- d: Q, tailor, final output ----------------
__global__ __launch_bounds__(256) void d_kernel(const float* __restrict__ stats,
                                                const float* __restrict__ wq,
                                                const float* __restrict__ bq,
                                                const float* __restrict__ gamma,
                                                float* __restrict__ out) {
  __shared__ float matl[128 * 16];
  __shared__ float wql[128 * 16];
  __shared__ float vsl[128];
  __shared__ float ksl[16];
  int t = threadIdx.x;
  int b = blockIdx.y;
  const float* st = stats + (size_t)b * 2192;
  for (int i = t; i < 2048; i += 256) {
    int m = i >> 7, c = i & 127;
    matl[c * 16 + m] = st[i];
    wql[c * 16 + m]  = wq[m * 128 + c];
  }
  if (t < 128) vsl[t] = st[2048 + t];
  if (t < 16)  ksl[t] = st[2048 + 128 + t] + EPS_V;
  __syncthreads();

  int px = blockIdx.x * 256 + t;
  float* ob = out + (size_t)b * 128 * NPIX;

  float q[16];
#pragma unroll
  for (int m = 0; m < 16; ++m) q[m] = bq[m];
  for (int c = 0; c < 128; ++c) {
    float xv = ob[(size_t)c * NPIX + px];
    const float4* wp = (const float4*)(wql + c * 16);
#pragma unroll
    for (int jj = 0; jj < 4; ++jj) {
      float4 w = wp[jj];
      q[jj*4+0] = fmaf(w.x, xv, q[jj*4+0]);
      q[jj*4+1] = fmaf(w.y, xv, q[jj*4+1]);
      q[jj*4+2] = fmaf(w.z, xv, q[jj*4+2]);
      q[jj*4+3] = fmaf(w.w, xv, q[jj*4+3]);
    }
  }
  float ss = 0.f;
#pragma unroll
  for (int m = 0; m < 16; ++m) ss = fmaf(q[m], q[m], ss);
  float inv = rsqrtf(ss);
#pragma unroll
  for (int m = 0; m < 16; ++m) q[m] *= inv;
  float den = (float)NPIX;
#pragma unroll
  for (int m = 0; m < 16; ++m) den = fmaf(q[m], ksl[m], den);
  float tl = gamma[0] / den;

  for (int c = 0; c < 128; ++c) {
    float s = vsl[c];
    const float4* mp = (const float4*)(matl + c * 16);
#pragma unroll
    for (int jj = 0; jj < 4; ++jj) {
      float4 w = mp[jj];
      s = fmaf(w.x, q[jj*4+0], s);
      s = fmaf(w.y, q[jj*4+1], s);
      s = fmaf(w.z, q[jj*4+2], s);
      s = fmaf(w.w, q[jj*4+3], s);
    }
    ob[(size_t)c * NPIX + px] = tl * s;
  }
}

extern "C" void kernel_launch(void* const* d_in, const int* in_sizes, int n_in,
                              void* d_out, int out_size, void* d_ws, size_t ws_size,
                              hipStream_t stream) {
  (void)in_sizes; (void)n_in; (void)out_size;
  const float* x   = (const float*)d_in[0];
  const float* w1  = (const float*)d_in[1];
  const float* w2  = (const float*)d_in[2];
  const float* w3  = (const float*)d_in[3];
  const float* w4  = (const float*)d_in[4];
  const float* bns = (const float*)d_in[5];
  const float* bnb = (const float*)d_in[6];
  const float* bnm = (const float*)d_in[7];
  const float* bnv = (const float*)d_in[8];
  const float* wq  = (const float*)d_in[9];
  const float* bq  = (const float*)d_in[10];
  const float* wk  = (const float*)d_in[11];
  const float* bk  = (const float*)d_in[12];
  const float* wv  = (const float*)d_in[13];
  const float* bv  = (const float*)d_in[14];
  const float* gm  = (const float*)d_in[15];
  float* ws  = (float*)d_ws;
  float* out = (float*)d_out;

  float* Kbuf = ws + OFF_K;
  float* w1f  = ws + OFF_W1F;
  float* wkt  = ws + OFF_WKT;
  float* wvt  = ws + OFF_WVT;
  float* bfp  = ws + OFF_BF;
  float* part = ws + OFF_PART;
  float* stat = ws + OFF_STATS;

  prep_common_kernel<<<64, 256, 0, stream>>>(w1, bns, bnb, bnm, bnv, wk, wv,
                                             w1f, wkt, wvt, bfp);

  bool use_mfma = ws_size >= NEW_END * sizeof(float);
  if (use_mfma) {
    unsigned short* wbtr = (unsigned short*)(ws + OFF_WBT);
    unsigned short* xt   = (unsigned short*)(ws + OFF_XT);
    unsigned short* wvbr = (unsigned short*)(ws + OFF_WVB);
    unsigned short* wxbr = (unsigned short*)(ws + OFF_K);   // reuse freed Kbuf region
    prep_convb_kernel<<<64, 256, 0, stream>>>(w1, w2, w3, w4, bns, bnv, wk, wv,
                                              wbtr, wvbr, wxbr);
    a0_kernel<<<dim3(256, 8), 256, 0, stream>>>(x, xt);
    a2m_kernel<<<dim3(1536), 256, 0, stream>>>(xt, wbtr, bfp, out);
    cm_kernel<<<dim3(64, 8), 256, 0, stream>>>(xt, wvbr, wxbr, bv, bfp, bk, out, part);
  } else {
    float* w24t = ws + OFF_W24T;
    prep_convf_kernel<<<64, 256, 0, stream>>>(w2, w3, w4, bns, bnv, w24t);
    a1_kernel<<<dim3(64, 8), 256, 0, stream>>>(x, w1f, wkt, bfp, bk, out, Kbuf);
    a2f_kernel<<<dim3(32, 8, 3), 256, 0, stream>>>(x, w24t, bfp, out);
    cf_kernel<<<dim3(64, 8), 256, 0, stream>>>(x, bv, Kbuf, wvt, part);
  }
  reduce_kernel<<<8, 256, 0, stream>>>(part, stat);
  d_kernel<<<dim3(64, 8), 256, 0, stream>>>(stat, wq, bq, gm, out);
}

// Round 6
// 197.166 us; speedup vs baseline: 1.1501x; 1.1501x over previous
//
#include <hip/hip_runtime.h>
#include <hip/hip_bf16.h>
#include <math.h>

#define NPIX   16384
#define BATCH  8
#define BN_EPS 1e-5f
#define EPS_V  1e-6f

typedef __attribute__((ext_vector_type(8))) short bf16x8;
typedef __attribute__((ext_vector_type(4))) float f32x4;

// ---- workspace layout (float offsets) ----
// common
#define OFF_K     ((size_t)0)          // fallback: Kbuf. mfma path: wxbr (reuse)
#define OFF_W1F   ((size_t)2097152)    // 128*32   = 4096
#define OFF_WKT   ((size_t)2101248)    // 128*16   = 2048
#define OFF_WVT   ((size_t)2103296)    // 128*128  = 16384
#define OFF_BF    ((size_t)2119680)    // 4*32     = 128
#define OFF_PART  ((size_t)2119808)    // 512*2192 = 1122304
#define OFF_STATS ((size_t)3242112)    // 8*2192   = 17536
#define BASE_END  ((size_t)3259648)
// new (bf16-MFMA) path extras
#define OFF_WBT   BASE_END             // 3*9*4*2*64*8 ushort = 55296 floats
#define OFF_XT    ((size_t)3314976)    // 8*4*16384*32 ushort = 8388608 floats
#define OFF_WVB   ((size_t)11703584)   // 4*8*64*8 ushort = 8192 floats
#define NEW_END   ((size_t)11711776)
// old (fp32) fallback extras
#define OFF_W24T  BASE_END             // 3*128*9*32 = 110592

__device__ inline unsigned short f2bf(float f) {
  union { float f; unsigned int u; } v; v.f = f;
  unsigned int r = (v.u + 0x7FFFu + ((v.u >> 16) & 1u)) >> 16;
  return (unsigned short)r;
}

// ---------------- prep_common ----------------
__global__ void prep_common_kernel(const float* __restrict__ w1,
                                   const float* __restrict__ bns, const float* __restrict__ bnb,
                                   const float* __restrict__ bnm, const float* __restrict__ bnv,
                                   const float* __restrict__ wk, const float* __restrict__ wv,
                                   float* __restrict__ w1f, float* __restrict__ wkt,
                                   float* __restrict__ wvt, float* __restrict__ bf) {
  int tid = blockIdx.x * blockDim.x + threadIdx.x;
  int nt  = gridDim.x * blockDim.x;
  for (int i = tid; i < 128; i += nt) {
    float inv = bns[i] * rsqrtf(bnv[i] + BN_EPS);
    bf[i] = bnb[i] - bnm[i] * inv;
  }
  for (int i = tid; i < 4096; i += nt) {          // w1f[c][o]
    int c = i >> 5, o = i & 31;
    float inv = bns[o] * rsqrtf(bnv[o] + BN_EPS);
    w1f[i] = w1[o * 128 + c] * inv;
  }
  for (int i = tid; i < 2048; i += nt) {          // wkt[c][m]
    int c = i >> 4, m = i & 15;
    wkt[i] = wk[m * 128 + c];
  }
  for (int i = tid; i < 16384; i += nt) {         // wvt[c][o]
    int c = i >> 7, o = i & 127;
    wvt[i] = wv[o * 128 + c];
  }
}

// ---------------- prep_convb: MFMA-fragment-ordered bf16 weights ----------------
// wbtr[br][tap][q][pair][lane(64)][e(8)] : W[oc=pair*16+(lane&15)][c=q*32+(lane>>4)*8+e]
// wvbr[q][f(8)][lane][e]                 : WV[oc=f*16+(lane&15)][c]
// wxbr[q][tile(3)][lane][e]              : tile0/1 = w1f oc=tile*16+l15; tile2 = wk m=l15
__global__ void prep_convb_kernel(const float* __restrict__ w1,
                                  const float* __restrict__ w2, const float* __restrict__ w3,
                                  const float* __restrict__ w4,
                                  const float* __restrict__ bns, const float* __restrict__ bnv,
                                  const float* __restrict__ wk, const float* __restrict__ wv,
                                  unsigned short* __restrict__ wbtr,
                                  unsigned short* __restrict__ wvbr,
                                  unsigned short* __restrict__ wxbr) {
  int tid = blockIdx.x * blockDim.x + threadIdx.x;
  int nt  = gridDim.x * blockDim.x;
  for (int i = tid; i < 16384; i += nt) {
    int e = i & 7, lane = (i >> 3) & 63, f = (i >> 9) & 7, q = i >> 12;
    int oc = f * 16 + (lane & 15);
    int c  = q * 32 + (lane >> 4) * 8 + e;
    wvbr[i] = f2bf(wv[oc * 128 + c]);
  }
  for (int i = tid; i < 6144; i += nt) {
    int e = i & 7, lane = (i >> 3) & 63, ct = i >> 9;
    int tile = ct % 3, q = ct / 3;
    int c = q * 32 + (lane >> 4) * 8 + e;
    float val;
    if (tile < 2) {
      int oc = tile * 16 + (lane & 15);
      val = w1[oc * 128 + c] * (bns[oc] * rsqrtf(bnv[oc] + BN_EPS));
    } else {
      val = wk[(lane & 15) * 128 + c];
    }
    wxbr[i] = f2bf(val);
  }
  for (int i = tid; i < 110592; i += nt) {
    int br = i / 36864;
    int r  = i - br * 36864;
    int tap  = r >> 12;
    int r2   = r & 4095;
    int q    = r2 >> 10;
    int r3   = r2 & 1023;
    int pair = r3 >> 9;
    int r4   = r3 & 511;
    int lane = r4 >> 3, e = r4 & 7;
    int oc = pair * 16 + (lane & 15);
    int c  = q * 32 + (lane >> 4) * 8 + e;
    const float* w = (br == 0) ? w2 : ((br == 1) ? w3 : w4);
    int bo = (br + 1) * 32 + oc;
    float inv = bns[bo] * rsqrtf(bnv[bo] + BN_EPS);
    wbtr[i] = f2bf(w[(oc * 128 + c) * 9 + tap] * inv);
  }
}

// ---------------- prep_convf (fallback) ----------------
__global__ void prep_convf_kernel(const float* __restrict__ w2, const float* __restrict__ w3,
                                  const float* __restrict__ w4,
                                  const float* __restrict__ bns, const float* __restrict__ bnv,
                                  float* __restrict__ w24t) {
  int tid = blockIdx.x * blockDim.x + threadIdx.x;
  int nt  = gridDim.x * blockDim.x;
  for (int i = tid; i < 110592; i += nt) {
    int br  = i / 36864;
    int rem = i - br * 36864;
    int c   = rem / 288;
    int k   = (rem % 288) >> 5;
    int o   = rem & 31;
    const float* w = (br == 0) ? w2 : ((br == 1) ? w3 : w4);
    int bo = (br + 1) * 32 + o;
    float inv = bns[bo] * rsqrtf(bnv[bo] + BN_EPS);
    w24t[i] = w[(o * 128 + c) * 9 + k] * inv;
  }
}

// ---------------- a0: transpose x -> xt bf16, quarter-major [b][q][px][32c] ----------------
__global__ __launch_bounds__(256) void a0_kernel(const float* __restrict__ x,
                                                 unsigned short* __restrict__ xt) {
  __shared__ unsigned short Ts[64][132];
  int t   = threadIdx.x;
  int b   = blockIdx.y;
  int px0 = blockIdx.x * 64;
  const float* xb = x + (size_t)b * 128 * NPIX;
  int p = t & 63, cq = t >> 6;
#pragma unroll 8
  for (int i = 0; i < 32; ++i) {
    int c = cq * 32 + i;
    Ts[p][c] = f2bf(xb[(size_t)c * NPIX + px0 + p]);
  }
  __syncthreads();
  int pw = t >> 2, cg = t & 3;   // cg == quarter
  unsigned short* dst = xt + ((size_t)(b * 4 + cg) * 16384 + px0 + pw) * 32;
#pragma unroll
  for (int k = 0; k < 8; ++k) {
    uint2 v = *(const uint2*)(&Ts[pw][cg * 32 + k * 4]);
    *(uint2*)(dst + k * 4) = v;
  }
}

// ---------------- a1 (fallback only) ----------------
__global__ __launch_bounds__(256) void a1_kernel(const float* __restrict__ x,
                                                 const float* __restrict__ w1f,
                                                 const float* __restrict__ wkt,
                                                 const float* __restrict__ bfp,
                                                 const float* __restrict__ bk,
                                                 float* __restrict__ out,
                                                 float* __restrict__ Kbuf) {
  __shared__ float lw1[128 * 32];
  __shared__ float lwk[128 * 16];
  __shared__ float lbf[32];
  int t = threadIdx.x;
  for (int i = t; i < 4096; i += 256) lw1[i] = w1f[i];
  for (int i = t; i < 2048; i += 256) lwk[i] = wkt[i];
  if (t < 32) lbf[t] = bfp[t];
  __syncthreads();

  int b  = blockIdx.y;
  int px = blockIdx.x * 256 + t;
  const float* xb = x + (size_t)b * 128 * NPIX;

  float acc[48];
#pragma unroll
  for (int i = 0; i < 48; ++i) acc[i] = 0.f;

  for (int c = 0; c < 128; ++c) {
    float xv = xb[(size_t)c * NPIX + px];
    const float4* w1p = (const float4*)(lw1 + c * 32);
#pragma unroll
    for (int j = 0; j < 8; ++j) {
      float4 w = w1p[j];
      acc[j*4+0] = fmaf(w.x, xv, acc[j*4+0]);
      acc[j*4+1] = fmaf(w.y, xv, acc[j*4+1]);
      acc[j*4+2] = fmaf(w.z, xv, acc[j*4+2]);
      acc[j*4+3] = fmaf(w.w, xv, acc[j*4+3]);
    }
    const float4* wkp = (const float4*)(lwk + c * 16);
#pragma unroll
    for (int j = 0; j < 4; ++j) {
      float4 w = wkp[j];
      acc[32+j*4+0] = fmaf(w.x, xv, acc[32+j*4+0]);
      acc[32+j*4+1] = fmaf(w.y, xv, acc[32+j*4+1]);
      acc[32+j*4+2] = fmaf(w.z, xv, acc[32+j*4+2]);
      acc[32+j*4+3] = fmaf(w.w, xv, acc[32+j*4+3]);
    }
  }
#pragma unroll
  for (int o = 0; o < 32; ++o)
    out[((size_t)(b * 128 + o)) * NPIX + px] = fmaxf(acc[o] + lbf[o], 0.f);
#pragma unroll
  for (int m = 0; m < 16; ++m)
    Kbuf[((size_t)(b * 16 + m)) * NPIX + px] = acc[32 + m] + bk[m];
}

// ---------------- a2m: LDS-staged conv + async stage ----------------
__global__ __launch_bounds__(256) void a2m_kernel(const unsigned short* __restrict__ xt,
                                                  const unsigned short* __restrict__ wbtr,
                                                  const float* __restrict__ bfp,
                                                  float* __restrict__ out) {
  __shared__ uint4 sxv[3073];                 // 48KB staged + 16B zero page
  unsigned short* sx = (unsigned short*)sxv;
  int t    = threadIdx.x;
  int wave = t >> 6, lane = t & 63;
  int l15  = lane & 15, cg = lane >> 4;
  int idx  = blockIdx.x;
  int b    = idx & 7;                         // batch -> XCD
  int rest = idx >> 3;
  int h2   = rest & 63;
  int br   = rest >> 6;
  int d    = 6 * (br + 1);
  int h0   = h2 * 2;
  int j    = wave >> 1;                       // row of the pair
  int p0   = (wave & 1) * 64;                 // px half

  if (t == 0) sxv[3072] = make_uint4(0u, 0u, 0u, 0u);

  const unsigned short* wb = wbtr + (size_t)br * 36864;

  f32x4 acc[2][4];
#pragma unroll
  for (int i = 0; i < 2; ++i)
#pragma unroll
    for (int n = 0; n < 4; ++n) acc[i][n] = (f32x4){0.f, 0.f, 0.f, 0.f};

  int pxb[3], xorv[3];
#pragma unroll
  for (int kw = 0; kw < 3; ++kw) {
    pxb[kw]  = p0 + l15 + (kw - 1) * d;
    xorv[kw] = (cg ^ ((pxb[kw] >> 1) & 3)) << 4;
  }

  // per-slot source rows (q-independent)
  int srow[6];
  bool sval[6];
#pragma unroll
  for (int slot = 0; slot < 6; ++slot) {
    srow[slot] = h0 + (slot & 1) + ((slot >> 1) - 1) * d;
    sval[slot] = ((unsigned)srow[slot] < 128u);
  }

  uint4 stv[12];
  // preload q=0
  {
    const unsigned short* slab = xt + (size_t)(b * 4 + 0) * 524288;
#pragma unroll
    for (int k = 0; k < 12; ++k) {
      int slot = k >> 1;
      int su   = ((k & 1) << 8) + t;
      stv[k] = sval[slot] ? *(const uint4*)(slab + (size_t)srow[slot] * 4096 + su * 8)
                          : make_uint4(0u, 0u, 0u, 0u);
    }
  }

  for (int q = 0; q < 4; ++q) {
    __syncthreads();                            // prior compute done reading LDS
#pragma unroll
    for (int k = 0; k < 12; ++k) {
      int slot = k >> 1;
      int su   = ((k & 1) << 8) + t;
      int px   = su >> 2, cgs = su & 3;
      int phys = slot * 4096 + px * 32 + ((cgs ^ ((px >> 1) & 3)) << 3);
      *(uint4*)(sx + phys) = stv[k];
    }
    __syncthreads();                            // staged visible
    if (q < 3) {                                // issue next-q loads early
      const unsigned short* slab = xt + (size_t)(b * 4 + q + 1) * 524288;
#pragma unroll
      for (int k = 0; k < 12; ++k) {
        int slot = k >> 1;
        int su   = ((k & 1) << 8) + t;
        stv[k] = sval[slot] ? *(const uint4*)(slab + (size_t)srow[slot] * 4096 + su * 8)
                            : make_uint4(0u, 0u, 0u, 0u);
      }
    }
    // ---- compute q: 9 taps x 32c ----
#pragma unroll
    for (int kh = 0; kh < 3; ++kh) {
      int slot  = kh * 2 + j;
      int sbase = slot * 8192;                  // byte
      bf16x8 a[3][2];
#pragma unroll
      for (int kw = 0; kw < 3; ++kw) {
        int tap = kh * 3 + kw;
        const unsigned short* wt = wb + ((((size_t)tap * 4 + q) * 2) << 9);
        a[kw][0] = *(const bf16x8*)(wt + lane * 8);
        a[kw][1] = *(const bf16x8*)(wt + 512 + lane * 8);
      }
#pragma unroll
      for (int kw = 0; kw < 3; ++kw) {
        int base = sbase + pxb[kw] * 64 + xorv[kw];
#pragma unroll
        for (int nf = 0; nf < 4; ++nf) {
          int px   = pxb[kw] + nf * 16;
          int addr = ((unsigned)px < 128u) ? (base + nf * 1024) : 49152;
          bf16x8 bv = *(const bf16x8*)((const char*)sx + addr);
          acc[0][nf] = __builtin_amdgcn_mfma_f32_16x16x32_bf16(a[kw][0], bv, acc[0][nf], 0, 0, 0);
          acc[1][nf] = __builtin_amdgcn_mfma_f32_16x16x32_bf16(a[kw][1], bv, acc[1][nf], 0, 0, 0);
        }
      }
    }
  }

  int ocb = (br + 1) * 32;
  int pxw = (h0 + j) * 128 + p0;
#pragma unroll
  for (int mf = 0; mf < 2; ++mf) {
#pragma unroll
    for (int r = 0; r < 4; ++r) {
      int oc = mf * 16 + cg * 4 + r;
      float bias = bfp[ocb + oc];
      float* op = out + ((size_t)(b * 128 + ocb + oc)) * NPIX + pxw + l15;
#pragma unroll
      for (int nf = 0; nf < 4; ++nf)
        op[nf * 16] = fmaxf(acc[mf][nf][r] + bias, 0.f);
    }
  }
}

// ---------------- a2f (fallback) ----------------
__global__ __launch_bounds__(256) void a2f_kernel(const float* __restrict__ x,
                                                  const float* __restrict__ w24t,
                                                  const float* __restrict__ bfp,
                                                  float* __restrict__ out) {
  int t  = threadIdx.x;
  int og = t & 3;
  int pg = (t >> 2) & 15;
  int r  = t >> 6;
  int br = blockIdx.z;
  int b  = blockIdx.y;
  int h  = blockIdx.x * 4 + r;
  int d  = 6 * (br + 1);

  const float* wt = w24t + (size_t)br * 36864;
  const float* bf = bfp + (br + 1) * 32;
  const float* xb = x + (size_t)b * 128 * NPIX;
  int w0 = pg << 3;

  float acc[8][8];
#pragma unroll
  for (int p = 0; p < 8; ++p)
#pragma unroll
    for (int o = 0; o < 8; ++o) acc[p][o] = 0.f;

  for (int c = 0; c < 128; ++c) {
    const float* xc = xb + (size_t)c * NPIX;
    const float* wc = wt + c * 288;
#pragma unroll
    for (int kh = 0; kh < 3; ++kh) {
      int row = h + (kh - 1) * d;
      if ((unsigned)row >= 128u) continue;
      const float* xr = xc + row * 128;
#pragma unroll
      for (int kw = 0; kw < 3; ++kw) {
        int wb = w0 + (kw - 1) * d;
        float xv[8];
        if (wb >= 0 && wb <= 120) {
          const float2* p2 = (const float2*)(xr + wb);
#pragma unroll
          for (int jj = 0; jj < 4; ++jj) {
            float2 v = p2[jj];
            xv[2*jj] = v.x; xv[2*jj+1] = v.y;
          }
        } else {
#pragma unroll
          for (int jj = 0; jj < 8; ++jj) {
            int ww = wb + jj;
            xv[jj] = ((unsigned)ww < 128u) ? xr[ww] : 0.f;
          }
        }
        const float4* wp = (const float4*)(wc + (kh * 3 + kw) * 32 + og * 8);
        float4 wa = wp[0], wbv = wp[1];
        float wr[8] = {wa.x, wa.y, wa.z, wa.w, wbv.x, wbv.y, wbv.z, wbv.w};
#pragma unroll
        for (int p = 0; p < 8; ++p)
#pragma unroll
          for (int o = 0; o < 8; ++o)
            acc[p][o] = fmaf(xv[p], wr[o], acc[p][o]);
      }
    }
  }

  int chbase = (br + 1) * 32 + og * 8;
  int n = h * 128 + w0;
#pragma unroll
  for (int o = 0; o < 8; ++o) {
    float bias = bf[og * 8 + o];
    float* op = out + ((size_t)(b * 128 + chbase + o)) * NPIX + n;
    float4 v0 = make_float4(fmaxf(acc[0][o] + bias, 0.f), fmaxf(acc[1][o] + bias, 0.f),
                            fmaxf(acc[2][o] + bias, 0.f), fmaxf(acc[3][o] + bias, 0.f));
    float4 v1 = make_float4(fmaxf(acc[4][o] + bias, 0.f), fmaxf(acc[5][o] + bias, 0.f),
                            fmaxf(acc[6][o] + bias, 0.f), fmaxf(acc[7][o] + bias, 0.f));
    ((float4*)op)[0] = v0;
    ((float4*)op)[1] = v1;
  }
}

// ---------------- cm v5: fused branch1+K+V, px-half-split to cap VGPR ----------------
__global__ __launch_bounds__(256) void cm_kernel(const unsigned short* __restrict__ xt,
                                                 const unsigned short* __restrict__ wvbr,
                                                 const unsigned short* __restrict__ wxbr,
                                                 const float* __restrict__ bv,
                                                 const float* __restrict__ bfp,
                                                 const float* __restrict__ bk,
                                                 float* __restrict__ out,
                                                 float* __restrict__ part) {
  __shared__ __align__(16) unsigned short Vl[128 * 136];   // bf16 [oc][px]
  __shared__ __align__(16) unsigned short knl[16 * 136];   // bf16 [m][px]
  int t    = threadIdx.x;
  int b    = blockIdx.y;
  int blk  = blockIdx.x;
  int wave = t >> 6, lane = t & 63;
  int l15  = lane & 15, cg = lane >> 4;
  int ocb  = wave * 32;

  float bvr[2][4];
#pragma unroll
  for (int mf = 0; mf < 2; ++mf)
#pragma unroll
    for (int r = 0; r < 4; ++r) bvr[mf][r] = bv[ocb + mf * 16 + cg * 4 + r];

  // extra-tile bias: wave0/1 -> branch1, wave2 -> bk
  float xb4[4];
#pragma unroll
  for (int r = 0; r < 4; ++r) xb4[r] = 0.f;
  if (wave == 0) {
#pragma unroll
    for (int r = 0; r < 4; ++r) xb4[r] = bfp[cg * 4 + r];
  } else if (wave == 1) {
#pragma unroll
    for (int r = 0; r < 4; ++r) xb4[r] = bfp[16 + cg * 4 + r];
  } else if (wave == 2) {
#pragma unroll
    for (int r = 0; r < 4; ++r) xb4[r] = bk[cg * 4 + r];
  }
  int xwave = (wave < 3) ? wave : 0;   // safe wxbr tile index for wave 3

  float kr[4] = {0.f, 0.f, 0.f, 0.f};
  float sv[2][4];
#pragma unroll
  for (int mf = 0; mf < 2; ++mf)
#pragma unroll
    for (int r = 0; r < 4; ++r) sv[mf][r] = 0.f;
  f32x4 am[2];
  am[0] = (f32x4){0.f,0.f,0.f,0.f};
  am[1] = (f32x4){0.f,0.f,0.f,0.f};

  for (int tile = blk; tile < 128; tile += 64) {
    __syncthreads();   // prior phase-3 reads done
    int pbase = tile << 7;

    // phase 2 in two 64-px halves (caps live accumulators at 48 VGPR)
#pragma unroll
    for (int hf = 0; hf < 2; ++hf) {
      f32x4 vacc[2][4];
      f32x4 xacc[4];
#pragma unroll
      for (int i = 0; i < 2; ++i)
#pragma unroll
        for (int n = 0; n < 4; ++n) vacc[i][n] = (f32x4){0.f,0.f,0.f,0.f};
#pragma unroll
      for (int n = 0; n < 4; ++n) xacc[n] = (f32x4){0.f,0.f,0.f,0.f};

#pragma unroll
      for (int cc = 0; cc < 4; ++cc) {
        const unsigned short* xq = xt + ((size_t)(b * 4 + cc) * 16384 + pbase) * 32;
        bf16x8 a0 = *(const bf16x8*)(wvbr + ((cc * 8 + wave * 2 + 0) << 9) + lane * 8);
        bf16x8 a1 = *(const bf16x8*)(wvbr + ((cc * 8 + wave * 2 + 1) << 9) + lane * 8);
        bf16x8 ax = *(const bf16x8*)(wxbr + ((cc * 3 + xwave) << 9) + lane * 8);
#pragma unroll
        for (int nf = 0; nf < 4; ++nf) {
          int nfg = hf * 4 + nf;
          bf16x8 bx = *(const bf16x8*)(xq + (size_t)(nfg * 16 + l15) * 32 + cg * 8);
          vacc[0][nf] = __builtin_amdgcn_mfma_f32_16x16x32_bf16(a0, bx, vacc[0][nf], 0, 0, 0);
          vacc[1][nf] = __builtin_amdgcn_mfma_f32_16x16x32_bf16(a1, bx, vacc[1][nf], 0, 0, 0);
          if (wave < 3)
            xacc[nf] = __builtin_amdgcn_mfma_f32_16x16x32_bf16(ax, bx, xacc[nf], 0, 0, 0);
        }
      }

      // V: vsum partial (fp32) + Vl bf16 (bias included)
#pragma unroll
      for (int mf = 0; mf < 2; ++mf) {
#pragma unroll
        for (int r = 0; r < 4; ++r) {
          float s = 0.f;
#pragma unroll
          for (int nf = 0; nf < 4; ++nf) s += vacc[mf][nf][r];
          sv[mf][r] += s;
          int c = ocb + mf * 16 + cg * 4 + r;
#pragma unroll
          for (int nf = 0; nf < 4; ++nf)
            Vl[c * 136 + (hf * 4 + nf) * 16 + l15] = f2bf(vacc[mf][nf][r] + bvr[mf][r]);
        }
      }

      if (wave < 2) {
        // branch1 out: bias+relu, fp32, channels 0..31
#pragma unroll
        for (int r = 0; r < 4; ++r) {
          int oc = wave * 16 + cg * 4 + r;
          float* op = out + ((size_t)(b * 128 + oc)) * NPIX + pbase + l15;
#pragma unroll
          for (int nf = 0; nf < 4; ++nf)
            op[(hf * 4 + nf) * 16] = fmaxf(xacc[nf][r] + xb4[r], 0.f);
        }
      } else if (wave == 2) {
        // K -> Kn -> knl (bf16) + ksum
#pragma unroll
        for (int nf = 0; nf < 4; ++nf) {
          int nfg = hf * 4 + nf;
          float kq[4]; float s2 = 0.f;
#pragma unroll
          for (int r = 0; r < 4; ++r) {
            kq[r] = xacc[nf][r] + xb4[r];
            s2 = fmaf(kq[r], kq[r], s2);
          }
          s2 += __shfl_xor(s2, 16);
          s2 += __shfl_xor(s2, 32);
          float inv = rsqrtf(s2);
#pragma unroll
          for (int r = 0; r < 4; ++r) {
            float kn = kq[r] * inv;
            knl[(cg * 4 + r) * 136 + nfg * 16 + l15] = f2bf(kn);
            kr[r] += kn;
          }
        }
      }
    }
    __syncthreads();

    // phase 3: mat[m][c] += Kn · V^T via MFMA
#pragma unroll
    for (int ks = 0; ks < 4; ++ks) {
      bf16x8 af = *(const bf16x8*)(knl + l15 * 136 + ks * 32 + cg * 8);
      bf16x8 b0 = *(const bf16x8*)(Vl + (size_t)(ocb + l15) * 136 + ks * 32 + cg * 8);
      bf16x8 b1 = *(const bf16x8*)(Vl + (size_t)(ocb + 16 + l15) * 136 + ks * 32 + cg * 8);
      am[0] = __builtin_amdgcn_mfma_f32_16x16x32_bf16(af, b0, am[0], 0, 0, 0);
      am[1] = __builtin_amdgcn_mfma_f32_16x16x32_bf16(af, b1, am[1], 0, 0, 0);
    }
  }

  // ---- write partials ----
  int blkid = b * 64 + blk;
  float* pp = part + (size_t)blkid * 2192;
#pragma unroll
  for (int nf2 = 0; nf2 < 2; ++nf2)
#pragma unroll
    for (int r = 0; r < 4; ++r)
      pp[(cg * 4 + r) * 128 + ocb + nf2 * 16 + l15] = am[nf2][r];
  // vsum: reduce over l15
#pragma unroll
  for (int off = 1; off < 16; off <<= 1) {
#pragma unroll
    for (int mf = 0; mf < 2; ++mf)
#pragma unroll
      for (int r = 0; r < 4; ++r)
        sv[mf][r] += __shfl_xor(sv[mf][r], off);
  }
  if (l15 == 0) {
#pragma unroll
    for (int mf = 0; mf < 2; ++mf)
#pragma unroll
      for (int r = 0; r < 4; ++r) {
        int c = ocb + mf * 16 + cg * 4 + r;
        pp[2048 + c] = sv[mf][r] + 256.f * bv[c];
      }
  }
  // ksum (wave 2)
  if (wave == 2) {
#pragma unroll
    for (int off = 1; off < 16; off <<= 1) {
#pragma unroll
      for (int r = 0; r < 4; ++r)
        kr[r] += __shfl_xor(kr[r], off);
    }
    if (l15 == 0) {
#pragma unroll
      for (int r = 0; r < 4; ++r)
        pp[2048 + 128 + cg * 4 + r] = kr[r];
    }
  }
}

// ---------------- cf (fallback) ----------------
__global__ __launch_bounds__(256) void cf_kernel(const float* __restrict__ x,
                                                 const float* __restrict__ bv,
                                                 const float* __restrict__ Kbuf,
                                                 const float* __restrict__ wvt,
                                                 float* __restrict__ part) {
  __shared__ float Vl[128 * 129];
  __shared__ float knl[16 * 132];
  int t   = threadIdx.x;
  int b   = blockIdx.y;
  int blk = blockIdx.x;
  const float* Kb = Kbuf + (size_t)b * 16 * NPIX;
  const float* xb = x + (size_t)b * 128 * NPIX;

  int m_own = t & 15;
  int c0    = (t >> 4) << 3;
  int pxg   = t & 15;

  float bvr[8];
#pragma unroll
  for (int jj = 0; jj < 8; ++jj) bvr[jj] = bv[c0 + jj];

  float macc[8] = {0,0,0,0,0,0,0,0};
  float vs[8]   = {0,0,0,0,0,0,0,0};
  float ksum[16];
#pragma unroll
  for (int m = 0; m < 16; ++m) ksum[m] = 0.f;

  for (int tile = blk; tile < 128; tile += 64) {
    __syncthreads();
    int pbase = tile << 7;

    if (t < 128) {
      float kv[16]; float ss = 0.f;
#pragma unroll
      for (int m = 0; m < 16; ++m) {
        kv[m] = Kb[(size_t)m * NPIX + pbase + t];
        ss = fmaf(kv[m], kv[m], ss);
      }
      float inv = rsqrtf(ss);
#pragma unroll
      for (int m = 0; m < 16; ++m) {
        float kn = kv[m] * inv;
        knl[m * 132 + t] = kn;
        ksum[m] += kn;
      }
    }

    float v[8][8];
#pragma unroll
    for (int i = 0; i < 8; ++i)
#pragma unroll
      for (int jj = 0; jj < 8; ++jj) v[i][jj] = 0.f;
    int px0 = pbase + (pxg << 3);
    for (int k = 0; k < 128; ++k) {
      const float4* xp = (const float4*)(xb + (size_t)k * NPIX + px0);
      float4 xa = xp[0], xc4 = xp[1];
      const float4* wp = (const float4*)(wvt + k * 128 + c0);
      float4 wa = wp[0], wc4 = wp[1];
      float xv[8] = {xa.x, xa.y, xa.z, xa.w, xc4.x, xc4.y, xc4.z, xc4.w};
      float wr[8] = {wa.x, wa.y, wa.z, wa.w, wc4.x, wc4.y, wc4.z, wc4.w};
#pragma unroll
      for (int i = 0; i < 8; ++i)
#pragma unroll
        for (int jj = 0; jj < 8; ++jj)
          v[i][jj] = fmaf(wr[i], xv[jj], v[i][jj]);
    }
#pragma unroll
    for (int i = 0; i < 8; ++i)
#pragma unroll
      for (int jj = 0; jj < 8; ++jj)
        Vl[(c0 + i) * 129 + (pxg << 3) + jj] = v[i][jj] + bvr[i];
    __syncthreads();

    for (int px = 0; px < 128; ++px) {
      float knv = knl[m_own * 132 + px];
      float vv[8];
#pragma unroll
      for (int jj = 0; jj < 8; ++jj) vv[jj] = Vl[(c0 + jj) * 129 + px];
#pragma unroll
      for (int jj = 0; jj < 8; ++jj) macc[jj] = fmaf(knv, vv[jj], macc[jj]);
      if (m_own == 0) {
#pragma unroll
        for (int jj = 0; jj < 8; ++jj) vs[jj] += vv[jj];
      }
    }
  }

  int blkid = b * 64 + blk;
  float* pp = part + (size_t)blkid * 2192;
#pragma unroll
  for (int jj = 0; jj < 8; ++jj) pp[m_own * 128 + c0 + jj] = macc[jj];
  if (m_own == 0) {
#pragma unroll
    for (int jj = 0; jj < 8; ++jj) pp[2048 + c0 + jj] = vs[jj];
  }
  __syncthreads();
  if (t < 128) {
#pragma unroll
    for (int m = 0; m < 16; ++m) knl[m * 132 + t] = ksum[m];
  }
  __syncthreads();
  if (t < 16) {
    float s = 0.f;
    for (int i = 0; i < 128; ++i) s += knl[t * 132 + i];
    pp[2048 + 128 + t] = s;
  }
}

// ---------------- reduce ----------------
__global__ void reduce_kernel(const float* __restrict__ part, float* __restrict__ stats) {
  int b = blockIdx.x, t = threadIdx.x;
  const float* pp = part + (size_t)b * 64 * 2192;
  float* st = stats + (size_t)b * 2192;
  for (int e = t; e < 2192; e += 256) {
    float s = 0.f;
    for (int g = 0; g < 64; ++g) s += pp[(size_t)g * 2192 + e];
    st[e] = s;
  }
}

// ---------------- d v2: Q, tailor, final output; 2 px per thread ----------------
__global__ __launch_bounds__(256) void d_kernel(const float* __restrict__ stats,
                                                const float* __restrict__ wq,
                                                const float* __restrict__ bq,
                                                const float* __restrict__ gamma,
                                                float* __restrict__ out) {
  __shared__ float matl[128 * 16];
  __shared__ float wql[128 * 16];
  __shared__ float vsl[128];
  __shared__ float ksl[16];
  int t = threadIdx.x;
  int b = blockIdx.y;
  const float* st = stats + (size_t)b * 2192;
  for (int i = t; i < 2048; i += 256) {
    int m = i >> 7, c = i & 127;
    matl[c * 16 + m] = st[i];
    wql[c * 16 + m]  = wq[m * 128 + c];
  }
  if (t < 128) vsl[t] = st[2048 + t];
  if (t < 16)  ksl[t] = st[2048 + 128 + t] + EPS_V;
  __syncthreads();

  int px0 = blockIdx.x * 512 + t * 2;
  float* ob = out + (size_t)b * 128 * NPIX;

  float q0[16], q1[16];
#pragma unroll
  for (int m = 0; m < 16; ++m) { q0[m] = bq[m]; q1[m] = bq[m]; }
  for (int c = 0; c < 128; ++c) {
    float2 xv = *(const float2*)(ob + (size_t)c * NPIX + px0);
    const float4* wp = (const float4*)(wql + c * 16);
#pragma unroll
    for (int jj = 0; jj < 4; ++jj) {
      float4 w = wp[jj];
      q0[jj*4+0] = fmaf(w.x, xv.x, q0[jj*4+0]);  q1[jj*4+0] = fmaf(w.x, xv.y, q1[jj*4+0]);
      q0[jj*4+1] = fmaf(w.y, xv.x, q0[jj*4+1]);  q1[jj*4+1] = fmaf(w.y, xv.y, q1[jj*4+1]);
      q0[jj*4+2] = fmaf(w.z, xv.x, q0[jj*4+2]);  q1[jj*4+2] = fmaf(w.z, xv.y, q1[jj*4+2]);
      q0[jj*4+3] = fmaf(w.w, xv.x, q0[jj*4+3]);  q1[jj*4+3] = fmaf(w.w, xv.y, q1[jj*4+3]);
    }
  }
  float ss0 = 0.f, ss1 = 0.f;
#pragma unroll
  for (int m = 0; m < 16; ++m) { ss0 = fmaf(q0[m], q0[m], ss0); ss1 = fmaf(q1[m], q1[m], ss1); }
  float inv0 = rsqrtf(ss0), inv1 = rsqrtf(ss1);
#pragma unroll
  for (int m = 0; m < 16; ++m) { q0[m] *= inv0; q1[m] *= inv1; }
  float den0 = (float)NPIX, den1 = (float)NPIX;
#pragma unroll
  for (int m = 0; m < 16; ++m) { den0 = fmaf(q0[m], ksl[m], den0); den1 = fmaf(q1[m], ksl[m], den1); }
  float g = gamma[0];
  float tl0 = g / den0, tl1 = g / den1;

  for (int c = 0; c < 128; ++c) {
    float vs = vsl[c];
    float s0 = vs, s1 = vs;
    const float4* mp = (const float4*)(matl + c * 16);
#pragma unroll
    for (int jj = 0; jj < 4; ++jj) {
      float4 w = mp[jj];
      s0 = fmaf(w.x, q0[jj*4+0], s0);  s1 = fmaf(w.x, q1[jj*4+0], s1);
      s0 = fmaf(w.y, q0[jj*4+1], s0);  s1 = fmaf(w.y, q1[jj*4+1], s1);
      s0 = fmaf(w.z, q0[jj*4+2], s0);  s1 = fmaf(w.z, q1[jj*4+2], s1);
      s0 = fmaf(w.w, q0[jj*4+3], s0);  s1 = fmaf(w.w, q1[jj*4+3], s1);
    }
    float2 res = make_float2(tl0 * s0, tl1 * s1);
    *(float2*)(ob + (size_t)c * NPIX + px0) = res;
  }
}

extern "C" void kernel_launch(void* const* d_in, const int* in_sizes, int n_in,
                              void* d_out, int out_size, void* d_ws, size_t ws_size,
                              hipStream_t stream) {
  (void)in_sizes; (void)n_in; (void)out_size;
  const float* x   = (const float*)d_in[0];
  const float* w1  = (const float*)d_in[1];
  const float* w2  = (const float*)d_in[2];
  const float* w3  = (const float*)d_in[3];
  const float* w4  = (const float*)d_in[4];
  const float* bns = (const float*)d_in[5];
  const float* bnb = (const float*)d_in[6];
  const float* bnm = (const float*)d_in[7];
  const float* bnv = (const float*)d_in[8];
  const float* wq  = (const float*)d_in[9];
  const float* bq  = (const float*)d_in[10];
  const float* wk  = (const float*)d_in[11];
  const float* bk  = (const float*)d_in[12];
  const float* wv  = (const float*)d_in[13];
  const float* bv  = (const float*)d_in[14];
  const float* gm  = (const float*)d_in[15];
  float* ws  = (float*)d_ws;
  float* out = (float*)d_out;

  float* Kbuf = ws + OFF_K;
  float* w1f  = ws + OFF_W1F;
  float* wkt  = ws + OFF_WKT;
  float* wvt  = ws + OFF_WVT;
  float* bfp  = ws + OFF_BF;
  float* part = ws + OFF_PART;
  float* stat = ws + OFF_STATS;

  prep_common_kernel<<<64, 256, 0, stream>>>(w1, bns, bnb, bnm, bnv, wk, wv,
                                             w1f, wkt, wvt, bfp);

  bool use_mfma = ws_size >= NEW_END * sizeof(float);
  if (use_mfma) {
    unsigned short* wbtr = (unsigned short*)(ws + OFF_WBT);
    unsigned short* xt   = (unsigned short*)(ws + OFF_XT);
    unsigned short* wvbr = (unsigned short*)(ws + OFF_WVB);
    unsigned short* wxbr = (unsigned short*)(ws + OFF_K);   // reuse freed Kbuf region
    prep_convb_kernel<<<64, 256, 0, stream>>>(w1, w2, w3, w4, bns, bnv, wk, wv,
                                              wbtr, wvbr, wxbr);
    a0_kernel<<<dim3(256, 8), 256, 0, stream>>>(x, xt);
    a2m_kernel<<<dim3(1536), 256, 0, stream>>>(xt, wbtr, bfp, out);
    cm_kernel<<<dim3(64, 8), 256, 0, stream>>>(xt, wvbr, wxbr, bv, bfp, bk, out, part);
  } else {
    float* w24t = ws + OFF_W24T;
    prep_convf_kernel<<<64, 256, 0, stream>>>(w2, w3, w4, bns, bnv, w24t);
    a1_kernel<<<dim3(64, 8), 256, 0, stream>>>(x, w1f, wkt, bfp, bk, out, Kbuf);
    a2f_kernel<<<dim3(32, 8, 3), 256, 0, stream>>>(x, w24t, bfp, out);
    cf_kernel<<<dim3(64, 8), 256, 0, stream>>>(x, bv, Kbuf, wvt, part);
  }
  reduce_kernel<<<8, 256, 0, stream>>>(part, stat);
  d_kernel<<<dim3(32, 8), 256, 0, stream>>>(stat, wq, bq, gm, out);
}

// Round 7
// 184.625 us; speedup vs baseline: 1.2283x; 1.0679x over previous
//
#include <hip/hip_runtime.h>
#include <hip/hip_bf16.h>
#include <math.h>

#define NPIX   16384
#define BATCH  8
#define BN_EPS 1e-5f
#define EPS_V  1e-6f

typedef __attribute__((ext_vector_type(8))) short bf16x8;
typedef __attribute__((ext_vector_type(4))) float f32x4;

// ---- workspace layout (float offsets) ----
// common
#define OFF_K     ((size_t)0)          // fallback: Kbuf. mfma path: wxbr (reuse)
#define OFF_W1F   ((size_t)2097152)    // 128*32   = 4096
#define OFF_WKT   ((size_t)2101248)    // 128*16   = 2048
#define OFF_WVT   ((size_t)2103296)    // 128*128  = 16384
#define OFF_BF    ((size_t)2119680)    // 4*32     = 128
#define OFF_PART  ((size_t)2119808)    // 512*2192 = 1122304
#define OFF_STATS ((size_t)3242112)    // 8*2192   = 17536
#define BASE_END  ((size_t)3259648)
// new (bf16-MFMA) path extras
#define OFF_WBT   BASE_END             // 3*9*4*2*64*8 ushort = 55296 floats
#define OFF_XT    ((size_t)3314976)    // 8*4*16384*32 ushort = 8388608 floats
#define OFF_WVB   ((size_t)11703584)   // 4*8*64*8 ushort = 8192 floats
#define NEW_END   ((size_t)11711776)
// old (fp32) fallback extras
#define OFF_W24T  BASE_END             // 3*128*9*32 = 110592

__device__ inline unsigned short f2bf(float f) {
  union { float f; unsigned int u; } v; v.f = f;
  unsigned int r = (v.u + 0x7FFFu + ((v.u >> 16) & 1u)) >> 16;
  return (unsigned short)r;
}

// ---------------- prep_common ----------------
__global__ void prep_common_kernel(const float* __restrict__ w1,
                                   const float* __restrict__ bns, const float* __restrict__ bnb,
                                   const float* __restrict__ bnm, const float* __restrict__ bnv,
                                   const float* __restrict__ wk, const float* __restrict__ wv,
                                   float* __restrict__ w1f, float* __restrict__ wkt,
                                   float* __restrict__ wvt, float* __restrict__ bf) {
  int tid = blockIdx.x * blockDim.x + threadIdx.x;
  int nt  = gridDim.x * blockDim.x;
  for (int i = tid; i < 128; i += nt) {
    float inv = bns[i] * rsqrtf(bnv[i] + BN_EPS);
    bf[i] = bnb[i] - bnm[i] * inv;
  }
  for (int i = tid; i < 4096; i += nt) {          // w1f[c][o]
    int c = i >> 5, o = i & 31;
    float inv = bns[o] * rsqrtf(bnv[o] + BN_EPS);
    w1f[i] = w1[o * 128 + c] * inv;
  }
  for (int i = tid; i < 2048; i += nt) {          // wkt[c][m]
    int c = i >> 4, m = i & 15;
    wkt[i] = wk[m * 128 + c];
  }
  for (int i = tid; i < 16384; i += nt) {         // wvt[c][o]
    int c = i >> 7, o = i & 127;
    wvt[i] = wv[o * 128 + c];
  }
}

// ---------------- prep_convb: MFMA-fragment-ordered bf16 weights ----------------
__global__ void prep_convb_kernel(const float* __restrict__ w1,
                                  const float* __restrict__ w2, const float* __restrict__ w3,
                                  const float* __restrict__ w4,
                                  const float* __restrict__ bns, const float* __restrict__ bnv,
                                  const float* __restrict__ wk, const float* __restrict__ wv,
                                  unsigned short* __restrict__ wbtr,
                                  unsigned short* __restrict__ wvbr,
                                  unsigned short* __restrict__ wxbr) {
  int tid = blockIdx.x * blockDim.x + threadIdx.x;
  int nt  = gridDim.x * blockDim.x;
  for (int i = tid; i < 16384; i += nt) {
    int e = i & 7, lane = (i >> 3) & 63, f = (i >> 9) & 7, q = i >> 12;
    int oc = f * 16 + (lane & 15);
    int c  = q * 32 + (lane >> 4) * 8 + e;
    wvbr[i] = f2bf(wv[oc * 128 + c]);
  }
  for (int i = tid; i < 6144; i += nt) {
    int e = i & 7, lane = (i >> 3) & 63, ct = i >> 9;
    int tile = ct % 3, q = ct / 3;
    int c = q * 32 + (lane >> 4) * 8 + e;
    float val;
    if (tile < 2) {
      int oc = tile * 16 + (lane & 15);
      val = w1[oc * 128 + c] * (bns[oc] * rsqrtf(bnv[oc] + BN_EPS));
    } else {
      val = wk[(lane & 15) * 128 + c];
    }
    wxbr[i] = f2bf(val);
  }
  for (int i = tid; i < 110592; i += nt) {
    int br = i / 36864;
    int r  = i - br * 36864;
    int tap  = r >> 12;
    int r2   = r & 4095;
    int q    = r2 >> 10;
    int r3   = r2 & 1023;
    int pair = r3 >> 9;
    int r4   = r3 & 511;
    int lane = r4 >> 3, e = r4 & 7;
    int oc = pair * 16 + (lane & 15);
    int c  = q * 32 + (lane >> 4) * 8 + e;
    const float* w = (br == 0) ? w2 : ((br == 1) ? w3 : w4);
    int bo = (br + 1) * 32 + oc;
    float inv = bns[bo] * rsqrtf(bnv[bo] + BN_EPS);
    wbtr[i] = f2bf(w[(oc * 128 + c) * 9 + tap] * inv);
  }
}

// ---------------- prep_convf (fallback) ----------------
__global__ void prep_convf_kernel(const float* __restrict__ w2, const float* __restrict__ w3,
                                  const float* __restrict__ w4,
                                  const float* __restrict__ bns, const float* __restrict__ bnv,
                                  float* __restrict__ w24t) {
  int tid = blockIdx.x * blockDim.x + threadIdx.x;
  int nt  = gridDim.x * blockDim.x;
  for (int i = tid; i < 110592; i += nt) {
    int br  = i / 36864;
    int rem = i - br * 36864;
    int c   = rem / 288;
    int k   = (rem % 288) >> 5;
    int o   = rem & 31;
    const float* w = (br == 0) ? w2 : ((br == 1) ? w3 : w4);
    int bo = (br + 1) * 32 + o;
    float inv = bns[bo] * rsqrtf(bnv[bo] + BN_EPS);
    w24t[i] = w[(o * 128 + c) * 9 + k] * inv;
  }
}

// ---------------- a0: transpose x -> xt bf16, quarter-major [b][q][px][32c] ----------------
__global__ __launch_bounds__(256) void a0_kernel(const float* __restrict__ x,
                                                 unsigned short* __restrict__ xt) {
  __shared__ unsigned short Ts[64][132];
  int t   = threadIdx.x;
  int b   = blockIdx.y;
  int px0 = blockIdx.x * 64;
  const float* xb = x + (size_t)b * 128 * NPIX;
  int p = t & 63, cq = t >> 6;
#pragma unroll 8
  for (int i = 0; i < 32; ++i) {
    int c = cq * 32 + i;
    Ts[p][c] = f2bf(xb[(size_t)c * NPIX + px0 + p]);
  }
  __syncthreads();
  int pw = t >> 2, cg = t & 3;   // cg == quarter
  unsigned short* dst = xt + ((size_t)(b * 4 + cg) * 16384 + px0 + pw) * 32;
#pragma unroll
  for (int k = 0; k < 8; ++k) {
    uint2 v = *(const uint2*)(&Ts[pw][cg * 32 + k * 4]);
    *(uint2*)(dst + k * 4) = v;
  }
}

// ---------------- a1 (fallback only) ----------------
__global__ __launch_bounds__(256) void a1_kernel(const float* __restrict__ x,
                                                 const float* __restrict__ w1f,
                                                 const float* __restrict__ wkt,
                                                 const float* __restrict__ bfp,
                                                 const float* __restrict__ bk,
                                                 float* __restrict__ out,
                                                 float* __restrict__ Kbuf) {
  __shared__ float lw1[128 * 32];
  __shared__ float lwk[128 * 16];
  __shared__ float lbf[32];
  int t = threadIdx.x;
  for (int i = t; i < 4096; i += 256) lw1[i] = w1f[i];
  for (int i = t; i < 2048; i += 256) lwk[i] = wkt[i];
  if (t < 32) lbf[t] = bfp[t];
  __syncthreads();

  int b  = blockIdx.y;
  int px = blockIdx.x * 256 + t;
  const float* xb = x + (size_t)b * 128 * NPIX;

  float acc[48];
#pragma unroll
  for (int i = 0; i < 48; ++i) acc[i] = 0.f;

  for (int c = 0; c < 128; ++c) {
    float xv = xb[(size_t)c * NPIX + px];
    const float4* w1p = (const float4*)(lw1 + c * 32);
#pragma unroll
    for (int j = 0; j < 8; ++j) {
      float4 w = w1p[j];
      acc[j*4+0] = fmaf(w.x, xv, acc[j*4+0]);
      acc[j*4+1] = fmaf(w.y, xv, acc[j*4+1]);
      acc[j*4+2] = fmaf(w.z, xv, acc[j*4+2]);
      acc[j*4+3] = fmaf(w.w, xv, acc[j*4+3]);
    }
    const float4* wkp = (const float4*)(lwk + c * 16);
#pragma unroll
    for (int j = 0; j < 4; ++j) {
      float4 w = wkp[j];
      acc[32+j*4+0] = fmaf(w.x, xv, acc[32+j*4+0]);
      acc[32+j*4+1] = fmaf(w.y, xv, acc[32+j*4+1]);
      acc[32+j*4+2] = fmaf(w.z, xv, acc[32+j*4+2]);
      acc[32+j*4+3] = fmaf(w.w, xv, acc[32+j*4+3]);
    }
  }
#pragma unroll
  for (int o = 0; o < 32; ++o)
    out[((size_t)(b * 128 + o)) * NPIX + px] = fmaxf(acc[o] + lbf[o], 0.f);
#pragma unroll
  for (int m = 0; m < 16; ++m)
    Kbuf[((size_t)(b * 16 + m)) * NPIX + px] = acc[32 + m] + bk[m];
}

// ---------------- a2m (round-4 structure): LDS-staged conv, MFMA ----------------
__global__ __launch_bounds__(256) void a2m_kernel(const unsigned short* __restrict__ xt,
                                                  const unsigned short* __restrict__ wbtr,
                                                  const float* __restrict__ bfp,
                                                  float* __restrict__ out) {
  __shared__ uint4 sxv[3073];                 // 48KB staged + 16B zero page
  unsigned short* sx = (unsigned short*)sxv;
  int t    = threadIdx.x;
  int wave = t >> 6, lane = t & 63;
  int l15  = lane & 15, cg = lane >> 4;
  int idx  = blockIdx.x;
  int b    = idx & 7;                         // batch -> XCD
  int rest = idx >> 3;
  int h2   = rest & 63;
  int br   = rest >> 6;
  int d    = 6 * (br + 1);
  int h0   = h2 * 2;
  int j    = wave >> 1;                       // row of the pair
  int p0   = (wave & 1) * 64;                 // px half

  if (t == 0) sxv[3072] = make_uint4(0u, 0u, 0u, 0u);   // zero page @ byte 49152

  const unsigned short* wb = wbtr + (size_t)br * 36864;

  f32x4 acc[2][4];
#pragma unroll
  for (int i = 0; i < 2; ++i)
#pragma unroll
    for (int n = 0; n < 4; ++n) acc[i][n] = (f32x4){0.f, 0.f, 0.f, 0.f};

  int pxb[3], xorv[3];
#pragma unroll
  for (int kw = 0; kw < 3; ++kw) {
    pxb[kw]  = p0 + l15 + (kw - 1) * d;
    xorv[kw] = (cg ^ ((pxb[kw] >> 1) & 3)) << 4;
  }

  for (int q = 0; q < 4; ++q) {
    __syncthreads();                            // previous compute done
    // ---- stage 6 rows x 8KB (reg-staged, coalesced reads, swizzled LDS writes) ----
    const unsigned short* slab = xt + (size_t)(b * 4 + q) * 524288;
    uint4 stv[12];
#pragma unroll
    for (int k = 0; k < 12; ++k) {
      int slot = k >> 1;                                  // kh*2 + jrow
      int srow = h0 + (slot & 1) + ((slot >> 1) - 1) * d;
      int su   = ((k & 1) << 8) + t;                      // 16B unit within slot
      if ((unsigned)srow < 128u)
        stv[k] = *(const uint4*)(slab + (size_t)srow * 4096 + su * 8);
      else
        stv[k] = make_uint4(0u, 0u, 0u, 0u);
    }
#pragma unroll
    for (int k = 0; k < 12; ++k) {
      int slot = k >> 1;
      int su   = ((k & 1) << 8) + t;
      int px   = su >> 2, cgs = su & 3;
      int phys = slot * 4096 + px * 32 + ((cgs ^ ((px >> 1) & 3)) << 3);  // ushort idx
      *(uint4*)(sx + phys) = stv[k];
    }
    __syncthreads();                            // staged visible
    // ---- compute: 9 taps x 32c ----
#pragma unroll
    for (int kh = 0; kh < 3; ++kh) {
      int slot  = kh * 2 + j;
      int sbase = slot * 8192;                  // byte
      bf16x8 a[3][2];
#pragma unroll
      for (int kw = 0; kw < 3; ++kw) {
        int tap = kh * 3 + kw;
        const unsigned short* wt = wb + ((((size_t)tap * 4 + q) * 2) << 9);
        a[kw][0] = *(const bf16x8*)(wt + lane * 8);
        a[kw][1] = *(const bf16x8*)(wt + 512 + lane * 8);
      }
#pragma unroll
      for (int kw = 0; kw < 3; ++kw) {
        int base = sbase + pxb[kw] * 64 + xorv[kw];
#pragma unroll
        for (int nf = 0; nf < 4; ++nf) {
          int px   = pxb[kw] + nf * 16;
          int addr = ((unsigned)px < 128u) ? (base + nf * 1024) : 49152;
          bf16x8 bv = *(const bf16x8*)((const char*)sx + addr);
          acc[0][nf] = __builtin_amdgcn_mfma_f32_16x16x32_bf16(a[kw][0], bv, acc[0][nf], 0, 0, 0);
          acc[1][nf] = __builtin_amdgcn_mfma_f32_16x16x32_bf16(a[kw][1], bv, acc[1][nf], 0, 0, 0);
        }
      }
    }
  }

  // epilogue: bias + relu, fp32 out
  int ocb = (br + 1) * 32;
  int pxw = (h0 + j) * 128 + p0;
#pragma unroll
  for (int mf = 0; mf < 2; ++mf) {
#pragma unroll
    for (int r = 0; r < 4; ++r) {
      int oc = mf * 16 + cg * 4 + r;
      float bias = bfp[ocb + oc];
      float* op = out + ((size_t)(b * 128 + ocb + oc)) * NPIX + pxw + l15;
#pragma unroll
      for (int nf = 0; nf < 4; ++nf)
        op[nf * 16] = fmaxf(acc[mf][nf][r] + bias, 0.f);
    }
  }
}

// ---------------- a2f (fallback) ----------------
__global__ __launch_bounds__(256) void a2f_kernel(const float* __restrict__ x,
                                                  const float* __restrict__ w24t,
                                                  const float* __restrict__ bfp,
                                                  float* __restrict__ out) {
  int t  = threadIdx.x;
  int og = t & 3;
  int pg = (t >> 2) & 15;
  int r  = t >> 6;
  int br = blockIdx.z;
  int b  = blockIdx.y;
  int h  = blockIdx.x * 4 + r;
  int d  = 6 * (br + 1);

  const float* wt = w24t + (size_t)br * 36864;
  const float* bf = bfp + (br + 1) * 32;
  const float* xb = x + (size_t)b * 128 * NPIX;
  int w0 = pg << 3;

  float acc[8][8];
#pragma unroll
  for (int p = 0; p < 8; ++p)
#pragma unroll
    for (int o = 0; o < 8; ++o) acc[p][o] = 0.f;

  for (int c = 0; c < 128; ++c) {
    const float* xc = xb + (size_t)c * NPIX;
    const float* wc = wt + c * 288;
#pragma unroll
    for (int kh = 0; kh < 3; ++kh) {
      int row = h + (kh - 1) * d;
      if ((unsigned)row >= 128u) continue;
      const float* xr = xc + row * 128;
#pragma unroll
      for (int kw = 0; kw < 3; ++kw) {
        int wb = w0 + (kw - 1) * d;
        float xv[8];
        if (wb >= 0 && wb <= 120) {
          const float2* p2 = (const float2*)(xr + wb);
#pragma unroll
          for (int jj = 0; jj < 4; ++jj) {
            float2 v = p2[jj];
            xv[2*jj] = v.x; xv[2*jj+1] = v.y;
          }
        } else {
#pragma unroll
          for (int jj = 0; jj < 8; ++jj) {
            int ww = wb + jj;
            xv[jj] = ((unsigned)ww < 128u) ? xr[ww] : 0.f;
          }
        }
        const float4* wp = (const float4*)(wc + (kh * 3 + kw) * 32 + og * 8);
        float4 wa = wp[0], wbv = wp[1];
        float wr[8] = {wa.x, wa.y, wa.z, wa.w, wbv.x, wbv.y, wbv.z, wbv.w};
#pragma unroll
        for (int p = 0; p < 8; ++p)
#pragma unroll
          for (int o = 0; o < 8; ++o)
            acc[p][o] = fmaf(xv[p], wr[o], acc[p][o]);
      }
    }
  }

  int chbase = (br + 1) * 32 + og * 8;
  int n = h * 128 + w0;
#pragma unroll
  for (int o = 0; o < 8; ++o) {
    float bias = bf[og * 8 + o];
    float* op = out + ((size_t)(b * 128 + chbase + o)) * NPIX + n;
    float4 v0 = make_float4(fmaxf(acc[0][o] + bias, 0.f), fmaxf(acc[1][o] + bias, 0.f),
                            fmaxf(acc[2][o] + bias, 0.f), fmaxf(acc[3][o] + bias, 0.f));
    float4 v1 = make_float4(fmaxf(acc[4][o] + bias, 0.f), fmaxf(acc[5][o] + bias, 0.f),
                            fmaxf(acc[6][o] + bias, 0.f), fmaxf(acc[7][o] + bias, 0.f));
    ((float4*)op)[0] = v0;
    ((float4*)op)[1] = v1;
  }
}

// ---------------- cm v5: fused branch1+K+V, px-half-split to cap VGPR ----------------
__global__ __launch_bounds__(256) void cm_kernel(const unsigned short* __restrict__ xt,
                                                 const unsigned short* __restrict__ wvbr,
                                                 const unsigned short* __restrict__ wxbr,
                                                 const float* __restrict__ bv,
                                                 const float* __restrict__ bfp,
                                                 const float* __restrict__ bk,
                                                 float* __restrict__ out,
                                                 float* __restrict__ part) {
  __shared__ __align__(16) unsigned short Vl[128 * 136];   // bf16 [oc][px]
  __shared__ __align__(16) unsigned short knl[16 * 136];   // bf16 [m][px]
  int t    = threadIdx.x;
  int b    = blockIdx.y;
  int blk  = blockIdx.x;
  int wave = t >> 6, lane = t & 63;
  int l15  = lane & 15, cg = lane >> 4;
  int ocb  = wave * 32;

  float bvr[2][4];
#pragma unroll
  for (int mf = 0; mf < 2; ++mf)
#pragma unroll
    for (int r = 0; r < 4; ++r) bvr[mf][r] = bv[ocb + mf * 16 + cg * 4 + r];

  // extra-tile bias: wave0/1 -> branch1, wave2 -> bk
  float xb4[4];
#pragma unroll
  for (int r = 0; r < 4; ++r) xb4[r] = 0.f;
  if (wave == 0) {
#pragma unroll
    for (int r = 0; r < 4; ++r) xb4[r] = bfp[cg * 4 + r];
  } else if (wave == 1) {
#pragma unroll
    for (int r = 0; r < 4; ++r) xb4[r] = bfp[16 + cg * 4 + r];
  } else if (wave == 2) {
#pragma unroll
    for (int r = 0; r < 4; ++r) xb4[r] = bk[cg * 4 + r];
  }
  int xwave = (wave < 3) ? wave : 0;   // safe wxbr tile index for wave 3

  float kr[4] = {0.f, 0.f, 0.f, 0.f};
  float sv[2][4];
#pragma unroll
  for (int mf = 0; mf < 2; ++mf)
#pragma unroll
    for (int r = 0; r < 4; ++r) sv[mf][r] = 0.f;
  f32x4 am[2];
  am[0] = (f32x4){0.f,0.f,0.f,0.f};
  am[1] = (f32x4){0.f,0.f,0.f,0.f};

  for (int tile = blk; tile < 128; tile += 64) {
    __syncthreads();   // prior phase-3 reads done
    int pbase = tile << 7;

    // phase 2 in two 64-px halves (caps live accumulators at 48 VGPR)
#pragma unroll
    for (int hf = 0; hf < 2; ++hf) {
      f32x4 vacc[2][4];
      f32x4 xacc[4];
#pragma unroll
      for (int i = 0; i < 2; ++i)
#pragma unroll
        for (int n = 0; n < 4; ++n) vacc[i][n] = (f32x4){0.f,0.f,0.f,0.f};
#pragma unroll
      for (int n = 0; n < 4; ++n) xacc[n] = (f32x4){0.f,0.f,0.f,0.f};

#pragma unroll
      for (int cc = 0; cc < 4; ++cc) {
        const unsigned short* xq = xt + ((size_t)(b * 4 + cc) * 16384 + pbase) * 32;
        bf16x8 a0 = *(const bf16x8*)(wvbr + ((cc * 8 + wave * 2 + 0) << 9) + lane * 8);
        bf16x8 a1 = *(const bf16x8*)(wvbr + ((cc * 8 + wave * 2 + 1) << 9) + lane * 8);
        bf16x8 ax = *(const bf16x8*)(wxbr + ((cc * 3 + xwave) << 9) + lane * 8);
#pragma unroll
        for (int nf = 0; nf < 4; ++nf) {
          int nfg = hf * 4 + nf;
          bf16x8 bx = *(const bf16x8*)(xq + (size_t)(nfg * 16 + l15) * 32 + cg * 8);
          vacc[0][nf] = __builtin_amdgcn_mfma_f32_16x16x32_bf16(a0, bx, vacc[0][nf], 0, 0, 0);
          vacc[1][nf] = __builtin_amdgcn_mfma_f32_16x16x32_bf16(a1, bx, vacc[1][nf], 0, 0, 0);
          if (wave < 3)
            xacc[nf] = __builtin_amdgcn_mfma_f32_16x16x32_bf16(ax, bx, xacc[nf], 0, 0, 0);
        }
      }

      // V: vsum partial (fp32) + Vl bf16 (bias included)
#pragma unroll
      for (int mf = 0; mf < 2; ++mf) {
#pragma unroll
        for (int r = 0; r < 4; ++r) {
          float s = 0.f;
#pragma unroll
          for (int nf = 0; nf < 4; ++nf) s += vacc[mf][nf][r];
          sv[mf][r] += s;
          int c = ocb + mf * 16 + cg * 4 + r;
#pragma unroll
          for (int nf = 0; nf < 4; ++nf)
            Vl[c * 136 + (hf * 4 + nf) * 16 + l15] = f2bf(vacc[mf][nf][r] + bvr[mf][r]);
        }
      }

      if (wave < 2) {
        // branch1 out: bias+relu, fp32, channels 0..31
#pragma unroll
        for (int r = 0; r < 4; ++r) {
          int oc = wave * 16 + cg * 4 + r;
          float* op = out + ((size_t)(b * 128 + oc)) * NPIX + pbase + l15;
#pragma unroll
          for (int nf = 0; nf < 4; ++nf)
            op[(hf * 4 + nf) * 16] = fmaxf(xacc[nf][r] + xb4[r], 0.f);
        }
      } else if (wave == 2) {
        // K -> Kn -> knl (bf16) + ksum
#pragma unroll
        for (int nf = 0; nf < 4; ++nf) {
          int nfg = hf * 4 + nf;
          float kq[4]; float s2 = 0.f;
#pragma unroll
          for (int r = 0; r < 4; ++r) {
            kq[r] = xacc[nf][r] + xb4[r];
            s2 = fmaf(kq[r], kq[r], s2);
          }
          s2 += __shfl_xor(s2, 16);
          s2 += __shfl_xor(s2, 32);
          float inv = rsqrtf(s2);
#pragma unroll
          for (int r = 0; r < 4; ++r) {
            float kn = kq[r] * inv;
            knl[(cg * 4 + r) * 136 + nfg * 16 + l15] = f2bf(kn);
            kr[r] += kn;
          }
        }
      }
    }
    __syncthreads();

    // phase 3: mat[m][c] += Kn · V^T via MFMA
#pragma unroll
    for (int ks = 0; ks < 4; ++ks) {
      bf16x8 af = *(const bf16x8*)(knl + l15 * 136 + ks * 32 + cg * 8);
      bf16x8 b0 = *(const bf16x8*)(Vl + (size_t)(ocb + l15) * 136 + ks * 32 + cg * 8);
      bf16x8 b1 = *(const bf16x8*)(Vl + (size_t)(ocb + 16 + l15) * 136 + ks * 32 + cg * 8);
      am[0] = __builtin_amdgcn_mfma_f32_16x16x32_bf16(af, b0, am[0], 0, 0, 0);
      am[1] = __builtin_amdgcn_mfma_f32_16x16x32_bf16(af, b1, am[1], 0, 0, 0);
    }
  }

  // ---- write partials ----
  int blkid = b * 64 + blk;
  float* pp = part + (size_t)blkid * 2192;
#pragma unroll
  for (int nf2 = 0; nf2 < 2; ++nf2)
#pragma unroll
    for (int r = 0; r < 4; ++r)
      pp[(cg * 4 + r) * 128 + ocb + nf2 * 16 + l15] = am[nf2][r];
  // vsum: reduce over l15
#pragma unroll
  for (int off = 1; off < 16; off <<= 1) {
#pragma unroll
    for (int mf = 0; mf < 2; ++mf)
#pragma unroll
      for (int r = 0; r < 4; ++r)
        sv[mf][r] += __shfl_xor(sv[mf][r], off);
  }
  if (l15 == 0) {
#pragma unroll
    for (int mf = 0; mf < 2; ++mf)
#pragma unroll
      for (int r = 0; r < 4; ++r) {
        int c = ocb + mf * 16 + cg * 4 + r;
        pp[2048 + c] = sv[mf][r] + 256.f * bv[c];
      }
  }
  // ksum (wave 2)
  if (wave == 2) {
#pragma unroll
    for (int off = 1; off < 16; off <<= 1) {
#pragma unroll
      for (int r = 0; r < 4; ++r)
        kr[r] += __shfl_xor(kr[r], off);
    }
    if (l15 == 0) {
#pragma unroll
      for (int r = 0; r < 4; ++r)
        pp[2048 + 128 + cg * 4 + r] = kr[r];
    }
  }
}

// ---------------- cf (fallback) ----------------
__global__ __launch_bounds__(256) void cf_kernel(const float* __restrict__ x,
                                                 const float* __restrict__ bv,
                                                 const float* __restrict__ Kbuf,
                                                 const float* __restrict__ wvt,
                                                 float* __restrict__ part) {
  __shared__ float Vl[128 * 129];
  __shared__ float knl[16 * 132];
  int t   = threadIdx.x;
  int b   = blockIdx.y;
  int blk = blockIdx.x;
  const float* Kb = Kbuf + (size_t)b * 16 * NPIX;
  const float* xb = x + (size_t)b * 128 * NPIX;

  int m_own = t & 15;
  int c0    = (t >> 4) << 3;
  int pxg   = t & 15;

  float bvr[8];
#pragma unroll
  for (int jj = 0; jj < 8; ++jj) bvr[jj] = bv[c0 + jj];

  float macc[8] = {0,0,0,0,0,0,0,0};
  float vs[8]   = {0,0,0,0,0,0,0,0};
  float ksum[16];
#pragma unroll
  for (int m = 0; m < 16; ++m) ksum[m] = 0.f;

  for (int tile = blk; tile < 128; tile += 64) {
    __syncthreads();
    int pbase = tile << 7;

    if (t < 128) {
      float kv[16]; float ss = 0.f;
#pragma unroll
      for (int m = 0; m < 16; ++m) {
        kv[m] = Kb[(size_t)m * NPIX + pbase + t];
        ss = fmaf(kv[m], kv[m], ss);
      }
      float inv = rsqrtf(ss);
#pragma unroll
      for (int m = 0; m < 16; ++m) {
        float kn = kv[m] * inv;
        knl[m * 132 + t] = kn;
        ksum[m] += kn;
      }
    }

    float v[8][8];
#pragma unroll
    for (int i = 0; i < 8; ++i)
#pragma unroll
      for (int jj = 0; jj < 8; ++jj) v[i][jj] = 0.f;
    int px0 = pbase + (pxg << 3);
    for (int k = 0; k < 128; ++k) {
      const float4* xp = (const float4*)(xb + (size_t)k * NPIX + px0);
      float4 xa = xp[0], xc4 = xp[1];
      const float4* wp = (const float4*)(wvt + k * 128 + c0);
      float4 wa = wp[0], wc4 = wp[1];
      float xv[8] = {xa.x, xa.y, xa.z, xa.w, xc4.x, xc4.y, xc4.z, xc4.w};
      float wr[8] = {wa.x, wa.y, wa.z, wa.w, wc4.x, wc4.y, wc4.z, wc4.w};
#pragma unroll
      for (int i = 0; i < 8; ++i)
#pragma unroll
        for (int jj = 0; jj < 8; ++jj)
          v[i][jj] = fmaf(wr[i], xv[jj], v[i][jj]);
    }
#pragma unroll
    for (int i = 0; i < 8; ++i)
#pragma unroll
      for (int jj = 0; jj < 8; ++jj)
        Vl[(c0 + i) * 129 + (pxg << 3) + jj] = v[i][jj] + bvr[i];
    __syncthreads();

    for (int px = 0; px < 128; ++px) {
      float knv = knl[m_own * 132 + px];
      float vv[8];
#pragma unroll
      for (int jj = 0; jj < 8; ++jj) vv[jj] = Vl[(c0 + jj) * 129 + px];
#pragma unroll
      for (int jj = 0; jj < 8; ++jj) macc[jj] = fmaf(knv, vv[jj], macc[jj]);
      if (m_own == 0) {
#pragma unroll
        for (int jj = 0; jj < 8; ++jj) vs[jj] += vv[jj];
      }
    }
  }

  int blkid = b * 64 + blk;
  float* pp = part + (size_t)blkid * 2192;
#pragma unroll
  for (int jj = 0; jj < 8; ++jj) pp[m_own * 128 + c0 + jj] = macc[jj];
  if (m_own == 0) {
#pragma unroll
    for (int jj = 0; jj < 8; ++jj) pp[2048 + c0 + jj] = vs[jj];
  }
  __syncthreads();
  if (t < 128) {
#pragma unroll
    for (int m = 0; m < 16; ++m) knl[m * 132 + t] = ksum[m];
  }
  __syncthreads();
  if (t < 16) {
    float s = 0.f;
    for (int i = 0; i < 128; ++i) s += knl[t * 132 + i];
    pp[2048 + 128 + t] = s;
  }
}

// ---------------- reduce: 72 blocks (9 chunks x 8 batches) ----------------
__global__ void reduce_kernel(const float* __restrict__ part, float* __restrict__ stats) {
  int b = blockIdx.y, t = threadIdx.x;
  int e = blockIdx.x * 256 + t;
  if (e >= 2192) return;
  const float* pp = part + (size_t)b * 64 * 2192;
  float s = 0.f;
  for (int g = 0; g < 64; ++g) s += pp[(size_t)g * 2192 + e];
  stats[(size_t)b * 2192 + e] = s;
}

// ---------------- d v3: Q, tailor, final output; 4 px per thread ----------------
__global__ __launch_bounds__(256) void d_kernel(const float* __restrict__ stats,
                                                const float* __restrict__ wq,
                                                const float* __restrict__ bq,
                                                const float* __restrict__ gamma,
                                                float* __restrict__ out) {
  __shared__ float matl[128 * 16];
  __shared__ float wql[128 * 16];
  __shared__ float vsl[128];
  __shared__ float ksl[16];
  int t = threadIdx.x;
  int b = blockIdx.y;
  const float* st = stats + (size_t)b * 2192;
  for (int i = t; i < 2048; i += 256) {
    int m = i >> 7, c = i & 127;
    matl[c * 16 + m] = st[i];
    wql[c * 16 + m]  = wq[m * 128 + c];
  }
  if (t < 128) vsl[t] = st[2048 + t];
  if (t < 16)  ksl[t] = st[2048 + 128 + t] + EPS_V;
  __syncthreads();

  int px0 = blockIdx.x * 1024 + t * 4;
  float* ob = out + (size_t)b * 128 * NPIX;

  float q[4][16];
#pragma unroll
  for (int p = 0; p < 4; ++p)
#pragma unroll
    for (int m = 0; m < 16; ++m) q[p][m] = bq[m];

  for (int c = 0; c < 128; ++c) {
    float4 xv = *(const float4*)(ob + (size_t)c * NPIX + px0);
    float xa[4] = {xv.x, xv.y, xv.z, xv.w};
    const float4* wp = (const float4*)(wql + c * 16);
#pragma unroll
    for (int jj = 0; jj < 4; ++jj) {
      float4 w = wp[jj];
#pragma unroll
      for (int p = 0; p < 4; ++p) {
        q[p][jj*4+0] = fmaf(w.x, xa[p], q[p][jj*4+0]);
        q[p][jj*4+1] = fmaf(w.y, xa[p], q[p][jj*4+1]);
        q[p][jj*4+2] = fmaf(w.z, xa[p], q[p][jj*4+2]);
        q[p][jj*4+3] = fmaf(w.w, xa[p], q[p][jj*4+3]);
      }
    }
  }
  float tl[4];
#pragma unroll
  for (int p = 0; p < 4; ++p) {
    float ss = 0.f;
#pragma unroll
    for (int m = 0; m < 16; ++m) ss = fmaf(q[p][m], q[p][m], ss);
    float inv = rsqrtf(ss);
#pragma unroll
    for (int m = 0; m < 16; ++m) q[p][m] *= inv;
    float den = (float)NPIX;
#pragma unroll
    for (int m = 0; m < 16; ++m) den = fmaf(q[p][m], ksl[m], den);
    tl[p] = gamma[0] / den;
  }

  for (int c = 0; c < 128; ++c) {
    float vs = vsl[c];
    float s[4] = {vs, vs, vs, vs};
    const float4* mp = (const float4*)(matl + c * 16);
#pragma unroll
    for (int jj = 0; jj < 4; ++jj) {
      float4 w = mp[jj];
#pragma unroll
      for (int p = 0; p < 4; ++p) {
        s[p] = fmaf(w.x, q[p][jj*4+0], s[p]);
        s[p] = fmaf(w.y, q[p][jj*4+1], s[p]);
        s[p] = fmaf(w.z, q[p][jj*4+2], s[p]);
        s[p] = fmaf(w.w, q[p][jj*4+3], s[p]);
      }
    }
    float4 res = make_float4(tl[0]*s[0], tl[1]*s[1], tl[2]*s[2], tl[3]*s[3]);
    *(float4*)(ob + (size_t)c * NPIX + px0) = res;
  }
}

extern "C" void kernel_launch(void* const* d_in, const int* in_sizes, int n_in,
                              void* d_out, int out_size, void* d_ws, size_t ws_size,
                              hipStream_t stream) {
  (void)in_sizes; (void)n_in; (void)out_size;
  const float* x   = (const float*)d_in[0];
  const float* w1  = (const float*)d_in[1];
  const float* w2  = (const float*)d_in[2];
  const float* w3  = (const float*)d_in[3];
  const float* w4  = (const float*)d_in[4];
  const float* bns = (const float*)d_in[5];
  const float* bnb = (const float*)d_in[6];
  const float* bnm = (const float*)d_in[7];
  const float* bnv = (const float*)d_in[8];
  const float* wq  = (const float*)d_in[9];
  const float* bq  = (const float*)d_in[10];
  const float* wk  = (const float*)d_in[11];
  const float* bk  = (const float*)d_in[12];
  const float* wv  = (const float*)d_in[13];
  const float* bv  = (const float*)d_in[14];
  const float* gm  = (const float*)d_in[15];
  float* ws  = (float*)d_ws;
  float* out = (float*)d_out;

  float* Kbuf = ws + OFF_K;
  float* w1f  = ws + OFF_W1F;
  float* wkt  = ws + OFF_WKT;
  float* wvt  = ws + OFF_WVT;
  float* bfp  = ws + OFF_BF;
  float* part = ws + OFF_PART;
  float* stat = ws + OFF_STATS;

  prep_common_kernel<<<64, 256, 0, stream>>>(w1, bns, bnb, bnm, bnv, wk, wv,
                                             w1f, wkt, wvt, bfp);

  bool use_mfma = ws_size >= NEW_END * sizeof(float);
  if (use_mfma) {
    unsigned short* wbtr = (unsigned short*)(ws + OFF_WBT);
    unsigned short* xt   = (unsigned short*)(ws + OFF_XT);
    unsigned short* wvbr = (unsigned short*)(ws + OFF_WVB);
    unsigned short* wxbr = (unsigned short*)(ws + OFF_K);   // reuse freed Kbuf region
    prep_convb_kernel<<<64, 256, 0, stream>>>(w1, w2, w3, w4, bns, bnv, wk, wv,
                                              wbtr, wvbr, wxbr);
    a0_kernel<<<dim3(256, 8), 256, 0, stream>>>(x, xt);
    a2m_kernel<<<dim3(1536), 256, 0, stream>>>(xt, wbtr, bfp, out);
    cm_kernel<<<dim3(64, 8), 256, 0, stream>>>(xt, wvbr, wxbr, bv, bfp, bk, out, part);
  } else {
    float* w24t = ws + OFF_W24T;
    prep_convf_kernel<<<64, 256, 0, stream>>>(w2, w3, w4, bns, bnv, w24t);
    a1_kernel<<<dim3(64, 8), 256, 0, stream>>>(x, w1f, wkt, bfp, bk, out, Kbuf);
    a2f_kernel<<<dim3(32, 8, 3), 256, 0, stream>>>(x, w24t, bfp, out);
    cf_kernel<<<dim3(64, 8), 256, 0, stream>>>(x, bv, Kbuf, wvt, part);
  }
  reduce_kernel<<<dim3(9, 8), 256, 0, stream>>>(part, stat);
  d_kernel<<<dim3(16, 8), 256, 0, stream>>>(stat, wq, bq, gm, out);
}

// Round 8
// 164.907 us; speedup vs baseline: 1.3751x; 1.1196x over previous
//
#include <hip/hip_runtime.h>
#include <hip/hip_bf16.h>
#include <math.h>

#define NPIX   16384
#define BATCH  8
#define BN_EPS 1e-5f
#define EPS_V  1e-6f

typedef __attribute__((ext_vector_type(8))) short bf16x8;
typedef __attribute__((ext_vector_type(4))) float f32x4;

// ---- workspace layout (float offsets) ----
// common
#define OFF_K     ((size_t)0)          // fallback: Kbuf. mfma path: wxbr (reuse)
#define OFF_W1F   ((size_t)2097152)    // 128*32   = 4096
#define OFF_WKT   ((size_t)2101248)    // 128*16   = 2048
#define OFF_WVT   ((size_t)2103296)    // 128*128  = 16384
#define OFF_BF    ((size_t)2119680)    // 4*32     = 128
#define OFF_PART  ((size_t)2119808)    // 512*2192 = 1122304
#define OFF_STATS ((size_t)3242112)    // 8*2192   = 17536
#define BASE_END  ((size_t)3259648)
// new (bf16-MFMA) path extras
#define OFF_WBT   BASE_END             // 3*9*4*2*64*8 ushort = 55296 floats
#define OFF_XT    ((size_t)3314976)    // 8*4*16384*32 ushort = 8388608 floats
#define OFF_WVB   ((size_t)11703584)   // 4*8*64*8 ushort = 8192 floats
#define NEW_END   ((size_t)11711776)
// d1/d2 scratch reuses the xt region (dead after cm; a0 rewrites it every call)
#define OFF_SQ    OFF_XT               // 8*16*16384 = 2097152 floats
#define OFF_TL    ((size_t)(OFF_XT + 2097152))   // 8*16384 = 131072 floats
// old (fp32) fallback extras
#define OFF_W24T  BASE_END             // 3*128*9*32 = 110592

__device__ inline unsigned short f2bf(float f) {
  union { float f; unsigned int u; } v; v.f = f;
  unsigned int r = (v.u + 0x7FFFu + ((v.u >> 16) & 1u)) >> 16;
  return (unsigned short)r;
}

// ---------------- prep_common ----------------
__global__ void prep_common_kernel(const float* __restrict__ w1,
                                   const float* __restrict__ bns, const float* __restrict__ bnb,
                                   const float* __restrict__ bnm, const float* __restrict__ bnv,
                                   const float* __restrict__ wk, const float* __restrict__ wv,
                                   float* __restrict__ w1f, float* __restrict__ wkt,
                                   float* __restrict__ wvt, float* __restrict__ bf) {
  int tid = blockIdx.x * blockDim.x + threadIdx.x;
  int nt  = gridDim.x * blockDim.x;
  for (int i = tid; i < 128; i += nt) {
    float inv = bns[i] * rsqrtf(bnv[i] + BN_EPS);
    bf[i] = bnb[i] - bnm[i] * inv;
  }
  for (int i = tid; i < 4096; i += nt) {          // w1f[c][o]
    int c = i >> 5, o = i & 31;
    float inv = bns[o] * rsqrtf(bnv[o] + BN_EPS);
    w1f[i] = w1[o * 128 + c] * inv;
  }
  for (int i = tid; i < 2048; i += nt) {          // wkt[c][m]
    int c = i >> 4, m = i & 15;
    wkt[i] = wk[m * 128 + c];
  }
  for (int i = tid; i < 16384; i += nt) {         // wvt[c][o]
    int c = i >> 7, o = i & 127;
    wvt[i] = wv[o * 128 + c];
  }
}

// ---------------- prep_convb: MFMA-fragment-ordered bf16 weights ----------------
__global__ void prep_convb_kernel(const float* __restrict__ w1,
                                  const float* __restrict__ w2, const float* __restrict__ w3,
                                  const float* __restrict__ w4,
                                  const float* __restrict__ bns, const float* __restrict__ bnv,
                                  const float* __restrict__ wk, const float* __restrict__ wv,
                                  unsigned short* __restrict__ wbtr,
                                  unsigned short* __restrict__ wvbr,
                                  unsigned short* __restrict__ wxbr) {
  int tid = blockIdx.x * blockDim.x + threadIdx.x;
  int nt  = gridDim.x * blockDim.x;
  for (int i = tid; i < 16384; i += nt) {
    int e = i & 7, lane = (i >> 3) & 63, f = (i >> 9) & 7, q = i >> 12;
    int oc = f * 16 + (lane & 15);
    int c  = q * 32 + (lane >> 4) * 8 + e;
    wvbr[i] = f2bf(wv[oc * 128 + c]);
  }
  for (int i = tid; i < 6144; i += nt) {
    int e = i & 7, lane = (i >> 3) & 63, ct = i >> 9;
    int tile = ct % 3, q = ct / 3;
    int c = q * 32 + (lane >> 4) * 8 + e;
    float val;
    if (tile < 2) {
      int oc = tile * 16 + (lane & 15);
      val = w1[oc * 128 + c] * (bns[oc] * rsqrtf(bnv[oc] + BN_EPS));
    } else {
      val = wk[(lane & 15) * 128 + c];
    }
    wxbr[i] = f2bf(val);
  }
  for (int i = tid; i < 110592; i += nt) {
    int br = i / 36864;
    int r  = i - br * 36864;
    int tap  = r >> 12;
    int r2   = r & 4095;
    int q    = r2 >> 10;
    int r3   = r2 & 1023;
    int pair = r3 >> 9;
    int r4   = r3 & 511;
    int lane = r4 >> 3, e = r4 & 7;
    int oc = pair * 16 + (lane & 15);
    int c  = q * 32 + (lane >> 4) * 8 + e;
    const float* w = (br == 0) ? w2 : ((br == 1) ? w3 : w4);
    int bo = (br + 1) * 32 + oc;
    float inv = bns[bo] * rsqrtf(bnv[bo] + BN_EPS);
    wbtr[i] = f2bf(w[(oc * 128 + c) * 9 + tap] * inv);
  }
}

// ---------------- prep_convf (fallback) ----------------
__global__ void prep_convf_kernel(const float* __restrict__ w2, const float* __restrict__ w3,
                                  const float* __restrict__ w4,
                                  const float* __restrict__ bns, const float* __restrict__ bnv,
                                  float* __restrict__ w24t) {
  int tid = blockIdx.x * blockDim.x + threadIdx.x;
  int nt  = gridDim.x * blockDim.x;
  for (int i = tid; i < 110592; i += nt) {
    int br  = i / 36864;
    int rem = i - br * 36864;
    int c   = rem / 288;
    int k   = (rem % 288) >> 5;
    int o   = rem & 31;
    const float* w = (br == 0) ? w2 : ((br == 1) ? w3 : w4);
    int bo = (br + 1) * 32 + o;
    float inv = bns[bo] * rsqrtf(bnv[bo] + BN_EPS);
    w24t[i] = w[(o * 128 + c) * 9 + k] * inv;
  }
}

// ---------------- a0: transpose x -> xt bf16, quarter-major [b][q][px][32c] ----------------
__global__ __launch_bounds__(256) void a0_kernel(const float* __restrict__ x,
                                                 unsigned short* __restrict__ xt) {
  __shared__ unsigned short Ts[64][132];
  int t   = threadIdx.x;
  int b   = blockIdx.y;
  int px0 = blockIdx.x * 64;
  const float* xb = x + (size_t)b * 128 * NPIX;
  int p = t & 63, cq = t >> 6;
#pragma unroll 8
  for (int i = 0; i < 32; ++i) {
    int c = cq * 32 + i;
    Ts[p][c] = f2bf(xb[(size_t)c * NPIX + px0 + p]);
  }
  __syncthreads();
  int pw = t >> 2, cg = t & 3;   // cg == quarter
  unsigned short* dst = xt + ((size_t)(b * 4 + cg) * 16384 + px0 + pw) * 32;
#pragma unroll
  for (int k = 0; k < 8; ++k) {
    uint2 v = *(const uint2*)(&Ts[pw][cg * 32 + k * 4]);
    *(uint2*)(dst + k * 4) = v;
  }
}

// ---------------- a1 (fallback only) ----------------
__global__ __launch_bounds__(256) void a1_kernel(const float* __restrict__ x,
                                                 const float* __restrict__ w1f,
                                                 const float* __restrict__ wkt,
                                                 const float* __restrict__ bfp,
                                                 const float* __restrict__ bk,
                                                 float* __restrict__ out,
                                                 float* __restrict__ Kbuf) {
  __shared__ float lw1[128 * 32];
  __shared__ float lwk[128 * 16];
  __shared__ float lbf[32];
  int t = threadIdx.x;
  for (int i = t; i < 4096; i += 256) lw1[i] = w1f[i];
  for (int i = t; i < 2048; i += 256) lwk[i] = wkt[i];
  if (t < 32) lbf[t] = bfp[t];
  __syncthreads();

  int b  = blockIdx.y;
  int px = blockIdx.x * 256 + t;
  const float* xb = x + (size_t)b * 128 * NPIX;

  float acc[48];
#pragma unroll
  for (int i = 0; i < 48; ++i) acc[i] = 0.f;

  for (int c = 0; c < 128; ++c) {
    float xv = xb[(size_t)c * NPIX + px];
    const float4* w1p = (const float4*)(lw1 + c * 32);
#pragma unroll
    for (int j = 0; j < 8; ++j) {
      float4 w = w1p[j];
      acc[j*4+0] = fmaf(w.x, xv, acc[j*4+0]);
      acc[j*4+1] = fmaf(w.y, xv, acc[j*4+1]);
      acc[j*4+2] = fmaf(w.z, xv, acc[j*4+2]);
      acc[j*4+3] = fmaf(w.w, xv, acc[j*4+3]);
    }
    const float4* wkp = (const float4*)(lwk + c * 16);
#pragma unroll
    for (int j = 0; j < 4; ++j) {
      float4 w = wkp[j];
      acc[32+j*4+0] = fmaf(w.x, xv, acc[32+j*4+0]);
      acc[32+j*4+1] = fmaf(w.y, xv, acc[32+j*4+1]);
      acc[32+j*4+2] = fmaf(w.z, xv, acc[32+j*4+2]);
      acc[32+j*4+3] = fmaf(w.w, xv, acc[32+j*4+3]);
    }
  }
#pragma unroll
  for (int o = 0; o < 32; ++o)
    out[((size_t)(b * 128 + o)) * NPIX + px] = fmaxf(acc[o] + lbf[o], 0.f);
#pragma unroll
  for (int m = 0; m < 16; ++m)
    Kbuf[((size_t)(b * 16 + m)) * NPIX + px] = acc[32 + m] + bk[m];
}

// ---------------- a2m: LDS-staged conv, MFMA ----------------
__global__ __launch_bounds__(256) void a2m_kernel(const unsigned short* __restrict__ xt,
                                                  const unsigned short* __restrict__ wbtr,
                                                  const float* __restrict__ bfp,
                                                  float* __restrict__ out) {
  __shared__ uint4 sxv[3073];                 // 48KB staged + 16B zero page
  unsigned short* sx = (unsigned short*)sxv;
  int t    = threadIdx.x;
  int wave = t >> 6, lane = t & 63;
  int l15  = lane & 15, cg = lane >> 4;
  int idx  = blockIdx.x;
  int b    = idx & 7;                         // batch -> XCD
  int rest = idx >> 3;
  int h2   = rest & 63;
  int br   = rest >> 6;
  int d    = 6 * (br + 1);
  int h0   = h2 * 2;
  int j    = wave >> 1;                       // row of the pair
  int p0   = (wave & 1) * 64;                 // px half

  if (t == 0) sxv[3072] = make_uint4(0u, 0u, 0u, 0u);   // zero page @ byte 49152

  const unsigned short* wb = wbtr + (size_t)br * 36864;

  f32x4 acc[2][4];
#pragma unroll
  for (int i = 0; i < 2; ++i)
#pragma unroll
    for (int n = 0; n < 4; ++n) acc[i][n] = (f32x4){0.f, 0.f, 0.f, 0.f};

  int pxb[3], xorv[3];
#pragma unroll
  for (int kw = 0; kw < 3; ++kw) {
    pxb[kw]  = p0 + l15 + (kw - 1) * d;
    xorv[kw] = (cg ^ ((pxb[kw] >> 1) & 3)) << 4;
  }

  for (int q = 0; q < 4; ++q) {
    __syncthreads();                            // previous compute done
    const unsigned short* slab = xt + (size_t)(b * 4 + q) * 524288;
    uint4 stv[12];
#pragma unroll
    for (int k = 0; k < 12; ++k) {
      int slot = k >> 1;                                  // kh*2 + jrow
      int srow = h0 + (slot & 1) + ((slot >> 1) - 1) * d;
      int su   = ((k & 1) << 8) + t;                      // 16B unit within slot
      if ((unsigned)srow < 128u)
        stv[k] = *(const uint4*)(slab + (size_t)srow * 4096 + su * 8);
      else
        stv[k] = make_uint4(0u, 0u, 0u, 0u);
    }
#pragma unroll
    for (int k = 0; k < 12; ++k) {
      int slot = k >> 1;
      int su   = ((k & 1) << 8) + t;
      int px   = su >> 2, cgs = su & 3;
      int phys = slot * 4096 + px * 32 + ((cgs ^ ((px >> 1) & 3)) << 3);  // ushort idx
      *(uint4*)(sx + phys) = stv[k];
    }
    __syncthreads();                            // staged visible
#pragma unroll
    for (int kh = 0; kh < 3; ++kh) {
      int slot  = kh * 2 + j;
      int sbase = slot * 8192;                  // byte
      bf16x8 a[3][2];
#pragma unroll
      for (int kw = 0; kw < 3; ++kw) {
        int tap = kh * 3 + kw;
        const unsigned short* wt = wb + ((((size_t)tap * 4 + q) * 2) << 9);
        a[kw][0] = *(const bf16x8*)(wt + lane * 8);
        a[kw][1] = *(const bf16x8*)(wt + 512 + lane * 8);
      }
#pragma unroll
      for (int kw = 0; kw < 3; ++kw) {
        int base = sbase + pxb[kw] * 64 + xorv[kw];
#pragma unroll
        for (int nf = 0; nf < 4; ++nf) {
          int px   = pxb[kw] + nf * 16;
          int addr = ((unsigned)px < 128u) ? (base + nf * 1024) : 49152;
          bf16x8 bv = *(const bf16x8*)((const char*)sx + addr);
          acc[0][nf] = __builtin_amdgcn_mfma_f32_16x16x32_bf16(a[kw][0], bv, acc[0][nf], 0, 0, 0);
          acc[1][nf] = __builtin_amdgcn_mfma_f32_16x16x32_bf16(a[kw][1], bv, acc[1][nf], 0, 0, 0);
        }
      }
    }
  }

  int ocb = (br + 1) * 32;
  int pxw = (h0 + j) * 128 + p0;
#pragma unroll
  for (int mf = 0; mf < 2; ++mf) {
#pragma unroll
    for (int r = 0; r < 4; ++r) {
      int oc = mf * 16 + cg * 4 + r;
      float bias = bfp[ocb + oc];
      float* op = out + ((size_t)(b * 128 + ocb + oc)) * NPIX + pxw + l15;
#pragma unroll
      for (int nf = 0; nf < 4; ++nf)
        op[nf * 16] = fmaxf(acc[mf][nf][r] + bias, 0.f);
    }
  }
}

// ---------------- a2f (fallback) ----------------
__global__ __launch_bounds__(256) void a2f_kernel(const float* __restrict__ x,
                                                  const float* __restrict__ w24t,
                                                  const float* __restrict__ bfp,
                                                  float* __restrict__ out) {
  int t  = threadIdx.x;
  int og = t & 3;
  int pg = (t >> 2) & 15;
  int r  = t >> 6;
  int br = blockIdx.z;
  int b  = blockIdx.y;
  int h  = blockIdx.x * 4 + r;
  int d  = 6 * (br + 1);

  const float* wt = w24t + (size_t)br * 36864;
  const float* bf = bfp + (br + 1) * 32;
  const float* xb = x + (size_t)b * 128 * NPIX;
  int w0 = pg << 3;

  float acc[8][8];
#pragma unroll
  for (int p = 0; p < 8; ++p)
#pragma unroll
    for (int o = 0; o < 8; ++o) acc[p][o] = 0.f;

  for (int c = 0; c < 128; ++c) {
    const float* xc = xb + (size_t)c * NPIX;
    const float* wc = wt + c * 288;
#pragma unroll
    for (int kh = 0; kh < 3; ++kh) {
      int row = h + (kh - 1) * d;
      if ((unsigned)row >= 128u) continue;
      const float* xr = xc + row * 128;
#pragma unroll
      for (int kw = 0; kw < 3; ++kw) {
        int wb = w0 + (kw - 1) * d;
        float xv[8];
        if (wb >= 0 && wb <= 120) {
          const float2* p2 = (const float2*)(xr + wb);
#pragma unroll
          for (int jj = 0; jj < 4; ++jj) {
            float2 v = p2[jj];
            xv[2*jj] = v.x; xv[2*jj+1] = v.y;
          }
        } else {
#pragma unroll
          for (int jj = 0; jj < 8; ++jj) {
            int ww = wb + jj;
            xv[jj] = ((unsigned)ww < 128u) ? xr[ww] : 0.f;
          }
        }
        const float4* wp = (const float4*)(wc + (kh * 3 + kw) * 32 + og * 8);
        float4 wa = wp[0], wbv = wp[1];
        float wr[8] = {wa.x, wa.y, wa.z, wa.w, wbv.x, wbv.y, wbv.z, wbv.w};
#pragma unroll
        for (int p = 0; p < 8; ++p)
#pragma unroll
          for (int o = 0; o < 8; ++o)
            acc[p][o] = fmaf(xv[p], wr[o], acc[p][o]);
      }
    }
  }

  int chbase = (br + 1) * 32 + og * 8;
  int n = h * 128 + w0;
#pragma unroll
  for (int o = 0; o < 8; ++o) {
    float bias = bf[og * 8 + o];
    float* op = out + ((size_t)(b * 128 + chbase + o)) * NPIX + n;
    float4 v0 = make_float4(fmaxf(acc[0][o] + bias, 0.f), fmaxf(acc[1][o] + bias, 0.f),
                            fmaxf(acc[2][o] + bias, 0.f), fmaxf(acc[3][o] + bias, 0.f));
    float4 v1 = make_float4(fmaxf(acc[4][o] + bias, 0.f), fmaxf(acc[5][o] + bias, 0.f),
                            fmaxf(acc[6][o] + bias, 0.f), fmaxf(acc[7][o] + bias, 0.f));
    ((float4*)op)[0] = v0;
    ((float4*)op)[1] = v1;
  }
}

// ---------------- cm v5: fused branch1+K+V, px-half-split to cap VGPR ----------------
__global__ __launch_bounds__(256) void cm_kernel(const unsigned short* __restrict__ xt,
                                                 const unsigned short* __restrict__ wvbr,
                                                 const unsigned short* __restrict__ wxbr,
                                                 const float* __restrict__ bv,
                                                 const float* __restrict__ bfp,
                                                 const float* __restrict__ bk,
                                                 float* __restrict__ out,
                                                 float* __restrict__ part) {
  __shared__ __align__(16) unsigned short Vl[128 * 136];   // bf16 [oc][px]
  __shared__ __align__(16) unsigned short knl[16 * 136];   // bf16 [m][px]
  int t    = threadIdx.x;
  int b    = blockIdx.y;
  int blk  = blockIdx.x;
  int wave = t >> 6, lane = t & 63;
  int l15  = lane & 15, cg = lane >> 4;
  int ocb  = wave * 32;

  float bvr[2][4];
#pragma unroll
  for (int mf = 0; mf < 2; ++mf)
#pragma unroll
    for (int r = 0; r < 4; ++r) bvr[mf][r] = bv[ocb + mf * 16 + cg * 4 + r];

  float xb4[4];
#pragma unroll
  for (int r = 0; r < 4; ++r) xb4[r] = 0.f;
  if (wave == 0) {
#pragma unroll
    for (int r = 0; r < 4; ++r) xb4[r] = bfp[cg * 4 + r];
  } else if (wave == 1) {
#pragma unroll
    for (int r = 0; r < 4; ++r) xb4[r] = bfp[16 + cg * 4 + r];
  } else if (wave == 2) {
#pragma unroll
    for (int r = 0; r < 4; ++r) xb4[r] = bk[cg * 4 + r];
  }
  int xwave = (wave < 3) ? wave : 0;

  float kr[4] = {0.f, 0.f, 0.f, 0.f};
  float sv[2][4];
#pragma unroll
  for (int mf = 0; mf < 2; ++mf)
#pragma unroll
    for (int r = 0; r < 4; ++r) sv[mf][r] = 0.f;
  f32x4 am[2];
  am[0] = (f32x4){0.f,0.f,0.f,0.f};
  am[1] = (f32x4){0.f,0.f,0.f,0.f};

  for (int tile = blk; tile < 128; tile += 64) {
    __syncthreads();
    int pbase = tile << 7;

#pragma unroll
    for (int hf = 0; hf < 2; ++hf) {
      f32x4 vacc[2][4];
      f32x4 xacc[4];
#pragma unroll
      for (int i = 0; i < 2; ++i)
#pragma unroll
        for (int n = 0; n < 4; ++n) vacc[i][n] = (f32x4){0.f,0.f,0.f,0.f};
#pragma unroll
      for (int n = 0; n < 4; ++n) xacc[n] = (f32x4){0.f,0.f,0.f,0.f};

#pragma unroll
      for (int cc = 0; cc < 4; ++cc) {
        const unsigned short* xq = xt + ((size_t)(b * 4 + cc) * 16384 + pbase) * 32;
        bf16x8 a0 = *(const bf16x8*)(wvbr + ((cc * 8 + wave * 2 + 0) << 9) + lane * 8);
        bf16x8 a1 = *(const bf16x8*)(wvbr + ((cc * 8 + wave * 2 + 1) << 9) + lane * 8);
        bf16x8 ax = *(const bf16x8*)(wxbr + ((cc * 3 + xwave) << 9) + lane * 8);
#pragma unroll
        for (int nf = 0; nf < 4; ++nf) {
          int nfg = hf * 4 + nf;
          bf16x8 bx = *(const bf16x8*)(xq + (size_t)(nfg * 16 + l15) * 32 + cg * 8);
          vacc[0][nf] = __builtin_amdgcn_mfma_f32_16x16x32_bf16(a0, bx, vacc[0][nf], 0, 0, 0);
          vacc[1][nf] = __builtin_amdgcn_mfma_f32_16x16x32_bf16(a1, bx, vacc[1][nf], 0, 0, 0);
          if (wave < 3)
            xacc[nf] = __builtin_amdgcn_mfma_f32_16x16x32_bf16(ax, bx, xacc[nf], 0, 0, 0);
        }
      }

#pragma unroll
      for (int mf = 0; mf < 2; ++mf) {
#pragma unroll
        for (int r = 0; r < 4; ++r) {
          float s = 0.f;
#pragma unroll
          for (int nf = 0; nf < 4; ++nf) s += vacc[mf][nf][r];
          sv[mf][r] += s;
          int c = ocb + mf * 16 + cg * 4 + r;
#pragma unroll
          for (int nf = 0; nf < 4; ++nf)
            Vl[c * 136 + (hf * 4 + nf) * 16 + l15] = f2bf(vacc[mf][nf][r] + bvr[mf][r]);
        }
      }

      if (wave < 2) {
#pragma unroll
        for (int r = 0; r < 4; ++r) {
          int oc = wave * 16 + cg * 4 + r;
          float* op = out + ((size_t)(b * 128 + oc)) * NPIX + pbase + l15;
#pragma unroll
          for (int nf = 0; nf < 4; ++nf)
            op[(hf * 4 + nf) * 16] = fmaxf(xacc[nf][r] + xb4[r], 0.f);
        }
      } else if (wave == 2) {
#pragma unroll
        for (int nf = 0; nf < 4; ++nf) {
          int nfg = hf * 4 + nf;
          float kq[4]; float s2 = 0.f;
#pragma unroll
          for (int r = 0; r < 4; ++r) {
            kq[r] = xacc[nf][r] + xb4[r];
            s2 = fmaf(kq[r], kq[r], s2);
          }
          s2 += __shfl_xor(s2, 16);
          s2 += __shfl_xor(s2, 32);
          float inv = rsqrtf(s2);
#pragma unroll
          for (int r = 0; r < 4; ++r) {
            float kn = kq[r] * inv;
            knl[(cg * 4 + r) * 136 + nfg * 16 + l15] = f2bf(kn);
            kr[r] += kn;
          }
        }
      }
    }
    __syncthreads();

#pragma unroll
    for (int ks = 0; ks < 4; ++ks) {
      bf16x8 af = *(const bf16x8*)(knl + l15 * 136 + ks * 32 + cg * 8);
      bf16x8 b0 = *(const bf16x8*)(Vl + (size_t)(ocb + l15) * 136 + ks * 32 + cg * 8);
      bf16x8 b1 = *(const bf16x8*)(Vl + (size_t)(ocb + 16 + l15) * 136 + ks * 32 + cg * 8);
      am[0] = __builtin_amdgcn_mfma_f32_16x16x32_bf16(af, b0, am[0], 0, 0, 0);
      am[1] = __builtin_amdgcn_mfma_f32_16x16x32_bf16(af, b1, am[1], 0, 0, 0);
    }
  }

  int blkid = b * 64 + blk;
  float* pp = part + (size_t)blkid * 2192;
#pragma unroll
  for (int nf2 = 0; nf2 < 2; ++nf2)
#pragma unroll
    for (int r = 0; r < 4; ++r)
      pp[(cg * 4 + r) * 128 + ocb + nf2 * 16 + l15] = am[nf2][r];
#pragma unroll
  for (int off = 1; off < 16; off <<= 1) {
#pragma unroll
    for (int mf = 0; mf < 2; ++mf)
#pragma unroll
      for (int r = 0; r < 4; ++r)
        sv[mf][r] += __shfl_xor(sv[mf][r], off);
  }
  if (l15 == 0) {
#pragma unroll
    for (int mf = 0; mf < 2; ++mf)
#pragma unroll
      for (int r = 0; r < 4; ++r) {
        int c = ocb + mf * 16 + cg * 4 + r;
        pp[2048 + c] = sv[mf][r] + 256.f * bv[c];
      }
  }
  if (wave == 2) {
#pragma unroll
    for (int off = 1; off < 16; off <<= 1) {
#pragma unroll
      for (int r = 0; r < 4; ++r)
        kr[r] += __shfl_xor(kr[r], off);
    }
    if (l15 == 0) {
#pragma unroll
      for (int r = 0; r < 4; ++r)
        pp[2048 + 128 + cg * 4 + r] = kr[r];
    }
  }
}

// ---------------- cf (fallback) ----------------
__global__ __launch_bounds__(256) void cf_kernel(const float* __restrict__ x,
                                                 const float* __restrict__ bv,
                                                 const float* __restrict__ Kbuf,
                                                 const float* __restrict__ wvt,
                                                 float* __restrict__ part) {
  __shared__ float Vl[128 * 129];
  __shared__ float knl[16 * 132];
  int t   = threadIdx.x;
  int b   = blockIdx.y;
  int blk = blockIdx.x;
  const float* Kb = Kbuf + (size_t)b * 16 * NPIX;
  const float* xb = x + (size_t)b * 128 * NPIX;

  int m_own = t & 15;
  int c0    = (t >> 4) << 3;
  int pxg   = t & 15;

  float bvr[8];
#pragma unroll
  for (int jj = 0; jj < 8; ++jj) bvr[jj] = bv[c0 + jj];

  float macc[8] = {0,0,0,0,0,0,0,0};
  float vs[8]   = {0,0,0,0,0,0,0,0};
  float ksum[16];
#pragma unroll
  for (int m = 0; m < 16; ++m) ksum[m] = 0.f;

  for (int tile = blk; tile < 128; tile += 64) {
    __syncthreads();
    int pbase = tile << 7;

    if (t < 128) {
      float kv[16]; float ss = 0.f;
#pragma unroll
      for (int m = 0; m < 16; ++m) {
        kv[m] = Kb[(size_t)m * NPIX + pbase + t];
        ss = fmaf(kv[m], kv[m], ss);
      }
      float inv = rsqrtf(ss);
#pragma unroll
      for (int m = 0; m < 16; ++m) {
        float kn = kv[m] * inv;
        knl[m * 132 + t] = kn;
        ksum[m] += kn;
      }
    }

    float v[8][8];
#pragma unroll
    for (int i = 0; i < 8; ++i)
#pragma unroll
      for (int jj = 0; jj < 8; ++jj) v[i][jj] = 0.f;
    int px0 = pbase + (pxg << 3);
    for (int k = 0; k < 128; ++k) {
      const float4* xp = (const float4*)(xb + (size_t)k * NPIX + px0);
      float4 xa = xp[0], xc4 = xp[1];
      const float4* wp = (const float4*)(wvt + k * 128 + c0);
      float4 wa = wp[0], wc4 = wp[1];
      float xv[8] = {xa.x, xa.y, xa.z, xa.w, xc4.x, xc4.y, xc4.z, xc4.w};
      float wr[8] = {wa.x, wa.y, wa.z, wa.w, wc4.x, wc4.y, wc4.z, wc4.w};
#pragma unroll
      for (int i = 0; i < 8; ++i)
#pragma unroll
        for (int jj = 0; jj < 8; ++jj)
          v[i][jj] = fmaf(wr[i], xv[jj], v[i][jj]);
    }
#pragma unroll
    for (int i = 0; i < 8; ++i)
#pragma unroll
      for (int jj = 0; jj < 8; ++jj)
        Vl[(c0 + i) * 129 + (pxg << 3) + jj] = v[i][jj] + bvr[i];
    __syncthreads();

    for (int px = 0; px < 128; ++px) {
      float knv = knl[m_own * 132 + px];
      float vv[8];
#pragma unroll
      for (int jj = 0; jj < 8; ++jj) vv[jj] = Vl[(c0 + jj) * 129 + px];
#pragma unroll
      for (int jj = 0; jj < 8; ++jj) macc[jj] = fmaf(knv, vv[jj], macc[jj]);
      if (m_own == 0) {
#pragma unroll
        for (int jj = 0; jj < 8; ++jj) vs[jj] += vv[jj];
      }
    }
  }

  int blkid = b * 64 + blk;
  float* pp = part + (size_t)blkid * 2192;
#pragma unroll
  for (int jj = 0; jj < 8; ++jj) pp[m_own * 128 + c0 + jj] = macc[jj];
  if (m_own == 0) {
#pragma unroll
    for (int jj = 0; jj < 8; ++jj) pp[2048 + c0 + jj] = vs[jj];
  }
  __syncthreads();
  if (t < 128) {
#pragma unroll
    for (int m = 0; m < 16; ++m) knl[m * 132 + t] = ksum[m];
  }
  __syncthreads();
  if (t < 16) {
    float s = 0.f;
    for (int i = 0; i < 128; ++i) s += knl[t * 132 + i];
    pp[2048 + 128 + t] = s;
  }
}

// ---------------- reduce: 72 blocks (9 chunks x 8 batches) ----------------
__global__ void reduce_kernel(const float* __restrict__ part, float* __restrict__ stats) {
  int b = blockIdx.y, t = threadIdx.x;
  int e = blockIdx.x * 256 + t;
  if (e >= 2192) return;
  const float* pp = part + (size_t)b * 64 * 2192;
  float s = 0.f;
  for (int g = 0; g < 64; ++g) s += pp[(size_t)g * 2192 + e];
  stats[(size_t)b * 2192 + e] = s;
}

// ---------------- d1: Q + tailor per pixel -> sq[16], tl ----------------
__global__ __launch_bounds__(256) void d1_kernel(const float* __restrict__ stats,
                                                 const float* __restrict__ wq,
                                                 const float* __restrict__ bq,
                                                 const float* __restrict__ gamma,
                                                 const float* __restrict__ out,
                                                 float* __restrict__ sq,
                                                 float* __restrict__ tlb) {
  __shared__ float wql[128 * 16];   // [c][m]
  __shared__ float ksl[16];
  int t = threadIdx.x;
  int b = blockIdx.y;
  const float* st = stats + (size_t)b * 2192;
  for (int i = t; i < 2048; i += 256) {
    int m = i >> 7, c = i & 127;
    wql[c * 16 + m] = wq[m * 128 + c];
  }
  if (t < 16) ksl[t] = st[2048 + 128 + t] + EPS_V;
  __syncthreads();

  int px = blockIdx.x * 256 + t;
  const float* ob = out + (size_t)b * 128 * NPIX;

  float q[16];
#pragma unroll
  for (int m = 0; m < 16; ++m) q[m] = bq[m];
  for (int c = 0; c < 128; ++c) {
    float xv = ob[(size_t)c * NPIX + px];
    const float4* wp = (const float4*)(wql + c * 16);
#pragma unroll
    for (int jj = 0; jj < 4; ++jj) {
      float4 w = wp[jj];
      q[jj*4+0] = fmaf(w.x, xv, q[jj*4+0]);
      q[jj*4+1] = fmaf(w.y, xv, q[jj*4+1]);
      q[jj*4+2] = fmaf(w.z, xv, q[jj*4+2]);
      q[jj*4+3] = fmaf(w.w, xv, q[jj*4+3]);
    }
  }
  float ss = 0.f;
#pragma unroll
  for (int m = 0; m < 16; ++m) ss = fmaf(q[m], q[m], ss);
  float inv = rsqrtf(ss);
#pragma unroll
  for (int m = 0; m < 16; ++m) q[m] *= inv;
  float den = (float)NPIX;
#pragma unroll
  for (int m = 0; m < 16; ++m) den = fmaf(q[m], ksl[m], den);
  float tl = gamma[0] / den;

  tlb[(size_t)b * NPIX + px] = tl;
#pragma unroll
  for (int m = 0; m < 16; ++m)
    sq[((size_t)(b * 16 + m)) * NPIX + px] = tl * q[m];
}

// ---------------- d2: out[c][px] = vsl[c]*tl + mat[m][c]*sq[m] ----------------
__global__ __launch_bounds__(256) void d2_kernel(const float* __restrict__ stats,
                                                 const float* __restrict__ sq,
                                                 const float* __restrict__ tlb,
                                                 float* __restrict__ out) {
  __shared__ float matl[128 * 16];  // [c][m]
  __shared__ float vsl[128];
  int t = threadIdx.x;
  int b = blockIdx.y;
  const float* st = stats + (size_t)b * 2192;
  for (int i = t; i < 2048; i += 256) {
    int m = i >> 7, c = i & 127;
    matl[c * 16 + m] = st[i];
  }
  if (t < 128) vsl[t] = st[2048 + t];
  __syncthreads();

  int px = blockIdx.x * 256 + t;
  float* ob = out + (size_t)b * 128 * NPIX;

  float tlv = tlb[(size_t)b * NPIX + px];
  float sv[16];
#pragma unroll
  for (int m = 0; m < 16; ++m)
    sv[m] = sq[((size_t)(b * 16 + m)) * NPIX + px];

  for (int c = 0; c < 128; ++c) {
    float s = vsl[c] * tlv;
    const float4* mp = (const float4*)(matl + c * 16);
#pragma unroll
    for (int jj = 0; jj < 4; ++jj) {
      float4 w = mp[jj];
      s = fmaf(w.x, sv[jj*4+0], s);
      s = fmaf(w.y, sv[jj*4+1], s);
      s = fmaf(w.z, sv[jj*4+2], s);
      s = fmaf(w.w, sv[jj*4+3], s);
    }
    ob[(size_t)c * NPIX + px] = s;
  }
}

// ---------------- df (fallback final) ----------------
__global__ __launch_bounds__(256) void df_kernel(const float* __restrict__ stats,
                                                 const float* __restrict__ wq,
                                                 const float* __restrict__ bq,
                                                 const float* __restrict__ gamma,
                                                 float* __restrict__ out) {
  __shared__ float matl[128 * 16];
  __shared__ float wql[128 * 16];
  __shared__ float vsl[128];
  __shared__ float ksl[16];
  int t = threadIdx.x;
  int b = blockIdx.y;
  const float* st = stats + (size_t)b * 2192;
  for (int i = t; i < 2048; i += 256) {
    int m = i >> 7, c = i & 127;
    matl[c * 16 + m] = st[i];
    wql[c * 16 + m]  = wq[m * 128 + c];
  }
  if (t < 128) vsl[t] = st[2048 + t];
  if (t < 16)  ksl[t] = st[2048 + 128 + t] + EPS_V;
  __syncthreads();

  int px = blockIdx.x * 256 + t;
  float* ob = out + (size_t)b * 128 * NPIX;

  float q[16];
#pragma unroll
  for (int m = 0; m < 16; ++m) q[m] = bq[m];
  for (int c = 0; c < 128; ++c) {
    float xv = ob[(size_t)c * NPIX + px];
    const float4* wp = (const float4*)(wql + c * 16);
#pragma unroll
    for (int jj = 0; jj < 4; ++jj) {
      float4 w = wp[jj];
      q[jj*4+0] = fmaf(w.x, xv, q[jj*4+0]);
      q[jj*4+1] = fmaf(w.y, xv, q[jj*4+1]);
      q[jj*4+2] = fmaf(w.z, xv, q[jj*4+2]);
      q[jj*4+3] = fmaf(w.w, xv, q[jj*4+3]);
    }
  }
  float ss = 0.f;
#pragma unroll
  for (int m = 0; m < 16; ++m) ss = fmaf(q[m], q[m], ss);
  float inv = rsqrtf(ss);
#pragma unroll
  for (int m = 0; m < 16; ++m) q[m] *= inv;
  float den = (float)NPIX;
#pragma unroll
  for (int m = 0; m < 16; ++m) den = fmaf(q[m], ksl[m], den);
  float tl = gamma[0] / den;

  for (int c = 0; c < 128; ++c) {
    float s = vsl[c];
    const float4* mp = (const float4*)(matl + c * 16);
#pragma unroll
    for (int jj = 0; jj < 4; ++jj) {
      float4 w = mp[jj];
      s = fmaf(w.x, q[jj*4+0], s);
      s = fmaf(w.y, q[jj*4+1], s);
      s = fmaf(w.z, q[jj*4+2], s);
      s = fmaf(w.w, q[jj*4+3], s);
    }
    ob[(size_t)c * NPIX + px] = tl * s;
  }
}

extern "C" void kernel_launch(void* const* d_in, const int* in_sizes, int n_in,
                              void* d_out, int out_size, void* d_ws, size_t ws_size,
                              hipStream_t stream) {
  (void)in_sizes; (void)n_in; (void)out_size;
  const float* x   = (const float*)d_in[0];
  const float* w1  = (const float*)d_in[1];
  const float* w2  = (const float*)d_in[2];
  const float* w3  = (const float*)d_in[3];
  const float* w4  = (const float*)d_in[4];
  const float* bns = (const float*)d_in[5];
  const float* bnb = (const float*)d_in[6];
  const float* bnm = (const float*)d_in[7];
  const float* bnv = (const float*)d_in[8];
  const float* wq  = (const float*)d_in[9];
  const float* bq  = (const float*)d_in[10];
  const float* wk  = (const float*)d_in[11];
  const float* bk  = (const float*)d_in[12];
  const float* wv  = (const float*)d_in[13];
  const float* bv  = (const float*)d_in[14];
  const float* gm  = (const float*)d_in[15];
  float* ws  = (float*)d_ws;
  float* out = (float*)d_out;

  float* Kbuf = ws + OFF_K;
  float* w1f  = ws + OFF_W1F;
  float* wkt  = ws + OFF_WKT;
  float* wvt  = ws + OFF_WVT;
  float* bfp  = ws + OFF_BF;
  float* part = ws + OFF_PART;
  float* stat = ws + OFF_STATS;

  prep_common_kernel<<<64, 256, 0, stream>>>(w1, bns, bnb, bnm, bnv, wk, wv,
                                             w1f, wkt, wvt, bfp);

  bool use_mfma = ws_size >= NEW_END * sizeof(float);
  if (use_mfma) {
    unsigned short* wbtr = (unsigned short*)(ws + OFF_WBT);
    unsigned short* xt   = (unsigned short*)(ws + OFF_XT);
    unsigned short* wvbr = (unsigned short*)(ws + OFF_WVB);
    unsigned short* wxbr = (unsigned short*)(ws + OFF_K);   // reuse freed Kbuf region
    float* sq  = ws + OFF_SQ;   // reuses xt region (dead after cm)
    float* tlb = ws + OFF_TL;
    prep_convb_kernel<<<64, 256, 0, stream>>>(w1, w2, w3, w4, bns, bnv, wk, wv,
                                              wbtr, wvbr, wxbr);
    a0_kernel<<<dim3(256, 8), 256, 0, stream>>>(x, xt);
    a2m_kernel<<<dim3(1536), 256, 0, stream>>>(xt, wbtr, bfp, out);
    cm_kernel<<<dim3(64, 8), 256, 0, stream>>>(xt, wvbr, wxbr, bv, bfp, bk, out, part);
    reduce_kernel<<<dim3(9, 8), 256, 0, stream>>>(part, stat);
    d1_kernel<<<dim3(64, 8), 256, 0, stream>>>(stat, wq, bq, gm, out, sq, tlb);
    d2_kernel<<<dim3(64, 8), 256, 0, stream>>>(stat, sq, tlb, out);
  } else {
    float* w24t = ws + OFF_W24T;
    prep_convf_kernel<<<64, 256, 0, stream>>>(w2, w3, w4, bns, bnv, w24t);
    a1_kernel<<<dim3(64, 8), 256, 0, stream>>>(x, w1f, wkt, bfp, bk, out, Kbuf);
    a2f_kernel<<<dim3(32, 8, 3), 256, 0, stream>>>(x, w24t, bfp, out);
    cf_kernel<<<dim3(64, 8), 256, 0, stream>>>(x, bv, Kbuf, wvt, part);
    reduce_kernel<<<dim3(9, 8), 256, 0, stream>>>(part, stat);
    df_kernel<<<dim3(64, 8), 256, 0, stream>>>(stat, wq, bq, gm, out);
  }
}

// Round 9
// 147.986 us; speedup vs baseline: 1.5324x; 1.1143x over previous
//
#include <hip/hip_runtime.h>
#include <hip/hip_bf16.h>
#include <math.h>

#define NPIX   16384
#define BATCH  8
#define BN_EPS 1e-5f
#define EPS_V  1e-6f

typedef __attribute__((ext_vector_type(8))) short bf16x8;
typedef __attribute__((ext_vector_type(4))) float f32x4;

// ---- workspace layout (float offsets) ----
// common
#define OFF_K     ((size_t)0)          // fallback: Kbuf. mfma path: wxbr + part2
#define OFF_PART2 ((size_t)8192)       // mfma: 512*2192 = 1122304 (ends 1130496 < 2097152)
#define OFF_W1F   ((size_t)2097152)    // 128*32   = 4096
#define OFF_WKT   ((size_t)2101248)    // 128*16   = 2048
#define OFF_WVT   ((size_t)2103296)    // 128*128  = 16384
#define OFF_BF    ((size_t)2119680)    // 4*32     = 128
#define OFF_PART  ((size_t)2119808)    // 512*2192 = 1122304
#define OFF_STATS ((size_t)3242112)    // 8*2192   = 17536
#define BASE_END  ((size_t)3259648)
// new (bf16-MFMA) path extras
#define OFF_WBT   BASE_END             // 3*9*4*2*64*8 ushort = 55296 floats
#define OFF_XT    ((size_t)3314976)    // 8*4*16384*32 ushort = 8388608 floats
#define OFF_WVB   ((size_t)11703584)   // 4*8*64*8 ushort = 8192 floats
#define NEW_END   ((size_t)11711776)
// d1/d2 scratch reuses the xt region (dead after cm; a0 rewrites it every call)
#define OFF_SQ    OFF_XT               // 8*16*16384 = 2097152 floats
#define OFF_TL    ((size_t)(OFF_XT + 2097152))   // 8*16384 = 131072 floats
// old (fp32) fallback extras
#define OFF_W24T  BASE_END             // 3*128*9*32 = 110592

__device__ inline unsigned short f2bf(float f) {
  union { float f; unsigned int u; } v; v.f = f;
  unsigned int r = (v.u + 0x7FFFu + ((v.u >> 16) & 1u)) >> 16;
  return (unsigned short)r;
}

// ---------------- prep_common ----------------
__global__ void prep_common_kernel(const float* __restrict__ w1,
                                   const float* __restrict__ bns, const float* __restrict__ bnb,
                                   const float* __restrict__ bnm, const float* __restrict__ bnv,
                                   const float* __restrict__ wk, const float* __restrict__ wv,
                                   float* __restrict__ w1f, float* __restrict__ wkt,
                                   float* __restrict__ wvt, float* __restrict__ bf) {
  int tid = blockIdx.x * blockDim.x + threadIdx.x;
  int nt  = gridDim.x * blockDim.x;
  for (int i = tid; i < 128; i += nt) {
    float inv = bns[i] * rsqrtf(bnv[i] + BN_EPS);
    bf[i] = bnb[i] - bnm[i] * inv;
  }
  for (int i = tid; i < 4096; i += nt) {          // w1f[c][o]
    int c = i >> 5, o = i & 31;
    float inv = bns[o] * rsqrtf(bnv[o] + BN_EPS);
    w1f[i] = w1[o * 128 + c] * inv;
  }
  for (int i = tid; i < 2048; i += nt) {          // wkt[c][m]
    int c = i >> 4, m = i & 15;
    wkt[i] = wk[m * 128 + c];
  }
  for (int i = tid; i < 16384; i += nt) {         // wvt[c][o]
    int c = i >> 7, o = i & 127;
    wvt[i] = wv[o * 128 + c];
  }
}

// ---------------- prep_convb: MFMA-fragment-ordered bf16 weights ----------------
__global__ void prep_convb_kernel(const float* __restrict__ w1,
                                  const float* __restrict__ w2, const float* __restrict__ w3,
                                  const float* __restrict__ w4,
                                  const float* __restrict__ bns, const float* __restrict__ bnv,
                                  const float* __restrict__ wk, const float* __restrict__ wv,
                                  unsigned short* __restrict__ wbtr,
                                  unsigned short* __restrict__ wvbr,
                                  unsigned short* __restrict__ wxbr) {
  int tid = blockIdx.x * blockDim.x + threadIdx.x;
  int nt  = gridDim.x * blockDim.x;
  for (int i = tid; i < 16384; i += nt) {
    int e = i & 7, lane = (i >> 3) & 63, f = (i >> 9) & 7, q = i >> 12;
    int oc = f * 16 + (lane & 15);
    int c  = q * 32 + (lane >> 4) * 8 + e;
    wvbr[i] = f2bf(wv[oc * 128 + c]);
  }
  for (int i = tid; i < 6144; i += nt) {
    int e = i & 7, lane = (i >> 3) & 63, ct = i >> 9;
    int tile = ct % 3, q = ct / 3;
    int c = q * 32 + (lane >> 4) * 8 + e;
    float val;
    if (tile < 2) {
      int oc = tile * 16 + (lane & 15);
      val = w1[oc * 128 + c] * (bns[oc] * rsqrtf(bnv[oc] + BN_EPS));
    } else {
      val = wk[(lane & 15) * 128 + c];
    }
    wxbr[i] = f2bf(val);
  }
  for (int i = tid; i < 110592; i += nt) {
    int br = i / 36864;
    int r  = i - br * 36864;
    int tap  = r >> 12;
    int r2   = r & 4095;
    int q    = r2 >> 10;
    int r3   = r2 & 1023;
    int pair = r3 >> 9;
    int r4   = r3 & 511;
    int lane = r4 >> 3, e = r4 & 7;
    int oc = pair * 16 + (lane & 15);
    int c  = q * 32 + (lane >> 4) * 8 + e;
    const float* w = (br == 0) ? w2 : ((br == 1) ? w3 : w4);
    int bo = (br + 1) * 32 + oc;
    float inv = bns[bo] * rsqrtf(bnv[bo] + BN_EPS);
    wbtr[i] = f2bf(w[(oc * 128 + c) * 9 + tap] * inv);
  }
}

// ---------------- prep_convf (fallback) ----------------
__global__ void prep_convf_kernel(const float* __restrict__ w2, const float* __restrict__ w3,
                                  const float* __restrict__ w4,
                                  const float* __restrict__ bns, const float* __restrict__ bnv,
                                  float* __restrict__ w24t) {
  int tid = blockIdx.x * blockDim.x + threadIdx.x;
  int nt  = gridDim.x * blockDim.x;
  for (int i = tid; i < 110592; i += nt) {
    int br  = i / 36864;
    int rem = i - br * 36864;
    int c   = rem / 288;
    int k   = (rem % 288) >> 5;
    int o   = rem & 31;
    const float* w = (br == 0) ? w2 : ((br == 1) ? w3 : w4);
    int bo = (br + 1) * 32 + o;
    float inv = bns[bo] * rsqrtf(bnv[bo] + BN_EPS);
    w24t[i] = w[(o * 128 + c) * 9 + k] * inv;
  }
}

// ---------------- a0: transpose x -> xt bf16, quarter-major [b][q][px][32c] ----------------
__global__ __launch_bounds__(256) void a0_kernel(const float* __restrict__ x,
                                                 unsigned short* __restrict__ xt) {
  __shared__ unsigned short Ts[64][132];
  int t   = threadIdx.x;
  int b   = blockIdx.y;
  int px0 = blockIdx.x * 64;
  const float* xb = x + (size_t)b * 128 * NPIX;
  int p = t & 63, cq = t >> 6;
#pragma unroll 8
  for (int i = 0; i < 32; ++i) {
    int c = cq * 32 + i;
    Ts[p][c] = f2bf(xb[(size_t)c * NPIX + px0 + p]);
  }
  __syncthreads();
  int pw = t >> 2, cg = t & 3;   // cg == quarter
  unsigned short* dst = xt + ((size_t)(b * 4 + cg) * 16384 + px0 + pw) * 32;
#pragma unroll
  for (int k = 0; k < 8; ++k) {
    uint2 v = *(const uint2*)(&Ts[pw][cg * 32 + k * 4]);
    *(uint2*)(dst + k * 4) = v;
  }
}

// ---------------- a1 (fallback only) ----------------
__global__ __launch_bounds__(256) void a1_kernel(const float* __restrict__ x,
                                                 const float* __restrict__ w1f,
                                                 const float* __restrict__ wkt,
                                                 const float* __restrict__ bfp,
                                                 const float* __restrict__ bk,
                                                 float* __restrict__ out,
                                                 float* __restrict__ Kbuf) {
  __shared__ float lw1[128 * 32];
  __shared__ float lwk[128 * 16];
  __shared__ float lbf[32];
  int t = threadIdx.x;
  for (int i = t; i < 4096; i += 256) lw1[i] = w1f[i];
  for (int i = t; i < 2048; i += 256) lwk[i] = wkt[i];
  if (t < 32) lbf[t] = bfp[t];
  __syncthreads();

  int b  = blockIdx.y;
  int px = blockIdx.x * 256 + t;
  const float* xb = x + (size_t)b * 128 * NPIX;

  float acc[48];
#pragma unroll
  for (int i = 0; i < 48; ++i) acc[i] = 0.f;

  for (int c = 0; c < 128; ++c) {
    float xv = xb[(size_t)c * NPIX + px];
    const float4* w1p = (const float4*)(lw1 + c * 32);
#pragma unroll
    for (int j = 0; j < 8; ++j) {
      float4 w = w1p[j];
      acc[j*4+0] = fmaf(w.x, xv, acc[j*4+0]);
      acc[j*4+1] = fmaf(w.y, xv, acc[j*4+1]);
      acc[j*4+2] = fmaf(w.z, xv, acc[j*4+2]);
      acc[j*4+3] = fmaf(w.w, xv, acc[j*4+3]);
    }
    const float4* wkp = (const float4*)(lwk + c * 16);
#pragma unroll
    for (int j = 0; j < 4; ++j) {
      float4 w = wkp[j];
      acc[32+j*4+0] = fmaf(w.x, xv, acc[32+j*4+0]);
      acc[32+j*4+1] = fmaf(w.y, xv, acc[32+j*4+1]);
      acc[32+j*4+2] = fmaf(w.z, xv, acc[32+j*4+2]);
      acc[32+j*4+3] = fmaf(w.w, xv, acc[32+j*4+3]);
    }
  }
#pragma unroll
  for (int o = 0; o < 32; ++o)
    out[((size_t)(b * 128 + o)) * NPIX + px] = fmaxf(acc[o] + lbf[o], 0.f);
#pragma unroll
  for (int m = 0; m < 16; ++m)
    Kbuf[((size_t)(b * 16 + m)) * NPIX + px] = acc[32 + m] + bk[m];
}

// ---------------- a2m: LDS-staged conv, MFMA ----------------
__global__ __launch_bounds__(256) void a2m_kernel(const unsigned short* __restrict__ xt,
                                                  const unsigned short* __restrict__ wbtr,
                                                  const float* __restrict__ bfp,
                                                  float* __restrict__ out) {
  __shared__ uint4 sxv[3073];                 // 48KB staged + 16B zero page
  unsigned short* sx = (unsigned short*)sxv;
  int t    = threadIdx.x;
  int wave = t >> 6, lane = t & 63;
  int l15  = lane & 15, cg = lane >> 4;
  int idx  = blockIdx.x;
  int b    = idx & 7;                         // batch -> XCD
  int rest = idx >> 3;
  int h2   = rest & 63;
  int br   = rest >> 6;
  int d    = 6 * (br + 1);
  int h0   = h2 * 2;
  int j    = wave >> 1;                       // row of the pair
  int p0   = (wave & 1) * 64;                 // px half

  if (t == 0) sxv[3072] = make_uint4(0u, 0u, 0u, 0u);   // zero page @ byte 49152

  const unsigned short* wb = wbtr + (size_t)br * 36864;

  f32x4 acc[2][4];
#pragma unroll
  for (int i = 0; i < 2; ++i)
#pragma unroll
    for (int n = 0; n < 4; ++n) acc[i][n] = (f32x4){0.f, 0.f, 0.f, 0.f};

  int pxb[3], xorv[3];
#pragma unroll
  for (int kw = 0; kw < 3; ++kw) {
    pxb[kw]  = p0 + l15 + (kw - 1) * d;
    xorv[kw] = (cg ^ ((pxb[kw] >> 1) & 3)) << 4;
  }

  for (int q = 0; q < 4; ++q) {
    __syncthreads();                            // previous compute done
    const unsigned short* slab = xt + (size_t)(b * 4 + q) * 524288;
    uint4 stv[12];
#pragma unroll
    for (int k = 0; k < 12; ++k) {
      int slot = k >> 1;                                  // kh*2 + jrow
      int srow = h0 + (slot & 1) + ((slot >> 1) - 1) * d;
      int su   = ((k & 1) << 8) + t;                      // 16B unit within slot
      if ((unsigned)srow < 128u)
        stv[k] = *(const uint4*)(slab + (size_t)srow * 4096 + su * 8);
      else
        stv[k] = make_uint4(0u, 0u, 0u, 0u);
    }
#pragma unroll
    for (int k = 0; k < 12; ++k) {
      int slot = k >> 1;
      int su   = ((k & 1) << 8) + t;
      int px   = su >> 2, cgs = su & 3;
      int phys = slot * 4096 + px * 32 + ((cgs ^ ((px >> 1) & 3)) << 3);  // ushort idx
      *(uint4*)(sx + phys) = stv[k];
    }
    __syncthreads();                            // staged visible
#pragma unroll
    for (int kh = 0; kh < 3; ++kh) {
      int slot  = kh * 2 + j;
      int sbase = slot * 8192;                  // byte
      bf16x8 a[3][2];
#pragma unroll
      for (int kw = 0; kw < 3; ++kw) {
        int tap = kh * 3 + kw;
        const unsigned short* wt = wb + ((((size_t)tap * 4 + q) * 2) << 9);
        a[kw][0] = *(const bf16x8*)(wt + lane * 8);
        a[kw][1] = *(const bf16x8*)(wt + 512 + lane * 8);
      }
#pragma unroll
      for (int kw = 0; kw < 3; ++kw) {
        int base = sbase + pxb[kw] * 64 + xorv[kw];
#pragma unroll
        for (int nf = 0; nf < 4; ++nf) {
          int px   = pxb[kw] + nf * 16;
          int addr = ((unsigned)px < 128u) ? (base + nf * 1024) : 49152;
          bf16x8 bv = *(const bf16x8*)((const char*)sx + addr);
          acc[0][nf] = __builtin_amdgcn_mfma_f32_16x16x32_bf16(a[kw][0], bv, acc[0][nf], 0, 0, 0);
          acc[1][nf] = __builtin_amdgcn_mfma_f32_16x16x32_bf16(a[kw][1], bv, acc[1][nf], 0, 0, 0);
        }
      }
    }
  }

  int ocb = (br + 1) * 32;
  int pxw = (h0 + j) * 128 + p0;
#pragma unroll
  for (int mf = 0; mf < 2; ++mf) {
#pragma unroll
    for (int r = 0; r < 4; ++r) {
      int oc = mf * 16 + cg * 4 + r;
      float bias = bfp[ocb + oc];
      float* op = out + ((size_t)(b * 128 + ocb + oc)) * NPIX + pxw + l15;
#pragma unroll
      for (int nf = 0; nf < 4; ++nf)
        op[nf * 16] = fmaxf(acc[mf][nf][r] + bias, 0.f);
    }
  }
}

// ---------------- a2f (fallback) ----------------
__global__ __launch_bounds__(256) void a2f_kernel(const float* __restrict__ x,
                                                  const float* __restrict__ w24t,
                                                  const float* __restrict__ bfp,
                                                  float* __restrict__ out) {
  int t  = threadIdx.x;
  int og = t & 3;
  int pg = (t >> 2) & 15;
  int r  = t >> 6;
  int br = blockIdx.z;
  int b  = blockIdx.y;
  int h  = blockIdx.x * 4 + r;
  int d  = 6 * (br + 1);

  const float* wt = w24t + (size_t)br * 36864;
  const float* bf = bfp + (br + 1) * 32;
  const float* xb = x + (size_t)b * 128 * NPIX;
  int w0 = pg << 3;

  float acc[8][8];
#pragma unroll
  for (int p = 0; p < 8; ++p)
#pragma unroll
    for (int o = 0; o < 8; ++o) acc[p][o] = 0.f;

  for (int c = 0; c < 128; ++c) {
    const float* xc = xb + (size_t)c * NPIX;
    const float* wc = wt + c * 288;
#pragma unroll
    for (int kh = 0; kh < 3; ++kh) {
      int row = h + (kh - 1) * d;
      if ((unsigned)row >= 128u) continue;
      const float* xr = xc + row * 128;
#pragma unroll
      for (int kw = 0; kw < 3; ++kw) {
        int wb = w0 + (kw - 1) * d;
        float xv[8];
        if (wb >= 0 && wb <= 120) {
          const float2* p2 = (const float2*)(xr + wb);
#pragma unroll
          for (int jj = 0; jj < 4; ++jj) {
            float2 v = p2[jj];
            xv[2*jj] = v.x; xv[2*jj+1] = v.y;
          }
        } else {
#pragma unroll
          for (int jj = 0; jj < 8; ++jj) {
            int ww = wb + jj;
            xv[jj] = ((unsigned)ww < 128u) ? xr[ww] : 0.f;
          }
        }
        const float4* wp = (const float4*)(wc + (kh * 3 + kw) * 32 + og * 8);
        float4 wa = wp[0], wbv = wp[1];
        float wr[8] = {wa.x, wa.y, wa.z, wa.w, wbv.x, wbv.y, wbv.z, wbv.w};
#pragma unroll
        for (int p = 0; p < 8; ++p)
#pragma unroll
          for (int o = 0; o < 8; ++o)
            acc[p][o] = fmaf(xv[p], wr[o], acc[p][o]);
      }
    }
  }

  int chbase = (br + 1) * 32 + og * 8;
  int n = h * 128 + w0;
#pragma unroll
  for (int o = 0; o < 8; ++o) {
    float bias = bf[og * 8 + o];
    float* op = out + ((size_t)(b * 128 + chbase + o)) * NPIX + n;
    float4 v0 = make_float4(fmaxf(acc[0][o] + bias, 0.f), fmaxf(acc[1][o] + bias, 0.f),
                            fmaxf(acc[2][o] + bias, 0.f), fmaxf(acc[3][o] + bias, 0.f));
    float4 v1 = make_float4(fmaxf(acc[4][o] + bias, 0.f), fmaxf(acc[5][o] + bias, 0.f),
                            fmaxf(acc[6][o] + bias, 0.f), fmaxf(acc[7][o] + bias, 0.f));
    ((float4*)op)[0] = v0;
    ((float4*)op)[1] = v1;
  }
}

// ---------------- cm v6: 1 tile/block, batch->XCD swizzle, dual part regions ----------------
__global__ __launch_bounds__(256) void cm_kernel(const unsigned short* __restrict__ xt,
                                                 const unsigned short* __restrict__ wvbr,
                                                 const unsigned short* __restrict__ wxbr,
                                                 const float* __restrict__ bv,
                                                 const float* __restrict__ bfp,
                                                 const float* __restrict__ bk,
                                                 float* __restrict__ out,
                                                 float* __restrict__ part1,
                                                 float* __restrict__ part2) {
  __shared__ __align__(16) unsigned short Vl[128 * 136];   // bf16 [oc][px]
  __shared__ __align__(16) unsigned short knl[16 * 136];   // bf16 [m][px]
  int t    = threadIdx.x;
  int idx  = blockIdx.x;
  int b    = idx & 7;           // batch -> XCD (1024 % 8 == 0, bijective)
  int blk  = idx >> 3;          // 0..127 == tile
  int wave = t >> 6, lane = t & 63;
  int l15  = lane & 15, cg = lane >> 4;
  int ocb  = wave * 32;
  int pbase = blk << 7;

  float bvr[2][4];
#pragma unroll
  for (int mf = 0; mf < 2; ++mf)
#pragma unroll
    for (int r = 0; r < 4; ++r) bvr[mf][r] = bv[ocb + mf * 16 + cg * 4 + r];

  float xb4[4];
#pragma unroll
  for (int r = 0; r < 4; ++r) xb4[r] = 0.f;
  if (wave == 0) {
#pragma unroll
    for (int r = 0; r < 4; ++r) xb4[r] = bfp[cg * 4 + r];
  } else if (wave == 1) {
#pragma unroll
    for (int r = 0; r < 4; ++r) xb4[r] = bfp[16 + cg * 4 + r];
  } else if (wave == 2) {
#pragma unroll
    for (int r = 0; r < 4; ++r) xb4[r] = bk[cg * 4 + r];
  }
  int xwave = (wave < 3) ? wave : 0;

  float kr[4] = {0.f, 0.f, 0.f, 0.f};
  float sv[2][4];
#pragma unroll
  for (int mf = 0; mf < 2; ++mf)
#pragma unroll
    for (int r = 0; r < 4; ++r) sv[mf][r] = 0.f;
  f32x4 am[2];
  am[0] = (f32x4){0.f,0.f,0.f,0.f};
  am[1] = (f32x4){0.f,0.f,0.f,0.f};

  // phase 2 in two 64-px halves (caps live accumulators)
#pragma unroll
  for (int hf = 0; hf < 2; ++hf) {
    f32x4 vacc[2][4];
    f32x4 xacc[4];
#pragma unroll
    for (int i = 0; i < 2; ++i)
#pragma unroll
      for (int n = 0; n < 4; ++n) vacc[i][n] = (f32x4){0.f,0.f,0.f,0.f};
#pragma unroll
    for (int n = 0; n < 4; ++n) xacc[n] = (f32x4){0.f,0.f,0.f,0.f};

#pragma unroll
    for (int cc = 0; cc < 4; ++cc) {
      const unsigned short* xq = xt + ((size_t)(b * 4 + cc) * 16384 + pbase) * 32;
      bf16x8 a0 = *(const bf16x8*)(wvbr + ((cc * 8 + wave * 2 + 0) << 9) + lane * 8);
      bf16x8 a1 = *(const bf16x8*)(wvbr + ((cc * 8 + wave * 2 + 1) << 9) + lane * 8);
      bf16x8 ax = *(const bf16x8*)(wxbr + ((cc * 3 + xwave) << 9) + lane * 8);
#pragma unroll
      for (int nf = 0; nf < 4; ++nf) {
        int nfg = hf * 4 + nf;
        bf16x8 bx = *(const bf16x8*)(xq + (size_t)(nfg * 16 + l15) * 32 + cg * 8);
        vacc[0][nf] = __builtin_amdgcn_mfma_f32_16x16x32_bf16(a0, bx, vacc[0][nf], 0, 0, 0);
        vacc[1][nf] = __builtin_amdgcn_mfma_f32_16x16x32_bf16(a1, bx, vacc[1][nf], 0, 0, 0);
        if (wave < 3)
          xacc[nf] = __builtin_amdgcn_mfma_f32_16x16x32_bf16(ax, bx, xacc[nf], 0, 0, 0);
      }
    }

#pragma unroll
    for (int mf = 0; mf < 2; ++mf) {
#pragma unroll
      for (int r = 0; r < 4; ++r) {
        float s = 0.f;
#pragma unroll
        for (int nf = 0; nf < 4; ++nf) s += vacc[mf][nf][r];
        sv[mf][r] += s;
        int c = ocb + mf * 16 + cg * 4 + r;
#pragma unroll
        for (int nf = 0; nf < 4; ++nf)
          Vl[c * 136 + (hf * 4 + nf) * 16 + l15] = f2bf(vacc[mf][nf][r] + bvr[mf][r]);
      }
    }

    if (wave < 2) {
#pragma unroll
      for (int r = 0; r < 4; ++r) {
        int oc = wave * 16 + cg * 4 + r;
        float* op = out + ((size_t)(b * 128 + oc)) * NPIX + pbase + l15;
#pragma unroll
        for (int nf = 0; nf < 4; ++nf)
          op[(hf * 4 + nf) * 16] = fmaxf(xacc[nf][r] + xb4[r], 0.f);
      }
    } else if (wave == 2) {
#pragma unroll
      for (int nf = 0; nf < 4; ++nf) {
        int nfg = hf * 4 + nf;
        float kq[4]; float s2 = 0.f;
#pragma unroll
        for (int r = 0; r < 4; ++r) {
          kq[r] = xacc[nf][r] + xb4[r];
          s2 = fmaf(kq[r], kq[r], s2);
        }
        s2 += __shfl_xor(s2, 16);
        s2 += __shfl_xor(s2, 32);
        float inv = rsqrtf(s2);
#pragma unroll
        for (int r = 0; r < 4; ++r) {
          float kn = kq[r] * inv;
          knl[(cg * 4 + r) * 136 + nfg * 16 + l15] = f2bf(kn);
          kr[r] += kn;
        }
      }
    }
  }
  __syncthreads();

  // phase 3: mat[m][c] += Kn · V^T via MFMA
#pragma unroll
  for (int ks = 0; ks < 4; ++ks) {
    bf16x8 af = *(const bf16x8*)(knl + l15 * 136 + ks * 32 + cg * 8);
    bf16x8 b0 = *(const bf16x8*)(Vl + (size_t)(ocb + l15) * 136 + ks * 32 + cg * 8);
    bf16x8 b1 = *(const bf16x8*)(Vl + (size_t)(ocb + 16 + l15) * 136 + ks * 32 + cg * 8);
    am[0] = __builtin_amdgcn_mfma_f32_16x16x32_bf16(af, b0, am[0], 0, 0, 0);
    am[1] = __builtin_amdgcn_mfma_f32_16x16x32_bf16(af, b1, am[1], 0, 0, 0);
  }

  // ---- write partials (blocks 0..63 -> part1, 64..127 -> part2) ----
  float* pp = (blk < 64) ? (part1 + ((size_t)b * 64 + blk) * 2192)
                         : (part2 + ((size_t)b * 64 + (blk - 64)) * 2192);
#pragma unroll
  for (int nf2 = 0; nf2 < 2; ++nf2)
#pragma unroll
    for (int r = 0; r < 4; ++r)
      pp[(cg * 4 + r) * 128 + ocb + nf2 * 16 + l15] = am[nf2][r];
#pragma unroll
  for (int off = 1; off < 16; off <<= 1) {
#pragma unroll
    for (int mf = 0; mf < 2; ++mf)
#pragma unroll
      for (int r = 0; r < 4; ++r)
        sv[mf][r] += __shfl_xor(sv[mf][r], off);
  }
  if (l15 == 0) {
#pragma unroll
    for (int mf = 0; mf < 2; ++mf)
#pragma unroll
      for (int r = 0; r < 4; ++r) {
        int c = ocb + mf * 16 + cg * 4 + r;
        pp[2048 + c] = sv[mf][r] + 128.f * bv[c];   // 128 px per block now
      }
  }
  if (wave == 2) {
#pragma unroll
    for (int off = 1; off < 16; off <<= 1) {
#pragma unroll
      for (int r = 0; r < 4; ++r)
        kr[r] += __shfl_xor(kr[r], off);
    }
    if (l15 == 0) {
#pragma unroll
      for (int r = 0; r < 4; ++r)
        pp[2048 + 128 + cg * 4 + r] = kr[r];
    }
  }
}

// ---------------- cf (fallback) ----------------
__global__ __launch_bounds__(256) void cf_kernel(const float* __restrict__ x,
                                                 const float* __restrict__ bv,
                                                 const float* __restrict__ Kbuf,
                                                 const float* __restrict__ wvt,
                                                 float* __restrict__ part) {
  __shared__ float Vl[128 * 129];
  __shared__ float knl[16 * 132];
  int t   = threadIdx.x;
  int b   = blockIdx.y;
  int blk = blockIdx.x;
  const float* Kb = Kbuf + (size_t)b * 16 * NPIX;
  const float* xb = x + (size_t)b * 128 * NPIX;

  int m_own = t & 15;
  int c0    = (t >> 4) << 3;
  int pxg   = t & 15;

  float bvr[8];
#pragma unroll
  for (int jj = 0; jj < 8; ++jj) bvr[jj] = bv[c0 + jj];

  float macc[8] = {0,0,0,0,0,0,0,0};
  float vs[8]   = {0,0,0,0,0,0,0,0};
  float ksum[16];
#pragma unroll
  for (int m = 0; m < 16; ++m) ksum[m] = 0.f;

  for (int tile = blk; tile < 128; tile += 64) {
    __syncthreads();
    int pbase = tile << 7;

    if (t < 128) {
      float kv[16]; float ss = 0.f;
#pragma unroll
      for (int m = 0; m < 16; ++m) {
        kv[m] = Kb[(size_t)m * NPIX + pbase + t];
        ss = fmaf(kv[m], kv[m], ss);
      }
      float inv = rsqrtf(ss);
#pragma unroll
      for (int m = 0; m < 16; ++m) {
        float kn = kv[m] * inv;
        knl[m * 132 + t] = kn;
        ksum[m] += kn;
      }
    }

    float v[8][8];
#pragma unroll
    for (int i = 0; i < 8; ++i)
#pragma unroll
      for (int jj = 0; jj < 8; ++jj) v[i][jj] = 0.f;
    int px0 = pbase + (pxg << 3);
    for (int k = 0; k < 128; ++k) {
      const float4* xp = (const float4*)(xb + (size_t)k * NPIX + px0);
      float4 xa = xp[0], xc4 = xp[1];
      const float4* wp = (const float4*)(wvt + k * 128 + c0);
      float4 wa = wp[0], wc4 = wp[1];
      float xv[8] = {xa.x, xa.y, xa.z, xa.w, xc4.x, xc4.y, xc4.z, xc4.w};
      float wr[8] = {wa.x, wa.y, wa.z, wa.w, wc4.x, wc4.y, wc4.z, wc4.w};
#pragma unroll
      for (int i = 0; i < 8; ++i)
#pragma unroll
        for (int jj = 0; jj < 8; ++jj)
          v[i][jj] = fmaf(wr[i], xv[jj], v[i][jj]);
    }
#pragma unroll
    for (int i = 0; i < 8; ++i)
#pragma unroll
      for (int jj = 0; jj < 8; ++jj)
        Vl[(c0 + i) * 129 + (pxg << 3) + jj] = v[i][jj] + bvr[i];
    __syncthreads();

    for (int px = 0; px < 128; ++px) {
      float knv = knl[m_own * 132 + px];
      float vv[8];
#pragma unroll
      for (int jj = 0; jj < 8; ++jj) vv[jj] = Vl[(c0 + jj) * 129 + px];
#pragma unroll
      for (int jj = 0; jj < 8; ++jj) macc[jj] = fmaf(knv, vv[jj], macc[jj]);
      if (m_own == 0) {
#pragma unroll
        for (int jj = 0; jj < 8; ++jj) vs[jj] += vv[jj];
      }
    }
  }

  int blkid = b * 64 + blk;
  float* pp = part + (size_t)blkid * 2192;
#pragma unroll
  for (int jj = 0; jj < 8; ++jj) pp[m_own * 128 + c0 + jj] = macc[jj];
  if (m_own == 0) {
#pragma unroll
    for (int jj = 0; jj < 8; ++jj) pp[2048 + c0 + jj] = vs[jj];
  }
  __syncthreads();
  if (t < 128) {
#pragma unroll
    for (int m = 0; m < 16; ++m) knl[m * 132 + t] = ksum[m];
  }
  __syncthreads();
  if (t < 16) {
    float s = 0.f;
    for (int i = 0; i < 128; ++i) s += knl[t * 132 + i];
    pp[2048 + 128 + t] = s;
  }
}

// ---------------- reduce (fallback: 64 groups) ----------------
__global__ void reduce_kernel(const float* __restrict__ part, float* __restrict__ stats) {
  int b = blockIdx.y, t = threadIdx.x;
  int e = blockIdx.x * 256 + t;
  if (e >= 2192) return;
  const float* pp = part + (size_t)b * 64 * 2192;
  float s = 0.f;
  for (int g = 0; g < 64; ++g) s += pp[(size_t)g * 2192 + e];
  stats[(size_t)b * 2192 + e] = s;
}

// ---------------- reduce2 (mfma: 64 + 64 groups) ----------------
__global__ void reduce2_kernel(const float* __restrict__ part1,
                               const float* __restrict__ part2,
                               float* __restrict__ stats) {
  int b = blockIdx.y, t = threadIdx.x;
  int e = blockIdx.x * 256 + t;
  if (e >= 2192) return;
  const float* p1 = part1 + (size_t)b * 64 * 2192;
  const float* p2 = part2 + (size_t)b * 64 * 2192;
  float s = 0.f;
  for (int g = 0; g < 64; ++g) s += p1[(size_t)g * 2192 + e];
  for (int g = 0; g < 64; ++g) s += p2[(size_t)g * 2192 + e];
  stats[(size_t)b * 2192 + e] = s;
}

// ---------------- d1: Q + tailor per pixel -> sq[16], tl ----------------
__global__ __launch_bounds__(256) void d1_kernel(const float* __restrict__ stats,
                                                 const float* __restrict__ wq,
                                                 const float* __restrict__ bq,
                                                 const float* __restrict__ gamma,
                                                 const float* __restrict__ out,
                                                 float* __restrict__ sq,
                                                 float* __restrict__ tlb) {
  __shared__ float wql[128 * 16];   // [c][m]
  __shared__ float ksl[16];
  int t = threadIdx.x;
  int b = blockIdx.y;
  const float* st = stats + (size_t)b * 2192;
  for (int i = t; i < 2048; i += 256) {
    int m = i >> 7, c = i & 127;
    wql[c * 16 + m] = wq[m * 128 + c];
  }
  if (t < 16) ksl[t] = st[2048 + 128 + t] + EPS_V;
  __syncthreads();

  int px = blockIdx.x * 256 + t;
  const float* ob = out + (size_t)b * 128 * NPIX;

  float q[16];
#pragma unroll
  for (int m = 0; m < 16; ++m) q[m] = bq[m];
  for (int c = 0; c < 128; ++c) {
    float xv = ob[(size_t)c * NPIX + px];
    const float4* wp = (const float4*)(wql + c * 16);
#pragma unroll
    for (int jj = 0; jj < 4; ++jj) {
      float4 w = wp[jj];
      q[jj*4+0] = fmaf(w.x, xv, q[jj*4+0]);
      q[jj*4+1] = fmaf(w.y, xv, q[jj*4+1]);
      q[jj*4+2] = fmaf(w.z, xv, q[jj*4+2]);
      q[jj*4+3] = fmaf(w.w, xv, q[jj*4+3]);
    }
  }
  float ss = 0.f;
#pragma unroll
  for (int m = 0; m < 16; ++m) ss = fmaf(q[m], q[m], ss);
  float inv = rsqrtf(ss);
#pragma unroll
  for (int m = 0; m < 16; ++m) q[m] *= inv;
  float den = (float)NPIX;
#pragma unroll
  for (int m = 0; m < 16; ++m) den = fmaf(q[m], ksl[m], den);
  float tl = gamma[0] / den;

  tlb[(size_t)b * NPIX + px] = tl;
#pragma unroll
  for (int m = 0; m < 16; ++m)
    sq[((size_t)(b * 16 + m)) * NPIX + px] = tl * q[m];
}

// ---------------- d2: out[c][px] = vsl[c]*tl + mat[m][c]*sq[m] ----------------
__global__ __launch_bounds__(256) void d2_kernel(const float* __restrict__ stats,
                                                 const float* __restrict__ sq,
                                                 const float* __restrict__ tlb,
                                                 float* __restrict__ out) {
  __shared__ float matl[128 * 16];  // [c][m]
  __shared__ float vsl[128];
  int t = threadIdx.x;
  int b = blockIdx.y;
  const float* st = stats + (size_t)b * 2192;
  for (int i = t; i < 2048; i += 256) {
    int m = i >> 7, c = i & 127;
    matl[c * 16 + m] = st[i];
  }
  if (t < 128) vsl[t] = st[2048 + t];
  __syncthreads();

  int px = blockIdx.x * 256 + t;
  float* ob = out + (size_t)b * 128 * NPIX;

  float tlv = tlb[(size_t)b * NPIX + px];
  float sv[16];
#pragma unroll
  for (int m = 0; m < 16; ++m)
    sv[m] = sq[((size_t)(b * 16 + m)) * NPIX + px];

  for (int c = 0; c < 128; ++c) {
    float s = vsl[c] * tlv;
    const float4* mp = (const float4*)(matl + c * 16);
#pragma unroll
    for (int jj = 0; jj < 4; ++jj) {
      float4 w = mp[jj];
      s = fmaf(w.x, sv[jj*4+0], s);
      s = fmaf(w.y, sv[jj*4+1], s);
      s = fmaf(w.z, sv[jj*4+2], s);
      s = fmaf(w.w, sv[jj*4+3], s);
    }
    ob[(size_t)c * NPIX + px] = s;
  }
}

// ---------------- df (fallback final) ----------------
__global__ __launch_bounds__(256) void df_kernel(const float* __restrict__ stats,
                                                 const float* __restrict__ wq,
                                                 const float* __restrict__ bq,
                                                 const float* __restrict__ gamma,
                                                 float* __restrict__ out) {
  __shared__ float matl[128 * 16];
  __shared__ float wql[128 * 16];
  __shared__ float vsl[128];
  __shared__ float ksl[16];
  int t = threadIdx.x;
  int b = blockIdx.y;
  const float* st = stats + (size_t)b * 2192;
  for (int i = t; i < 2048; i += 256) {
    int m = i >> 7, c = i & 127;
    matl[c * 16 + m] = st[i];
    wql[c * 16 + m]  = wq[m * 128 + c];
  }
  if (t < 128) vsl[t] = st[2048 + t];
  if (t < 16)  ksl[t] = st[2048 + 128 + t] + EPS_V;
  __syncthreads();

  int px = blockIdx.x * 256 + t;
  float* ob = out + (size_t)b * 128 * NPIX;

  float q[16];
#pragma unroll
  for (int m = 0; m < 16; ++m) q[m] = bq[m];
  for (int c = 0; c < 128; ++c) {
    float xv = ob[(size_t)c * NPIX + px];
    const float4* wp = (const float4*)(wql + c * 16);
#pragma unroll
    for (int jj = 0; jj < 4; ++jj) {
      float4 w = wp[jj];
      q[jj*4+0] = fmaf(w.x, xv, q[jj*4+0]);
      q[jj*4+1] = fmaf(w.y, xv, q[jj*4+1]);
      q[jj*4+2] = fmaf(w.z, xv, q[jj*4+2]);
      q[jj*4+3] = fmaf(w.w, xv, q[jj*4+3]);
    }
  }
  float ss = 0.f;
#pragma unroll
  for (int m = 0; m < 16; ++m) ss = fmaf(q[m], q[m], ss);
  float inv = rsqrtf(ss);
#pragma unroll
  for (int m = 0; m < 16; ++m) q[m] *= inv;
  float den = (float)NPIX;
#pragma unroll
  for (int m = 0; m < 16; ++m) den = fmaf(q[m], ksl[m], den);
  float tl = gamma[0] / den;

  for (int c = 0; c < 128; ++c) {
    float s = vsl[c];
    const float4* mp = (const float4*)(matl + c * 16);
#pragma unroll
    for (int jj = 0; jj < 4; ++jj) {
      float4 w = mp[jj];
      s = fmaf(w.x, q[jj*4+0], s);
      s = fmaf(w.y, q[jj*4+1], s);
      s = fmaf(w.z, q[jj*4+2], s);
      s = fmaf(w.w, q[jj*4+3], s);
    }
    ob[(size_t)c * NPIX + px] = tl * s;
  }
}

extern "C" void kernel_launch(void* const* d_in, const int* in_sizes, int n_in,
                              void* d_out, int out_size, void* d_ws, size_t ws_size,
                              hipStream_t stream) {
  (void)in_sizes; (void)n_in; (void)out_size;
  const float* x   = (const float*)d_in[0];
  const float* w1  = (const float*)d_in[1];
  const float* w2  = (const float*)d_in[2];
  const float* w3  = (const float*)d_in[3];
  const float* w4  = (const float*)d_in[4];
  const float* bns = (const float*)d_in[5];
  const float* bnb = (const float*)d_in[6];
  const float* bnm = (const float*)d_in[7];
  const float* bnv = (const float*)d_in[8];
  const float* wq  = (const float*)d_in[9];
  const float* bq  = (const float*)d_in[10];
  const float* wk  = (const float*)d_in[11];
  const float* bk  = (const float*)d_in[12];
  const float* wv  = (const float*)d_in[13];
  const float* bv  = (const float*)d_in[14];
  const float* gm  = (const float*)d_in[15];
  float* ws  = (float*)d_ws;
  float* out = (float*)d_out;

  float* Kbuf = ws + OFF_K;
  float* w1f  = ws + OFF_W1F;
  float* wkt  = ws + OFF_WKT;
  float* wvt  = ws + OFF_WVT;
  float* bfp  = ws + OFF_BF;
  float* part = ws + OFF_PART;
  float* stat = ws + OFF_STATS;

  prep_common_kernel<<<64, 256, 0, stream>>>(w1, bns, bnb, bnm, bnv, wk, wv,
                                             w1f, wkt, wvt, bfp);

  bool use_mfma = ws_size >= NEW_END * sizeof(float);
  if (use_mfma) {
    unsigned short* wbtr = (unsigned short*)(ws + OFF_WBT);
    unsigned short* xt   = (unsigned short*)(ws + OFF_XT);
    unsigned short* wvbr = (unsigned short*)(ws + OFF_WVB);
    unsigned short* wxbr = (unsigned short*)(ws + OFF_K);   // first 6144 floats of K region
    float* part2 = ws + OFF_PART2;                          // K region tail (dead in mfma path)
    float* sq  = ws + OFF_SQ;   // reuses xt region (dead after cm)
    float* tlb = ws + OFF_TL;
    prep_convb_kernel<<<64, 256, 0, stream>>>(w1, w2, w3, w4, bns, bnv, wk, wv,
                                              wbtr, wvbr, wxbr);
    a0_kernel<<<dim3(256, 8), 256, 0, stream>>>(x, xt);
    a2m_kernel<<<dim3(1536), 256, 0, stream>>>(xt, wbtr, bfp, out);
    cm_kernel<<<dim3(1024), 256, 0, stream>>>(xt, wvbr, wxbr, bv, bfp, bk, out, part, part2);
    reduce2_kernel<<<dim3(9, 8), 256, 0, stream>>>(part, part2, stat);
    d1_kernel<<<dim3(64, 8), 256, 0, stream>>>(stat, wq, bq, gm, out, sq, tlb);
    d2_kernel<<<dim3(64, 8), 256, 0, stream>>>(stat, sq, tlb, out);
  } else {
    float* w24t = ws + OFF_W24T;
    prep_convf_kernel<<<64, 256, 0, stream>>>(w2, w3, w4, bns, bnv, w24t);
    a1_kernel<<<dim3(64, 8), 256, 0, stream>>>(x, w1f, wkt, bfp, bk, out, Kbuf);
    a2f_kernel<<<dim3(32, 8, 3), 256, 0, stream>>>(x, w24t, bfp, out);
    cf_kernel<<<dim3(64, 8), 256, 0, stream>>>(x, bv, Kbuf, wvt, part);
    reduce_kernel<<<dim3(9, 8), 256, 0, stream>>>(part, stat);
    df_kernel<<<dim3(64, 8), 256, 0, stream>>>(stat, wq, bq, gm, out);
  }
}

// Round 10
// 146.198 us; speedup vs baseline: 1.5511x; 1.0122x over previous
//
#include <hip/hip_runtime.h>
#include <hip/hip_bf16.h>
#include <math.h>

#define NPIX   16384
#define BATCH  8
#define BN_EPS 1e-5f
#define EPS_V  1e-6f

typedef __attribute__((ext_vector_type(8))) short bf16x8;
typedef __attribute__((ext_vector_type(4))) float f32x4;
typedef const __attribute__((address_space(1))) unsigned int* gas_ptr;
typedef __attribute__((address_space(3))) unsigned int* las_ptr;

// ---- workspace layout (float offsets) ----
// common
#define OFF_K     ((size_t)0)          // fallback: Kbuf. mfma path: wxbr + part2
#define OFF_PART2 ((size_t)8192)       // mfma: 512*2192 = 1122304 (ends 1130496 < 2097152)
#define OFF_W1F   ((size_t)2097152)    // 128*32   = 4096
#define OFF_WKT   ((size_t)2101248)    // 128*16   = 2048
#define OFF_WVT   ((size_t)2103296)    // 128*128  = 16384
#define OFF_BF    ((size_t)2119680)    // 4*32     = 128
#define OFF_PART  ((size_t)2119808)    // 512*2192 = 1122304
#define OFF_STATS ((size_t)3242112)    // 8*2192   = 17536
#define BASE_END  ((size_t)3259648)
// new (bf16-MFMA) path extras
#define OFF_WBT   BASE_END             // 3*9*4*2*64*8 ushort = 55296 floats
#define OFF_XT    ((size_t)3314976)    // 8*4*16384*32 ushort = 8388608 floats (PRE-SWIZZLED)
#define OFF_WVB   ((size_t)11703584)   // 4*8*64*8 ushort = 8192 floats
#define OFF_ZROW  ((size_t)11711776)   // 4096 ushort zero row = 2048 floats
#define NEW_END   ((size_t)11713824)
// d1/d2 scratch reuses the xt region (dead after cm; a0 rewrites it every call)
#define OFF_SQ    OFF_XT               // 8*16*16384 = 2097152 floats
#define OFF_TL    ((size_t)(OFF_XT + 2097152))   // 8*16384 = 131072 floats
// old (fp32) fallback extras
#define OFF_W24T  BASE_END             // 3*128*9*32 = 110592

__device__ inline unsigned short f2bf(float f) {
  union { float f; unsigned int u; } v; v.f = f;
  unsigned int r = (v.u + 0x7FFFu + ((v.u >> 16) & 1u)) >> 16;
  return (unsigned short)r;
}

// ---------------- prep_common ----------------
__global__ void prep_common_kernel(const float* __restrict__ w1,
                                   const float* __restrict__ bns, const float* __restrict__ bnb,
                                   const float* __restrict__ bnm, const float* __restrict__ bnv,
                                   const float* __restrict__ wk, const float* __restrict__ wv,
                                   float* __restrict__ w1f, float* __restrict__ wkt,
                                   float* __restrict__ wvt, float* __restrict__ bf) {
  int tid = blockIdx.x * blockDim.x + threadIdx.x;
  int nt  = gridDim.x * blockDim.x;
  for (int i = tid; i < 128; i += nt) {
    float inv = bns[i] * rsqrtf(bnv[i] + BN_EPS);
    bf[i] = bnb[i] - bnm[i] * inv;
  }
  for (int i = tid; i < 4096; i += nt) {          // w1f[c][o]
    int c = i >> 5, o = i & 31;
    float inv = bns[o] * rsqrtf(bnv[o] + BN_EPS);
    w1f[i] = w1[o * 128 + c] * inv;
  }
  for (int i = tid; i < 2048; i += nt) {          // wkt[c][m]
    int c = i >> 4, m = i & 15;
    wkt[i] = wk[m * 128 + c];
  }
  for (int i = tid; i < 16384; i += nt) {         // wvt[c][o]
    int c = i >> 7, o = i & 127;
    wvt[i] = wv[o * 128 + c];
  }
}

// ---------------- prep_convb: MFMA-fragment-ordered bf16 weights + zero row ----------------
__global__ void prep_convb_kernel(const float* __restrict__ w1,
                                  const float* __restrict__ w2, const float* __restrict__ w3,
                                  const float* __restrict__ w4,
                                  const float* __restrict__ bns, const float* __restrict__ bnv,
                                  const float* __restrict__ wk, const float* __restrict__ wv,
                                  unsigned short* __restrict__ wbtr,
                                  unsigned short* __restrict__ wvbr,
                                  unsigned short* __restrict__ wxbr,
                                  unsigned short* __restrict__ zrow) {
  int tid = blockIdx.x * blockDim.x + threadIdx.x;
  int nt  = gridDim.x * blockDim.x;
  for (int i = tid; i < 4096; i += nt) zrow[i] = 0;
  for (int i = tid; i < 16384; i += nt) {
    int e = i & 7, lane = (i >> 3) & 63, f = (i >> 9) & 7, q = i >> 12;
    int oc = f * 16 + (lane & 15);
    int c  = q * 32 + (lane >> 4) * 8 + e;
    wvbr[i] = f2bf(wv[oc * 128 + c]);
  }
  for (int i = tid; i < 6144; i += nt) {
    int e = i & 7, lane = (i >> 3) & 63, ct = i >> 9;
    int tile = ct % 3, q = ct / 3;
    int c = q * 32 + (lane >> 4) * 8 + e;
    float val;
    if (tile < 2) {
      int oc = tile * 16 + (lane & 15);
      val = w1[oc * 128 + c] * (bns[oc] * rsqrtf(bnv[oc] + BN_EPS));
    } else {
      val = wk[(lane & 15) * 128 + c];
    }
    wxbr[i] = f2bf(val);
  }
  for (int i = tid; i < 110592; i += nt) {
    int br = i / 36864;
    int r  = i - br * 36864;
    int tap  = r >> 12;
    int r2   = r & 4095;
    int q    = r2 >> 10;
    int r3   = r2 & 1023;
    int pair = r3 >> 9;
    int r4   = r3 & 511;
    int lane = r4 >> 3, e = r4 & 7;
    int oc = pair * 16 + (lane & 15);
    int c  = q * 32 + (lane >> 4) * 8 + e;
    const float* w = (br == 0) ? w2 : ((br == 1) ? w3 : w4);
    int bo = (br + 1) * 32 + oc;
    float inv = bns[bo] * rsqrtf(bnv[bo] + BN_EPS);
    wbtr[i] = f2bf(w[(oc * 128 + c) * 9 + tap] * inv);
  }
}

// ---------------- prep_convf (fallback) ----------------
__global__ void prep_convf_kernel(const float* __restrict__ w2, const float* __restrict__ w3,
                                  const float* __restrict__ w4,
                                  const float* __restrict__ bns, const float* __restrict__ bnv,
                                  float* __restrict__ w24t) {
  int tid = blockIdx.x * blockDim.x + threadIdx.x;
  int nt  = gridDim.x * blockDim.x;
  for (int i = tid; i < 110592; i += nt) {
    int br  = i / 36864;
    int rem = i - br * 36864;
    int c   = rem / 288;
    int k   = (rem % 288) >> 5;
    int o   = rem & 31;
    const float* w = (br == 0) ? w2 : ((br == 1) ? w3 : w4);
    int bo = (br + 1) * 32 + o;
    float inv = bns[bo] * rsqrtf(bnv[bo] + BN_EPS);
    w24t[i] = w[(o * 128 + c) * 9 + k] * inv;
  }
}

// ---------------- a0: transpose x -> xt bf16, quarter-major, PRE-SWIZZLED 16B units ----------------
// unit for c-chunk cgs of pixel px stored at slot cgs ^ ((px>>1)&3) within the 64B px-row.
__global__ __launch_bounds__(256) void a0_kernel(const float* __restrict__ x,
                                                 unsigned short* __restrict__ xt) {
  __shared__ unsigned short Ts[64][132];
  int t   = threadIdx.x;
  int b   = blockIdx.y;
  int px0 = blockIdx.x * 64;
  const float* xb = x + (size_t)b * 128 * NPIX;
  int p = t & 63, cq = t >> 6;
#pragma unroll 8
  for (int i = 0; i < 32; ++i) {
    int c = cq * 32 + i;
    Ts[p][c] = f2bf(xb[(size_t)c * NPIX + px0 + p]);
  }
  __syncthreads();
  int pw = t >> 2, cg = t & 3;   // cg == quarter
  unsigned short* dst = xt + ((size_t)(b * 4 + cg) * 16384 + px0 + pw) * 32;
  int sw = (pw >> 1) & 3;
#pragma unroll
  for (int k = 0; k < 8; ++k) {
    uint2 v = *(const uint2*)(&Ts[pw][cg * 32 + k * 4]);
    int cgs = (k >> 1) ^ sw;
    *(uint2*)(dst + cgs * 8 + (k & 1) * 4) = v;
  }
}

// ---------------- a1 (fallback only) ----------------
__global__ __launch_bounds__(256) void a1_kernel(const float* __restrict__ x,
                                                 const float* __restrict__ w1f,
                                                 const float* __restrict__ wkt,
                                                 const float* __restrict__ bfp,
                                                 const float* __restrict__ bk,
                                                 float* __restrict__ out,
                                                 float* __restrict__ Kbuf) {
  __shared__ float lw1[128 * 32];
  __shared__ float lwk[128 * 16];
  __shared__ float lbf[32];
  int t = threadIdx.x;
  for (int i = t; i < 4096; i += 256) lw1[i] = w1f[i];
  for (int i = t; i < 2048; i += 256) lwk[i] = wkt[i];
  if (t < 32) lbf[t] = bfp[t];
  __syncthreads();

  int b  = blockIdx.y;
  int px = blockIdx.x * 256 + t;
  const float* xb = x + (size_t)b * 128 * NPIX;

  float acc[48];
#pragma unroll
  for (int i = 0; i < 48; ++i) acc[i] = 0.f;

  for (int c = 0; c < 128; ++c) {
    float xv = xb[(size_t)c * NPIX + px];
    const float4* w1p = (const float4*)(lw1 + c * 32);
#pragma unroll
    for (int j = 0; j < 8; ++j) {
      float4 w = w1p[j];
      acc[j*4+0] = fmaf(w.x, xv, acc[j*4+0]);
      acc[j*4+1] = fmaf(w.y, xv, acc[j*4+1]);
      acc[j*4+2] = fmaf(w.z, xv, acc[j*4+2]);
      acc[j*4+3] = fmaf(w.w, xv, acc[j*4+3]);
    }
    const float4* wkp = (const float4*)(lwk + c * 16);
#pragma unroll
    for (int j = 0; j < 4; ++j) {
      float4 w = wkp[j];
      acc[32+j*4+0] = fmaf(w.x, xv, acc[32+j*4+0]);
      acc[32+j*4+1] = fmaf(w.y, xv, acc[32+j*4+1]);
      acc[32+j*4+2] = fmaf(w.z, xv, acc[32+j*4+2]);
      acc[32+j*4+3] = fmaf(w.w, xv, acc[32+j*4+3]);
    }
  }
#pragma unroll
  for (int o = 0; o < 32; ++o)
    out[((size_t)(b * 128 + o)) * NPIX + px] = fmaxf(acc[o] + lbf[o], 0.f);
#pragma unroll
  for (int m = 0; m < 16; ++m)
    Kbuf[((size_t)(b * 16 + m)) * NPIX + px] = acc[32 + m] + bk[m];
}

// ---------------- a2m v5: (q,kh)-pipelined, 3 LDS sub-buffers, global_load_lds staging ----------------
__global__ __launch_bounds__(256) void a2m_kernel(const unsigned short* __restrict__ xt,
                                                  const unsigned short* __restrict__ zrow,
                                                  const unsigned short* __restrict__ wbtr,
                                                  const float* __restrict__ bfp,
                                                  float* __restrict__ out) {
  __shared__ unsigned short sx[3 * 8192 + 8];   // 3x16KB sub-buffers + 16B zero page @byte 49152
  int t    = threadIdx.x;
  int wave = t >> 6, lane = t & 63;
  int l15  = lane & 15, cg = lane >> 4;
  int idx  = blockIdx.x;
  int b    = idx & 7;                           // batch -> XCD
  int rest = idx >> 3;
  int h2   = rest & 63;
  int br   = rest >> 6;
  int d    = 6 * (br + 1);
  int h0   = h2 * 2;
  int j    = wave >> 1;                         // row of the pair this wave computes/stages
  int whalf = wave & 1;                         // px half (compute) / row half (stage)
  int p0   = whalf * 64;

  if (t == 0) *(uint4*)(sx + 24576) = make_uint4(0u, 0u, 0u, 0u);

  const unsigned short* wb    = wbtr + (size_t)br * 36864;
  const unsigned short* slabs = xt + (size_t)b * 4 * 524288;

  f32x4 acc[2][4];
#pragma unroll
  for (int i = 0; i < 2; ++i)
#pragma unroll
    for (int n = 0; n < 4; ++n) acc[i][n] = (f32x4){0.f, 0.f, 0.f, 0.f};

  int pxb[3], xorv[3];
#pragma unroll
  for (int kw = 0; kw < 3; ++kw) {
    pxb[kw]  = p0 + l15 + (kw - 1) * d;
    xorv[kw] = (cg ^ ((pxb[kw] >> 1) & 3)) << 4;
  }

  // stage step s = q*3+kh: copy rows {h0, h0+1} + (kh-1)*d of quarter q, linear, into buffer s%3.
  auto STAGE = [&](int s) {
    int q = s / 3, kh = s % 3;
    int srow = h0 + j + (kh - 1) * d;
    const unsigned short* rowsrc =
        ((unsigned)srow < 128u) ? (slabs + (size_t)q * 524288 + (size_t)srow * 4096)
                                : zrow;
    const unsigned short* gsrc = rowsrc + whalf * 2048 + lane * 8;
    unsigned short* lbase = sx + (s % 3) * 8192 + j * 4096 + whalf * 2048;
#pragma unroll
    for (int k = 0; k < 4; ++k)
      __builtin_amdgcn_global_load_lds((gas_ptr)(const void*)(gsrc + k * 512),
                                       (las_ptr)(void*)(lbase + k * 512), 16, 0, 0);
  };

  auto COMPUTE = [&](int s) {
    int q = s / 3, kh = s % 3;
    int bb = (s % 3) * 16384 + j * 8192;        // byte base of this wave's row
    bf16x8 a[3][2];
#pragma unroll
    for (int kw = 0; kw < 3; ++kw) {
      int tap = kh * 3 + kw;
      const unsigned short* wt = wb + ((((size_t)tap * 4 + q) * 2) << 9);
      a[kw][0] = *(const bf16x8*)(wt + lane * 8);
      a[kw][1] = *(const bf16x8*)(wt + 512 + lane * 8);
    }
#pragma unroll
    for (int kw = 0; kw < 3; ++kw) {
      int base = bb + pxb[kw] * 64 + xorv[kw];
#pragma unroll
      for (int nf = 0; nf < 4; ++nf) {
        int px   = pxb[kw] + nf * 16;
        int addr = ((unsigned)px < 128u) ? (base + nf * 1024) : 49152;
        bf16x8 bv = *(const bf16x8*)((const char*)sx + addr);
        acc[0][nf] = __builtin_amdgcn_mfma_f32_16x16x32_bf16(a[kw][0], bv, acc[0][nf], 0, 0, 0);
        acc[1][nf] = __builtin_amdgcn_mfma_f32_16x16x32_bf16(a[kw][1], bv, acc[1][nf], 0, 0, 0);
      }
    }
  };

  STAGE(0);
  __syncthreads();                              // drains vmcnt: buffer 0 ready
  for (int s = 0; s < 12; ++s) {
    if (s < 11) STAGE(s + 1);                   // loads fly under compute
    COMPUTE(s);
    __syncthreads();                            // drains vmcnt+lgkm: buffer (s+1)%3 ready
  }

  int ocb = (br + 1) * 32;
  int pxw = (h0 + j) * 128 + p0;
#pragma unroll
  for (int mf = 0; mf < 2; ++mf) {
#pragma unroll
    for (int r = 0; r < 4; ++r) {
      int oc = mf * 16 + cg * 4 + r;
      float bias = bfp[ocb + oc];
      float* op = out + ((size_t)(b * 128 + ocb + oc)) * NPIX + pxw + l15;
#pragma unroll
      for (int nf = 0; nf < 4; ++nf)
        op[nf * 16] = fmaxf(acc[mf][nf][r] + bias, 0.f);
    }
  }
}

// ---------------- a2f (fallback) ----------------
__global__ __launch_bounds__(256) void a2f_kernel(const float* __restrict__ x,
                                                  const float* __restrict__ w24t,
                                                  const float* __restrict__ bfp,
                                                  float* __restrict__ out) {
  int t  = threadIdx.x;
  int og = t & 3;
  int pg = (t >> 2) & 15;
  int r  = t >> 6;
  int br = blockIdx.z;
  int b  = blockIdx.y;
  int h  = blockIdx.x * 4 + r;
  int d  = 6 * (br + 1);

  const float* wt = w24t + (size_t)br * 36864;
  const float* bf = bfp + (br + 1) * 32;
  const float* xb = x + (size_t)b * 128 * NPIX;
  int w0 = pg << 3;

  float acc[8][8];
#pragma unroll
  for (int p = 0; p < 8; ++p)
#pragma unroll
    for (int o = 0; o < 8; ++o) acc[p][o] = 0.f;

  for (int c = 0; c < 128; ++c) {
    const float* xc = xb + (size_t)c * NPIX;
    const float* wc = wt + c * 288;
#pragma unroll
    for (int kh = 0; kh < 3; ++kh) {
      int row = h + (kh - 1) * d;
      if ((unsigned)row >= 128u) continue;
      const float* xr = xc + row * 128;
#pragma unroll
      for (int kw = 0; kw < 3; ++kw) {
        int wb = w0 + (kw - 1) * d;
        float xv[8];
        if (wb >= 0 && wb <= 120) {
          const float2* p2 = (const float2*)(xr + wb);
#pragma unroll
          for (int jj = 0; jj < 4; ++jj) {
            float2 v = p2[jj];
            xv[2*jj] = v.x; xv[2*jj+1] = v.y;
          }
        } else {
#pragma unroll
          for (int jj = 0; jj < 8; ++jj) {
            int ww = wb + jj;
            xv[jj] = ((unsigned)ww < 128u) ? xr[ww] : 0.f;
          }
        }
        const float4* wp = (const float4*)(wc + (kh * 3 + kw) * 32 + og * 8);
        float4 wa = wp[0], wbv = wp[1];
        float wr[8] = {wa.x, wa.y, wa.z, wa.w, wbv.x, wbv.y, wbv.z, wbv.w};
#pragma unroll
        for (int p = 0; p < 8; ++p)
#pragma unroll
          for (int o = 0; o < 8; ++o)
            acc[p][o] = fmaf(xv[p], wr[o], acc[p][o]);
      }
    }
  }

  int chbase = (br + 1) * 32 + og * 8;
  int n = h * 128 + w0;
#pragma unroll
  for (int o = 0; o < 8; ++o) {
    float bias = bf[og * 8 + o];
    float* op = out + ((size_t)(b * 128 + chbase + o)) * NPIX + n;
    float4 v0 = make_float4(fmaxf(acc[0][o] + bias, 0.f), fmaxf(acc[1][o] + bias, 0.f),
                            fmaxf(acc[2][o] + bias, 0.f), fmaxf(acc[3][o] + bias, 0.f));
    float4 v1 = make_float4(fmaxf(acc[4][o] + bias, 0.f), fmaxf(acc[5][o] + bias, 0.f),
                            fmaxf(acc[6][o] + bias, 0.f), fmaxf(acc[7][o] + bias, 0.f));
    ((float4*)op)[0] = v0;
    ((float4*)op)[1] = v1;
  }
}

// ---------------- cm v7: 1 tile/block, batch->XCD swizzle, swizzled-xt reads ----------------
__global__ __launch_bounds__(256) void cm_kernel(const unsigned short* __restrict__ xt,
                                                 const unsigned short* __restrict__ wvbr,
                                                 const unsigned short* __restrict__ wxbr,
                                                 const float* __restrict__ bv,
                                                 const float* __restrict__ bfp,
                                                 const float* __restrict__ bk,
                                                 float* __restrict__ out,
                                                 float* __restrict__ part1,
                                                 float* __restrict__ part2) {
  __shared__ __align__(16) unsigned short Vl[128 * 136];   // bf16 [oc][px]
  __shared__ __align__(16) unsigned short knl[16 * 136];   // bf16 [m][px]
  int t    = threadIdx.x;
  int idx  = blockIdx.x;
  int b    = idx & 7;           // batch -> XCD (1024 % 8 == 0, bijective)
  int blk  = idx >> 3;          // 0..127 == tile
  int wave = t >> 6, lane = t & 63;
  int l15  = lane & 15, cg = lane >> 4;
  int ocb  = wave * 32;
  int pbase = blk << 7;
  int cgsw = (cg ^ ((l15 >> 1) & 3)) << 3;   // swizzled-xt unit offset (ushorts)

  float bvr[2][4];
#pragma unroll
  for (int mf = 0; mf < 2; ++mf)
#pragma unroll
    for (int r = 0; r < 4; ++r) bvr[mf][r] = bv[ocb + mf * 16 + cg * 4 + r];

  float xb4[4];
#pragma unroll
  for (int r = 0; r < 4; ++r) xb4[r] = 0.f;
  if (wave == 0) {
#pragma unroll
    for (int r = 0; r < 4; ++r) xb4[r] = bfp[cg * 4 + r];
  } else if (wave == 1) {
#pragma unroll
    for (int r = 0; r < 4; ++r) xb4[r] = bfp[16 + cg * 4 + r];
  } else if (wave == 2) {
#pragma unroll
    for (int r = 0; r < 4; ++r) xb4[r] = bk[cg * 4 + r];
  }
  int xwave = (wave < 3) ? wave : 0;

  float kr[4] = {0.f, 0.f, 0.f, 0.f};
  float sv[2][4];
#pragma unroll
  for (int mf = 0; mf < 2; ++mf)
#pragma unroll
    for (int r = 0; r < 4; ++r) sv[mf][r] = 0.f;
  f32x4 am[2];
  am[0] = (f32x4){0.f,0.f,0.f,0.f};
  am[1] = (f32x4){0.f,0.f,0.f,0.f};

#pragma unroll
  for (int hf = 0; hf < 2; ++hf) {
    f32x4 vacc[2][4];
    f32x4 xacc[4];
#pragma unroll
    for (int i = 0; i < 2; ++i)
#pragma unroll
      for (int n = 0; n < 4; ++n) vacc[i][n] = (f32x4){0.f,0.f,0.f,0.f};
#pragma unroll
    for (int n = 0; n < 4; ++n) xacc[n] = (f32x4){0.f,0.f,0.f,0.f};

#pragma unroll
    for (int cc = 0; cc < 4; ++cc) {
      const unsigned short* xq = xt + ((size_t)(b * 4 + cc) * 16384 + pbase) * 32;
      bf16x8 a0 = *(const bf16x8*)(wvbr + ((cc * 8 + wave * 2 + 0) << 9) + lane * 8);
      bf16x8 a1 = *(const bf16x8*)(wvbr + ((cc * 8 + wave * 2 + 1) << 9) + lane * 8);
      bf16x8 ax = *(const bf16x8*)(wxbr + ((cc * 3 + xwave) << 9) + lane * 8);
#pragma unroll
      for (int nf = 0; nf < 4; ++nf) {
        int nfg = hf * 4 + nf;
        bf16x8 bx = *(const bf16x8*)(xq + (size_t)(nfg * 16 + l15) * 32 + cgsw);
        vacc[0][nf] = __builtin_amdgcn_mfma_f32_16x16x32_bf16(a0, bx, vacc[0][nf], 0, 0, 0);
        vacc[1][nf] = __builtin_amdgcn_mfma_f32_16x16x32_bf16(a1, bx, vacc[1][nf], 0, 0, 0);
        if (wave < 3)
          xacc[nf] = __builtin_amdgcn_mfma_f32_16x16x32_bf16(ax, bx, xacc[nf], 0, 0, 0);
      }
    }

#pragma unroll
    for (int mf = 0; mf < 2; ++mf) {
#pragma unroll
      for (int r = 0; r < 4; ++r) {
        float s = 0.f;
#pragma unroll
        for (int nf = 0; nf < 4; ++nf) s += vacc[mf][nf][r];
        sv[mf][r] += s;
        int c = ocb + mf * 16 + cg * 4 + r;
#pragma unroll
        for (int nf = 0; nf < 4; ++nf)
          Vl[c * 136 + (hf * 4 + nf) * 16 + l15] = f2bf(vacc[mf][nf][r] + bvr[mf][r]);
      }
    }

    if (wave < 2) {
#pragma unroll
      for (int r = 0; r < 4; ++r) {
        int oc = wave * 16 + cg * 4 + r;
        float* op = out + ((size_t)(b * 128 + oc)) * NPIX + pbase + l15;
#pragma unroll
        for (int nf = 0; nf < 4; ++nf)
          op[(hf * 4 + nf) * 16] = fmaxf(xacc[nf][r] + xb4[r], 0.f);
      }
    } else if (wave == 2) {
#pragma unroll
      for (int nf = 0; nf < 4; ++nf) {
        int nfg = hf * 4 + nf;
        float kq[4]; float s2 = 0.f;
#pragma unroll
        for (int r = 0; r < 4; ++r) {
          kq[r] = xacc[nf][r] + xb4[r];
          s2 = fmaf(kq[r], kq[r], s2);
        }
        s2 += __shfl_xor(s2, 16);
        s2 += __shfl_xor(s2, 32);
        float inv = rsqrtf(s2);
#pragma unroll
        for (int r = 0; r < 4; ++r) {
          float kn = kq[r] * inv;
          knl[(cg * 4 + r) * 136 + nfg * 16 + l15] = f2bf(kn);
          kr[r] += kn;
        }
      }
    }
  }
  __syncthreads();

#pragma unroll
  for (int ks = 0; ks < 4; ++ks) {
    bf16x8 af = *(const bf16x8*)(knl + l15 * 136 + ks * 32 + cg * 8);
    bf16x8 b0 = *(const bf16x8*)(Vl + (size_t)(ocb + l15) * 136 + ks * 32 + cg * 8);
    bf16x8 b1 = *(const bf16x8*)(Vl + (size_t)(ocb + 16 + l15) * 136 + ks * 32 + cg * 8);
    am[0] = __builtin_amdgcn_mfma_f32_16x16x32_bf16(af, b0, am[0], 0, 0, 0);
    am[1] = __builtin_amdgcn_mfma_f32_16x16x32_bf16(af, b1, am[1], 0, 0, 0);
  }

  float* pp = (blk < 64) ? (part1 + ((size_t)b * 64 + blk) * 2192)
                         : (part2 + ((size_t)b * 64 + (blk - 64)) * 2192);
#pragma unroll
  for (int nf2 = 0; nf2 < 2; ++nf2)
#pragma unroll
    for (int r = 0; r < 4; ++r)
      pp[(cg * 4 + r) * 128 + ocb + nf2 * 16 + l15] = am[nf2][r];
#pragma unroll
  for (int off = 1; off < 16; off <<= 1) {
#pragma unroll
    for (int mf = 0; mf < 2; ++mf)
#pragma unroll
      for (int r = 0; r < 4; ++r)
        sv[mf][r] += __shfl_xor(sv[mf][r], off);
  }
  if (l15 == 0) {
#pragma unroll
    for (int mf = 0; mf < 2; ++mf)
#pragma unroll
      for (int r = 0; r < 4; ++r) {
        int c = ocb + mf * 16 + cg * 4 + r;
        pp[2048 + c] = sv[mf][r] + 128.f * bv[c];
      }
  }
  if (wave == 2) {
#pragma unroll
    for (int off = 1; off < 16; off <<= 1) {
#pragma unroll
      for (int r = 0; r < 4; ++r)
        kr[r] += __shfl_xor(kr[r], off);
    }
    if (l15 == 0) {
#pragma unroll
      for (int r = 0; r < 4; ++r)
        pp[2048 + 128 + cg * 4 + r] = kr[r];
    }
  }
}

// ---------------- cf (fallback) ----------------
__global__ __launch_bounds__(256) void cf_kernel(const float* __restrict__ x,
                                                 const float* __restrict__ bv,
                                                 const float* __restrict__ Kbuf,
                                                 const float* __restrict__ wvt,
                                                 float* __restrict__ part) {
  __shared__ float Vl[128 * 129];
  __shared__ float knl[16 * 132];
  int t   = threadIdx.x;
  int b   = blockIdx.y;
  int blk = blockIdx.x;
  const float* Kb = Kbuf + (size_t)b * 16 * NPIX;
  const float* xb = x + (size_t)b * 128 * NPIX;

  int m_own = t & 15;
  int c0    = (t >> 4) << 3;
  int pxg   = t & 15;

  float bvr[8];
#pragma unroll
  for (int jj = 0; jj < 8; ++jj) bvr[jj] = bv[c0 + jj];

  float macc[8] = {0,0,0,0,0,0,0,0};
  float vs[8]   = {0,0,0,0,0,0,0,0};
  float ksum[16];
#pragma unroll
  for (int m = 0; m < 16; ++m) ksum[m] = 0.f;

  for (int tile = blk; tile < 128; tile += 64) {
    __syncthreads();
    int pbase = tile << 7;

    if (t < 128) {
      float kv[16]; float ss = 0.f;
#pragma unroll
      for (int m = 0; m < 16; ++m) {
        kv[m] = Kb[(size_t)m * NPIX + pbase + t];
        ss = fmaf(kv[m], kv[m], ss);
      }
      float inv = rsqrtf(ss);
#pragma unroll
      for (int m = 0; m < 16; ++m) {
        float kn = kv[m] * inv;
        knl[m * 132 + t] = kn;
        ksum[m] += kn;
      }
    }

    float v[8][8];
#pragma unroll
    for (int i = 0; i < 8; ++i)
#pragma unroll
      for (int jj = 0; jj < 8; ++jj) v[i][jj] = 0.f;
    int px0 = pbase + (pxg << 3);
    for (int k = 0; k < 128; ++k) {
      const float4* xp = (const float4*)(xb + (size_t)k * NPIX + px0);
      float4 xa = xp[0], xc4 = xp[1];
      const float4* wp = (const float4*)(wvt + k * 128 + c0);
      float4 wa = wp[0], wc4 = wp[1];
      float xv[8] = {xa.x, xa.y, xa.z, xa.w, xc4.x, xc4.y, xc4.z, xc4.w};
      float wr[8] = {wa.x, wa.y, wa.z, wa.w, wc4.x, wc4.y, wc4.z, wc4.w};
#pragma unroll
      for (int i = 0; i < 8; ++i)
#pragma unroll
        for (int jj = 0; jj < 8; ++jj)
          v[i][jj] = fmaf(wr[i], xv[jj], v[i][jj]);
    }
#pragma unroll
    for (int i = 0; i < 8; ++i)
#pragma unroll
      for (int jj = 0; jj < 8; ++jj)
        Vl[(c0 + i) * 129 + (pxg << 3) + jj] = v[i][jj] + bvr[i];
    __syncthreads();

    for (int px = 0; px < 128; ++px) {
      float knv = knl[m_own * 132 + px];
      float vv[8];
#pragma unroll
      for (int jj = 0; jj < 8; ++jj) vv[jj] = Vl[(c0 + jj) * 129 + px];
#pragma unroll
      for (int jj = 0; jj < 8; ++jj) macc[jj] = fmaf(knv, vv[jj], macc[jj]);
      if (m_own == 0) {
#pragma unroll
        for (int jj = 0; jj < 8; ++jj) vs[jj] += vv[jj];
      }
    }
  }

  int blkid = b * 64 + blk;
  float* pp = part + (size_t)blkid * 2192;
#pragma unroll
  for (int jj = 0; jj < 8; ++jj) pp[m_own * 128 + c0 + jj] = macc[jj];
  if (m_own == 0) {
#pragma unroll
    for (int jj = 0; jj < 8; ++jj) pp[2048 + c0 + jj] = vs[jj];
  }
  __syncthreads();
  if (t < 128) {
#pragma unroll
    for (int m = 0; m < 16; ++m) knl[m * 132 + t] = ksum[m];
  }
  __syncthreads();
  if (t < 16) {
    float s = 0.f;
    for (int i = 0; i < 128; ++i) s += knl[t * 132 + i];
    pp[2048 + 128 + t] = s;
  }
}

// ---------------- reduce (fallback: 64 groups) ----------------
__global__ void reduce_kernel(const float* __restrict__ part, float* __restrict__ stats) {
  int b = blockIdx.y, t = threadIdx.x;
  int e = blockIdx.x * 256 + t;
  if (e >= 2192) return;
  const float* pp = part + (size_t)b * 64 * 2192;
  float s = 0.f;
  for (int g = 0; g < 64; ++g) s += pp[(size_t)g * 2192 + e];
  stats[(size_t)b * 2192 + e] = s;
}

// ---------------- reduce2 (mfma: 64 + 64 groups) ----------------
__global__ void reduce2_kernel(const float* __restrict__ part1,
                               const float* __restrict__ part2,
                               float* __restrict__ stats) {
  int b = blockIdx.y, t = threadIdx.x;
  int e = blockIdx.x * 256 + t;
  if (e >= 2192) return;
  const float* p1 = part1 + (size_t)b * 64 * 2192;
  const float* p2 = part2 + (size_t)b * 64 * 2192;
  float s = 0.f;
  for (int g = 0; g < 64; ++g) s += p1[(size_t)g * 2192 + e];
  for (int g = 0; g < 64; ++g) s += p2[(size_t)g * 2192 + e];
  stats[(size_t)b * 2192 + e] = s;
}

// ---------------- d1: Q + tailor per pixel -> sq[16], tl ----------------
__global__ __launch_bounds__(256) void d1_kernel(const float* __restrict__ stats,
                                                 const float* __restrict__ wq,
                                                 const float* __restrict__ bq,
                                                 const float* __restrict__ gamma,
                                                 const float* __restrict__ out,
                                                 float* __restrict__ sq,
                                                 float* __restrict__ tlb) {
  __shared__ float wql[128 * 16];   // [c][m]
  __shared__ float ksl[16];
  int t = threadIdx.x;
  int b = blockIdx.y;
  const float* st = stats + (size_t)b * 2192;
  for (int i = t; i < 2048; i += 256) {
    int m = i >> 7, c = i & 127;
    wql[c * 16 + m] = wq[m * 128 + c];
  }
  if (t < 16) ksl[t] = st[2048 + 128 + t] + EPS_V;
  __syncthreads();

  int px = blockIdx.x * 256 + t;
  const float* ob = out + (size_t)b * 128 * NPIX;

  float q[16];
#pragma unroll
  for (int m = 0; m < 16; ++m) q[m] = bq[m];
  for (int c = 0; c < 128; ++c) {
    float xv = ob[(size_t)c * NPIX + px];
    const float4* wp = (const float4*)(wql + c * 16);
#pragma unroll
    for (int jj = 0; jj < 4; ++jj) {
      float4 w = wp[jj];
      q[jj*4+0] = fmaf(w.x, xv, q[jj*4+0]);
      q[jj*4+1] = fmaf(w.y, xv, q[jj*4+1]);
      q[jj*4+2] = fmaf(w.z, xv, q[jj*4+2]);
      q[jj*4+3] = fmaf(w.w, xv, q[jj*4+3]);
    }
  }
  float ss = 0.f;
#pragma unroll
  for (int m = 0; m < 16; ++m) ss = fmaf(q[m], q[m], ss);
  float inv = rsqrtf(ss);
#pragma unroll
  for (int m = 0; m < 16; ++m) q[m] *= inv;
  float den = (float)NPIX;
#pragma unroll
  for (int m = 0; m < 16; ++m) den = fmaf(q[m], ksl[m], den);
  float tl = gamma[0] / den;

  tlb[(size_t)b * NPIX + px] = tl;
#pragma unroll
  for (int m = 0; m < 16; ++m)
    sq[((size_t)(b * 16 + m)) * NPIX + px] = tl * q[m];
}

// ---------------- d2: out[c][px] = vsl[c]*tl + mat[m][c]*sq[m] ----------------
__global__ __launch_bounds__(256) void d2_kernel(const float* __restrict__ stats,
                                                 const float* __restrict__ sq,
                                                 const float* __restrict__ tlb,
                                                 float* __restrict__ out) {
  __shared__ float matl[128 * 16];  // [c][m]
  __shared__ float vsl[128];
  int t = threadIdx.x;
  int b = blockIdx.y;
  const float* st = stats + (size_t)b * 2192;
  for (int i = t; i < 2048; i += 256) {
    int m = i >> 7, c = i & 127;
    matl[c * 16 + m] = st[i];
  }
  if (t < 128) vsl[t] = st[2048 + t];
  __syncthreads();

  int px = blockIdx.x * 256 + t;
  float* ob = out + (size_t)b * 128 * NPIX;

  float tlv = tlb[(size_t)b * NPIX + px];
  float sv[16];
#pragma unroll
  for (int m = 0; m < 16; ++m)
    sv[m] = sq[((size_t)(b * 16 + m)) * NPIX + px];

  for (int c = 0; c < 128; ++c) {
    float s = vsl[c] * tlv;
    const float4* mp = (const float4*)(matl + c * 16);
#pragma unroll
    for (int jj = 0; jj < 4; ++jj) {
      float4 w = mp[jj];
      s = fmaf(w.x, sv[jj*4+0], s);
      s = fmaf(w.y, sv[jj*4+1], s);
      s = fmaf(w.z, sv[jj*4+2], s);
      s = fmaf(w.w, sv[jj*4+3], s);
    }
    ob[(size_t)c * NPIX + px] = s;
  }
}

// ---------------- df (fallback final) ----------------
__global__ __launch_bounds__(256) void df_kernel(const float* __restrict__ stats,
                                                 const float* __restrict__ wq,
                                                 const float* __restrict__ bq,
                                                 const float* __restrict__ gamma,
                                                 float* __restrict__ out) {
  __shared__ float matl[128 * 16];
  __shared__ float wql[128 * 16];
  __shared__ float vsl[128];
  __shared__ float ksl[16];
  int t = threadIdx.x;
  int b = blockIdx.y;
  const float* st = stats + (size_t)b * 2192;
  for (int i = t; i < 2048; i += 256) {
    int m = i >> 7, c = i & 127;
    matl[c * 16 + m] = st[i];
    wql[c * 16 + m]  = wq[m * 128 + c];
  }
  if (t < 128) vsl[t] = st[2048 + t];
  if (t < 16)  ksl[t] = st[2048 + 128 + t] + EPS_V;
  __syncthreads();

  int px = blockIdx.x * 256 + t;
  float* ob = out + (size_t)b * 128 * NPIX;

  float q[16];
#pragma unroll
  for (int m = 0; m < 16; ++m) q[m] = bq[m];
  for (int c = 0; c < 128; ++c) {
    float xv = ob[(size_t)c * NPIX + px];
    const float4* wp = (const float4*)(wql + c * 16);
#pragma unroll
    for (int jj = 0; jj < 4; ++jj) {
      float4 w = wp[jj];
      q[jj*4+0] = fmaf(w.x, xv, q[jj*4+0]);
      q[jj*4+1] = fmaf(w.y, xv, q[jj*4+1]);
      q[jj*4+2] = fmaf(w.z, xv, q[jj*4+2]);
      q[jj*4+3] = fmaf(w.w, xv, q[jj*4+3]);
    }
  }
  float ss = 0.f;
#pragma unroll
  for (int m = 0; m < 16; ++m) ss = fmaf(q[m], q[m], ss);
  float inv = rsqrtf(ss);
#pragma unroll
  for (int m = 0; m < 16; ++m) q[m] *= inv;
  float den = (float)NPIX;
#pragma unroll
  for (int m = 0; m < 16; ++m) den = fmaf(q[m], ksl[m], den);
  float tl = gamma[0] / den;

  for (int c = 0; c < 128; ++c) {
    float s = vsl[c];
    const float4* mp = (const float4*)(matl + c * 16);
#pragma unroll
    for (int jj = 0; jj < 4; ++jj) {
      float4 w = mp[jj];
      s = fmaf(w.x, q[jj*4+0], s);
      s = fmaf(w.y, q[jj*4+1], s);
      s = fmaf(w.z, q[jj*4+2], s);
      s = fmaf(w.w, q[jj*4+3], s);
    }
    ob[(size_t)c * NPIX + px] = tl * s;
  }
}

extern "C" void kernel_launch(void* const* d_in, const int* in_sizes, int n_in,
                              void* d_out, int out_size, void* d_ws, size_t ws_size,
                              hipStream_t stream) {
  (void)in_sizes; (void)n_in; (void)out_size;
  const float* x   = (const float*)d_in[0];
  const float* w1  = (const float*)d_in[1];
  const float* w2  = (const float*)d_in[2];
  const float* w3  = (const float*)d_in[3];
  const float* w4  = (const float*)d_in[4];
  const float* bns = (const float*)d_in[5];
  const float* bnb = (const float*)d_in[6];
  const float* bnm = (const float*)d_in[7];
  const float* bnv = (const float*)d_in[8];
  const float* wq  = (const float*)d_in[9];
  const float* bq  = (const float*)d_in[10];
  const float* wk  = (const float*)d_in[11];
  const float* bk  = (const float*)d_in[12];
  const float* wv  = (const float*)d_in[13];
  const float* bv  = (const float*)d_in[14];
  const float* gm  = (const float*)d_in[15];
  float* ws  = (float*)d_ws;
  float* out = (float*)d_out;

  float* Kbuf = ws + OFF_K;
  float* w1f  = ws + OFF_W1F;
  float* wkt  = ws + OFF_WKT;
  float* wvt  = ws + OFF_WVT;
  float* bfp  = ws + OFF_BF;
  float* part = ws + OFF_PART;
  float* stat = ws + OFF_STATS;

  prep_common_kernel<<<64, 256, 0, stream>>>(w1, bns, bnb, bnm, bnv, wk, wv,
                                             w1f, wkt, wvt, bfp);

  bool use_mfma = ws_size >= NEW_END * sizeof(float);
  if (use_mfma) {
    unsigned short* wbtr = (unsigned short*)(ws + OFF_WBT);
    unsigned short* xt   = (unsigned short*)(ws + OFF_XT);
    unsigned short* wvbr = (unsigned short*)(ws + OFF_WVB);
    unsigned short* zrow = (unsigned short*)(ws + OFF_ZROW);
    unsigned short* wxbr = (unsigned short*)(ws + OFF_K);   // first 6144 floats of K region
    float* part2 = ws + OFF_PART2;                          // K region tail (dead in mfma path)
    float* sq  = ws + OFF_SQ;   // reuses xt region (dead after cm)
    float* tlb = ws + OFF_TL;
    prep_convb_kernel<<<64, 256, 0, stream>>>(w1, w2, w3, w4, bns, bnv, wk, wv,
                                              wbtr, wvbr, wxbr, zrow);
    a0_kernel<<<dim3(256, 8), 256, 0, stream>>>(x, xt);
    a2m_kernel<<<dim3(1536), 256, 0, stream>>>(xt, zrow, wbtr, bfp, out);
    cm_kernel<<<dim3(1024), 256, 0, stream>>>(xt, wvbr, wxbr, bv, bfp, bk, out, part, part2);
    reduce2_kernel<<<dim3(9, 8), 256, 0, stream>>>(part, part2, stat);
    d1_kernel<<<dim3(64, 8), 256, 0, stream>>>(stat, wq, bq, gm, out, sq, tlb);
    d2_kernel<<<dim3(64, 8), 256, 0, stream>>>(stat, sq, tlb, out);
  } else {
    float* w24t = ws + OFF_W24T;
    prep_convf_kernel<<<64, 256, 0, stream>>>(w2, w3, w4, bns, bnv, w24t);
    a1_kernel<<<dim3(64, 8), 256, 0, stream>>>(x, w1f, wkt, bfp, bk, out, Kbuf);
    a2f_kernel<<<dim3(32, 8, 3), 256, 0, stream>>>(x, w24t, bfp, out);
    cf_kernel<<<dim3(64, 8), 256, 0, stream>>>(x, bv, Kbuf, wvt, part);
    reduce_kernel<<<dim3(9, 8), 256, 0, stream>>>(part, stat);
    df_kernel<<<dim3(64, 8), 256, 0, stream>>>(stat, wq, bq, gm, out);
  }
}

// Round 11
// 138.473 us; speedup vs baseline: 1.6376x; 1.0558x over previous
//
#include <hip/hip_runtime.h>
#include <hip/hip_bf16.h>
#include <math.h>

#define NPIX   16384
#define BATCH  8
#define BN_EPS 1e-5f
#define EPS_V  1e-6f

typedef __attribute__((ext_vector_type(8))) short bf16x8;
typedef __attribute__((ext_vector_type(4))) float f32x4;
typedef const __attribute__((address_space(1))) unsigned int* gas_ptr;
typedef __attribute__((address_space(3))) unsigned int* las_ptr;

// ---- workspace layout (float offsets) ----
// common
#define OFF_K     ((size_t)0)          // fallback: Kbuf. mfma path: wxbr + part2
#define OFF_PART2 ((size_t)8192)       // mfma: 512*2192 = 1122304 (ends 1130496 < 2097152)
#define OFF_W1F   ((size_t)2097152)    // 128*32   = 4096
#define OFF_WKT   ((size_t)2101248)    // 128*16   = 2048
#define OFF_WVT   ((size_t)2103296)    // 128*128  = 16384
#define OFF_BF    ((size_t)2119680)    // 4*32     = 128
#define OFF_PART  ((size_t)2119808)    // 512*2192 = 1122304
#define OFF_STATS ((size_t)3242112)    // 8*2192   = 17536
#define BASE_END  ((size_t)3259648)
// new (bf16-MFMA) path extras
#define OFF_WBT   BASE_END             // 3*9*4*2*64*8 ushort = 55296 floats
#define OFF_XT    ((size_t)3314976)    // 8*4*16384*32 ushort = 8388608 floats (PRE-SWIZZLED)
#define OFF_WVB   ((size_t)11703584)   // 4*8*64*8 ushort = 8192 floats
#define OFF_ZROW  ((size_t)11711776)   // 4096 ushort zero row = 2048 floats
#define NEW_END   ((size_t)11713824)
// old (fp32) fallback extras
#define OFF_W24T  BASE_END             // 3*128*9*32 = 110592

__device__ inline unsigned short f2bf(float f) {
  union { float f; unsigned int u; } v; v.f = f;
  unsigned int r = (v.u + 0x7FFFu + ((v.u >> 16) & 1u)) >> 16;
  return (unsigned short)r;
}

// ---------------- prep_common ----------------
__global__ void prep_common_kernel(const float* __restrict__ w1,
                                   const float* __restrict__ bns, const float* __restrict__ bnb,
                                   const float* __restrict__ bnm, const float* __restrict__ bnv,
                                   const float* __restrict__ wk, const float* __restrict__ wv,
                                   float* __restrict__ w1f, float* __restrict__ wkt,
                                   float* __restrict__ wvt, float* __restrict__ bf) {
  int tid = blockIdx.x * blockDim.x + threadIdx.x;
  int nt  = gridDim.x * blockDim.x;
  for (int i = tid; i < 128; i += nt) {
    float inv = bns[i] * rsqrtf(bnv[i] + BN_EPS);
    bf[i] = bnb[i] - bnm[i] * inv;
  }
  for (int i = tid; i < 4096; i += nt) {          // w1f[c][o]
    int c = i >> 5, o = i & 31;
    float inv = bns[o] * rsqrtf(bnv[o] + BN_EPS);
    w1f[i] = w1[o * 128 + c] * inv;
  }
  for (int i = tid; i < 2048; i += nt) {          // wkt[c][m]
    int c = i >> 4, m = i & 15;
    wkt[i] = wk[m * 128 + c];
  }
  for (int i = tid; i < 16384; i += nt) {         // wvt[c][o]
    int c = i >> 7, o = i & 127;
    wvt[i] = wv[o * 128 + c];
  }
}

// ---------------- prep_convb: MFMA-fragment-ordered bf16 weights + zero row ----------------
__global__ void prep_convb_kernel(const float* __restrict__ w1,
                                  const float* __restrict__ w2, const float* __restrict__ w3,
                                  const float* __restrict__ w4,
                                  const float* __restrict__ bns, const float* __restrict__ bnv,
                                  const float* __restrict__ wk, const float* __restrict__ wv,
                                  unsigned short* __restrict__ wbtr,
                                  unsigned short* __restrict__ wvbr,
                                  unsigned short* __restrict__ wxbr,
                                  unsigned short* __restrict__ zrow) {
  int tid = blockIdx.x * blockDim.x + threadIdx.x;
  int nt  = gridDim.x * blockDim.x;
  for (int i = tid; i < 4096; i += nt) zrow[i] = 0;
  for (int i = tid; i < 16384; i += nt) {
    int e = i & 7, lane = (i >> 3) & 63, f = (i >> 9) & 7, q = i >> 12;
    int oc = f * 16 + (lane & 15);
    int c  = q * 32 + (lane >> 4) * 8 + e;
    wvbr[i] = f2bf(wv[oc * 128 + c]);
  }
  for (int i = tid; i < 6144; i += nt) {
    int e = i & 7, lane = (i >> 3) & 63, ct = i >> 9;
    int tile = ct % 3, q = ct / 3;
    int c = q * 32 + (lane >> 4) * 8 + e;
    float val;
    if (tile < 2) {
      int oc = tile * 16 + (lane & 15);
      val = w1[oc * 128 + c] * (bns[oc] * rsqrtf(bnv[oc] + BN_EPS));
    } else {
      val = wk[(lane & 15) * 128 + c];
    }
    wxbr[i] = f2bf(val);
  }
  for (int i = tid; i < 110592; i += nt) {
    int br = i / 36864;
    int r  = i - br * 36864;
    int tap  = r >> 12;
    int r2   = r & 4095;
    int q    = r2 >> 10;
    int r3   = r2 & 1023;
    int pair = r3 >> 9;
    int r4   = r3 & 511;
    int lane = r4 >> 3, e = r4 & 7;
    int oc = pair * 16 + (lane & 15);
    int c  = q * 32 + (lane >> 4) * 8 + e;
    const float* w = (br == 0) ? w2 : ((br == 1) ? w3 : w4);
    int bo = (br + 1) * 32 + oc;
    float inv = bns[bo] * rsqrtf(bnv[bo] + BN_EPS);
    wbtr[i] = f2bf(w[(oc * 128 + c) * 9 + tap] * inv);
  }
}

// ---------------- prep_convf (fallback) ----------------
__global__ void prep_convf_kernel(const float* __restrict__ w2, const float* __restrict__ w3,
                                  const float* __restrict__ w4,
                                  const float* __restrict__ bns, const float* __restrict__ bnv,
                                  float* __restrict__ w24t) {
  int tid = blockIdx.x * blockDim.x + threadIdx.x;
  int nt  = gridDim.x * blockDim.x;
  for (int i = tid; i < 110592; i += nt) {
    int br  = i / 36864;
    int rem = i - br * 36864;
    int c   = rem / 288;
    int k   = (rem % 288) >> 5;
    int o   = rem & 31;
    const float* w = (br == 0) ? w2 : ((br == 1) ? w3 : w4);
    int bo = (br + 1) * 32 + o;
    float inv = bns[bo] * rsqrtf(bnv[bo] + BN_EPS);
    w24t[i] = w[(o * 128 + c) * 9 + k] * inv;
  }
}

// ---------------- a0: transpose x -> xt bf16, quarter-major, PRE-SWIZZLED 16B units ----------------
__global__ __launch_bounds__(256) void a0_kernel(const float* __restrict__ x,
                                                 unsigned short* __restrict__ xt) {
  __shared__ unsigned short Ts[64][132];
  int t   = threadIdx.x;
  int b   = blockIdx.y;
  int px0 = blockIdx.x * 64;
  const float* xb = x + (size_t)b * 128 * NPIX;
  int p = t & 63, cq = t >> 6;
#pragma unroll 8
  for (int i = 0; i < 32; ++i) {
    int c = cq * 32 + i;
    Ts[p][c] = f2bf(xb[(size_t)c * NPIX + px0 + p]);
  }
  __syncthreads();
  int pw = t >> 2, cg = t & 3;   // cg == quarter
  unsigned short* dst = xt + ((size_t)(b * 4 + cg) * 16384 + px0 + pw) * 32;
  int sw = (pw >> 1) & 3;
#pragma unroll
  for (int k = 0; k < 8; ++k) {
    uint2 v = *(const uint2*)(&Ts[pw][cg * 32 + k * 4]);
    int cgs = (k >> 1) ^ sw;
    *(uint2*)(dst + cgs * 8 + (k & 1) * 4) = v;
  }
}

// ---------------- a1 (fallback only) ----------------
__global__ __launch_bounds__(256) void a1_kernel(const float* __restrict__ x,
                                                 const float* __restrict__ w1f,
                                                 const float* __restrict__ wkt,
                                                 const float* __restrict__ bfp,
                                                 const float* __restrict__ bk,
                                                 float* __restrict__ out,
                                                 float* __restrict__ Kbuf) {
  __shared__ float lw1[128 * 32];
  __shared__ float lwk[128 * 16];
  __shared__ float lbf[32];
  int t = threadIdx.x;
  for (int i = t; i < 4096; i += 256) lw1[i] = w1f[i];
  for (int i = t; i < 2048; i += 256) lwk[i] = wkt[i];
  if (t < 32) lbf[t] = bfp[t];
  __syncthreads();

  int b  = blockIdx.y;
  int px = blockIdx.x * 256 + t;
  const float* xb = x + (size_t)b * 128 * NPIX;

  float acc[48];
#pragma unroll
  for (int i = 0; i < 48; ++i) acc[i] = 0.f;

  for (int c = 0; c < 128; ++c) {
    float xv = xb[(size_t)c * NPIX + px];
    const float4* w1p = (const float4*)(lw1 + c * 32);
#pragma unroll
    for (int j = 0; j < 8; ++j) {
      float4 w = w1p[j];
      acc[j*4+0] = fmaf(w.x, xv, acc[j*4+0]);
      acc[j*4+1] = fmaf(w.y, xv, acc[j*4+1]);
      acc[j*4+2] = fmaf(w.z, xv, acc[j*4+2]);
      acc[j*4+3] = fmaf(w.w, xv, acc[j*4+3]);
    }
    const float4* wkp = (const float4*)(lwk + c * 16);
#pragma unroll
    for (int j = 0; j < 4; ++j) {
      float4 w = wkp[j];
      acc[32+j*4+0] = fmaf(w.x, xv, acc[32+j*4+0]);
      acc[32+j*4+1] = fmaf(w.y, xv, acc[32+j*4+1]);
      acc[32+j*4+2] = fmaf(w.z, xv, acc[32+j*4+2]);
      acc[32+j*4+3] = fmaf(w.w, xv, acc[32+j*4+3]);
    }
  }
#pragma unroll
  for (int o = 0; o < 32; ++o)
    out[((size_t)(b * 128 + o)) * NPIX + px] = fmaxf(acc[o] + lbf[o], 0.f);
#pragma unroll
  for (int m = 0; m < 16; ++m)
    Kbuf[((size_t)(b * 16 + m)) * NPIX + px] = acc[32 + m] + bk[m];
}

// ---------------- a2m v6: counted-vmcnt 2-deep pipeline, 3 LDS buffers, global_load_lds ----------------
__global__ __launch_bounds__(256) void a2m_kernel(const unsigned short* __restrict__ xt,
                                                  const unsigned short* __restrict__ zrow,
                                                  const unsigned short* __restrict__ wbtr,
                                                  const float* __restrict__ bfp,
                                                  float* __restrict__ out) {
  __shared__ unsigned short sx[3 * 8192 + 8];   // 3x16KB sub-buffers + 16B zero page @byte 49152
  int t    = threadIdx.x;
  int wave = t >> 6, lane = t & 63;
  int l15  = lane & 15, cg = lane >> 4;
  int idx  = blockIdx.x;
  int b    = idx & 7;                           // batch -> XCD
  int rest = idx >> 3;
  int h2   = rest & 63;
  int br   = rest >> 6;
  int d    = 6 * (br + 1);
  int h0   = h2 * 2;
  int j    = wave >> 1;                         // row of the pair this wave computes/stages
  int whalf = wave & 1;                         // px half (compute) / row half (stage)
  int p0   = whalf * 64;

  if (t == 0) *(uint4*)(sx + 24576) = make_uint4(0u, 0u, 0u, 0u);

  const unsigned short* wb    = wbtr + (size_t)br * 36864;
  const unsigned short* slabs = xt + (size_t)b * 4 * 524288;

  f32x4 acc[2][4];
#pragma unroll
  for (int i = 0; i < 2; ++i)
#pragma unroll
    for (int n = 0; n < 4; ++n) acc[i][n] = (f32x4){0.f, 0.f, 0.f, 0.f};

  int pxb[3], xorv[3];
#pragma unroll
  for (int kw = 0; kw < 3; ++kw) {
    pxb[kw]  = p0 + l15 + (kw - 1) * d;
    xorv[kw] = (cg ^ ((pxb[kw] >> 1) & 3)) << 4;
  }

  // stage step s = q*3+kh: copy this wave's row of quarter q into buffer s%3 (4 loads/thread).
  auto STAGE = [&](int s) {
    int q = s / 3, kh = s % 3;
    int srow = h0 + j + (kh - 1) * d;
    const unsigned short* rowsrc =
        ((unsigned)srow < 128u) ? (slabs + (size_t)q * 524288 + (size_t)srow * 4096)
                                : zrow;
    const unsigned short* gsrc = rowsrc + whalf * 2048 + lane * 8;
    unsigned short* lbase = sx + (s % 3) * 8192 + j * 4096 + whalf * 2048;
#pragma unroll
    for (int k = 0; k < 4; ++k)
      __builtin_amdgcn_global_load_lds((gas_ptr)(const void*)(gsrc + k * 512),
                                       (las_ptr)(void*)(lbase + k * 512), 16, 0, 0);
  };

  auto COMPUTE = [&](int s) {
    int q = s / 3, kh = s % 3;
    int bb = (s % 3) * 16384 + j * 8192;        // byte base of this wave's row
    bf16x8 a[3][2];
#pragma unroll
    for (int kw = 0; kw < 3; ++kw) {
      int tap = kh * 3 + kw;
      const unsigned short* wt = wb + ((((size_t)tap * 4 + q) * 2) << 9);
      a[kw][0] = *(const bf16x8*)(wt + lane * 8);
      a[kw][1] = *(const bf16x8*)(wt + 512 + lane * 8);
    }
#pragma unroll
    for (int kw = 0; kw < 3; ++kw) {
      int base = bb + pxb[kw] * 64 + xorv[kw];
#pragma unroll
      for (int nf = 0; nf < 4; ++nf) {
        int px   = pxb[kw] + nf * 16;
        int addr = ((unsigned)px < 128u) ? (base + nf * 1024) : 49152;
        bf16x8 bv = *(const bf16x8*)((const char*)sx + addr);
        acc[0][nf] = __builtin_amdgcn_mfma_f32_16x16x32_bf16(a[kw][0], bv, acc[0][nf], 0, 0, 0);
        acc[1][nf] = __builtin_amdgcn_mfma_f32_16x16x32_bf16(a[kw][1], bv, acc[1][nf], 0, 0, 0);
      }
    }
  };

  STAGE(0);
  STAGE(1);
  __syncthreads();                              // full drain once: buffers 0,1 ready; zero page visible
  for (int s = 0; s < 12; ++s) {
    COMPUTE(s);
    if (s < 10) STAGE(s + 2);                   // keep 2 stages in flight
    if (s < 11) {
      // end of step s: buffer (s+1)%3 must be ready. Outstanding (this wave):
      // STAGE(s+1) [4, issued step s-1] + STAGE(s+2) [4, issued now] -> vmcnt(4)
      // retires oldest-first = STAGE(s+1). Last iter (s=10): only STAGE(11) -> vmcnt(0).
      if (s < 10) asm volatile("s_waitcnt vmcnt(4)" ::: "memory");
      else        asm volatile("s_waitcnt vmcnt(0)" ::: "memory");
      __builtin_amdgcn_s_barrier();
      __builtin_amdgcn_sched_barrier(0);        // keep next step's ds_reads below the barrier
    }
  }

  int ocb = (br + 1) * 32;
  int pxw = (h0 + j) * 128 + p0;
#pragma unroll
  for (int mf = 0; mf < 2; ++mf) {
#pragma unroll
    for (int r = 0; r < 4; ++r) {
      int oc = mf * 16 + cg * 4 + r;
      float bias = bfp[ocb + oc];
      float* op = out + ((size_t)(b * 128 + ocb + oc)) * NPIX + pxw + l15;
#pragma unroll
      for (int nf = 0; nf < 4; ++nf)
        op[nf * 16] = fmaxf(acc[mf][nf][r] + bias, 0.f);
    }
  }
}

// ---------------- a2f (fallback) ----------------
__global__ __launch_bounds__(256) void a2f_kernel(const float* __restrict__ x,
                                                  const float* __restrict__ w24t,
                                                  const float* __restrict__ bfp,
                                                  float* __restrict__ out) {
  int t  = threadIdx.x;
  int og = t & 3;
  int pg = (t >> 2) & 15;
  int r  = t >> 6;
  int br = blockIdx.z;
  int b  = blockIdx.y;
  int h  = blockIdx.x * 4 + r;
  int d  = 6 * (br + 1);

  const float* wt = w24t + (size_t)br * 36864;
  const float* bf = bfp + (br + 1) * 32;
  const float* xb = x + (size_t)b * 128 * NPIX;
  int w0 = pg << 3;

  float acc[8][8];
#pragma unroll
  for (int p = 0; p < 8; ++p)
#pragma unroll
    for (int o = 0; o < 8; ++o) acc[p][o] = 0.f;

  for (int c = 0; c < 128; ++c) {
    const float* xc = xb + (size_t)c * NPIX;
    const float* wc = wt + c * 288;
#pragma unroll
    for (int kh = 0; kh < 3; ++kh) {
      int row = h + (kh - 1) * d;
      if ((unsigned)row >= 128u) continue;
      const float* xr = xc + row * 128;
#pragma unroll
      for (int kw = 0; kw < 3; ++kw) {
        int wb = w0 + (kw - 1) * d;
        float xv[8];
        if (wb >= 0 && wb <= 120) {
          const float2* p2 = (const float2*)(xr + wb);
#pragma unroll
          for (int jj = 0; jj < 4; ++jj) {
            float2 v = p2[jj];
            xv[2*jj] = v.x; xv[2*jj+1] = v.y;
          }
        } else {
#pragma unroll
          for (int jj = 0; jj < 8; ++jj) {
            int ww = wb + jj;
            xv[jj] = ((unsigned)ww < 128u) ? xr[ww] : 0.f;
          }
        }
        const float4* wp = (const float4*)(wc + (kh * 3 + kw) * 32 + og * 8);
        float4 wa = wp[0], wbv = wp[1];
        float wr[8] = {wa.x, wa.y, wa.z, wa.w, wbv.x, wbv.y, wbv.z, wbv.w};
#pragma unroll
        for (int p = 0; p < 8; ++p)
#pragma unroll
          for (int o = 0; o < 8; ++o)
            acc[p][o] = fmaf(xv[p], wr[o], acc[p][o]);
      }
    }
  }

  int chbase = (br + 1) * 32 + og * 8;
  int n = h * 128 + w0;
#pragma unroll
  for (int o = 0; o < 8; ++o) {
    float bias = bf[og * 8 + o];
    float* op = out + ((size_t)(b * 128 + chbase + o)) * NPIX + n;
    float4 v0 = make_float4(fmaxf(acc[0][o] + bias, 0.f), fmaxf(acc[1][o] + bias, 0.f),
                            fmaxf(acc[2][o] + bias, 0.f), fmaxf(acc[3][o] + bias, 0.f));
    float4 v1 = make_float4(fmaxf(acc[4][o] + bias, 0.f), fmaxf(acc[5][o] + bias, 0.f),
                            fmaxf(acc[6][o] + bias, 0.f), fmaxf(acc[7][o] + bias, 0.f));
    ((float4*)op)[0] = v0;
    ((float4*)op)[1] = v1;
  }
}

// ---------------- cm v7: 1 tile/block, batch->XCD swizzle, swizzled-xt reads ----------------
__global__ __launch_bounds__(256) void cm_kernel(const unsigned short* __restrict__ xt,
                                                 const unsigned short* __restrict__ wvbr,
                                                 const unsigned short* __restrict__ wxbr,
                                                 const float* __restrict__ bv,
                                                 const float* __restrict__ bfp,
                                                 const float* __restrict__ bk,
                                                 float* __restrict__ out,
                                                 float* __restrict__ part1,
                                                 float* __restrict__ part2) {
  __shared__ __align__(16) unsigned short Vl[128 * 136];   // bf16 [oc][px]
  __shared__ __align__(16) unsigned short knl[16 * 136];   // bf16 [m][px]
  int t    = threadIdx.x;
  int idx  = blockIdx.x;
  int b    = idx & 7;           // batch -> XCD (1024 % 8 == 0, bijective)
  int blk  = idx >> 3;          // 0..127 == tile
  int wave = t >> 6, lane = t & 63;
  int l15  = lane & 15, cg = lane >> 4;
  int ocb  = wave * 32;
  int pbase = blk << 7;
  int cgsw = (cg ^ ((l15 >> 1) & 3)) << 3;   // swizzled-xt unit offset (ushorts)

  float bvr[2][4];
#pragma unroll
  for (int mf = 0; mf < 2; ++mf)
#pragma unroll
    for (int r = 0; r < 4; ++r) bvr[mf][r] = bv[ocb + mf * 16 + cg * 4 + r];

  float xb4[4];
#pragma unroll
  for (int r = 0; r < 4; ++r) xb4[r] = 0.f;
  if (wave == 0) {
#pragma unroll
    for (int r = 0; r < 4; ++r) xb4[r] = bfp[cg * 4 + r];
  } else if (wave == 1) {
#pragma unroll
    for (int r = 0; r < 4; ++r) xb4[r] = bfp[16 + cg * 4 + r];
  } else if (wave == 2) {
#pragma unroll
    for (int r = 0; r < 4; ++r) xb4[r] = bk[cg * 4 + r];
  }
  int xwave = (wave < 3) ? wave : 0;

  float kr[4] = {0.f, 0.f, 0.f, 0.f};
  float sv[2][4];
#pragma unroll
  for (int mf = 0; mf < 2; ++mf)
#pragma unroll
    for (int r = 0; r < 4; ++r) sv[mf][r] = 0.f;
  f32x4 am[2];
  am[0] = (f32x4){0.f,0.f,0.f,0.f};
  am[1] = (f32x4){0.f,0.f,0.f,0.f};

#pragma unroll
  for (int hf = 0; hf < 2; ++hf) {
    f32x4 vacc[2][4];
    f32x4 xacc[4];
#pragma unroll
    for (int i = 0; i < 2; ++i)
#pragma unroll
      for (int n = 0; n < 4; ++n) vacc[i][n] = (f32x4){0.f,0.f,0.f,0.f};
#pragma unroll
    for (int n = 0; n < 4; ++n) xacc[n] = (f32x4){0.f,0.f,0.f,0.f};

#pragma unroll
    for (int cc = 0; cc < 4; ++cc) {
      const unsigned short* xq = xt + ((size_t)(b * 4 + cc) * 16384 + pbase) * 32;
      bf16x8 a0 = *(const bf16x8*)(wvbr + ((cc * 8 + wave * 2 + 0) << 9) + lane * 8);
      bf16x8 a1 = *(const bf16x8*)(wvbr + ((cc * 8 + wave * 2 + 1) << 9) + lane * 8);
      bf16x8 ax = *(const bf16x8*)(wxbr + ((cc * 3 + xwave) << 9) + lane * 8);
#pragma unroll
      for (int nf = 0; nf < 4; ++nf) {
        int nfg = hf * 4 + nf;
        bf16x8 bx = *(const bf16x8*)(xq + (size_t)(nfg * 16 + l15) * 32 + cgsw);
        vacc[0][nf] = __builtin_amdgcn_mfma_f32_16x16x32_bf16(a0, bx, vacc[0][nf], 0, 0, 0);
        vacc[1][nf] = __builtin_amdgcn_mfma_f32_16x16x32_bf16(a1, bx, vacc[1][nf], 0, 0, 0);
        if (wave < 3)
          xacc[nf] = __builtin_amdgcn_mfma_f32_16x16x32_bf16(ax, bx, xacc[nf], 0, 0, 0);
      }
    }

#pragma unroll
    for (int mf = 0; mf < 2; ++mf) {
#pragma unroll
      for (int r = 0; r < 4; ++r) {
        float s = 0.f;
#pragma unroll
        for (int nf = 0; nf < 4; ++nf) s += vacc[mf][nf][r];
        sv[mf][r] += s;
        int c = ocb + mf * 16 + cg * 4 + r;
#pragma unroll
        for (int nf = 0; nf < 4; ++nf)
          Vl[c * 136 + (hf * 4 + nf) * 16 + l15] = f2bf(vacc[mf][nf][r] + bvr[mf][r]);
      }
    }

    if (wave < 2) {
#pragma unroll
      for (int r = 0; r < 4; ++r) {
        int oc = wave * 16 + cg * 4 + r;
        float* op = out + ((size_t)(b * 128 + oc)) * NPIX + pbase + l15;
#pragma unroll
        for (int nf = 0; nf < 4; ++nf)
          op[(hf * 4 + nf) * 16] = fmaxf(xacc[nf][r] + xb4[r], 0.f);
      }
    } else if (wave == 2) {
#pragma unroll
      for (int nf = 0; nf < 4; ++nf) {
        int nfg = hf * 4 + nf;
        float kq[4]; float s2 = 0.f;
#pragma unroll
        for (int r = 0; r < 4; ++r) {
          kq[r] = xacc[nf][r] + xb4[r];
          s2 = fmaf(kq[r], kq[r], s2);
        }
        s2 += __shfl_xor(s2, 16);
        s2 += __shfl_xor(s2, 32);
        float inv = rsqrtf(s2);
#pragma unroll
        for (int r = 0; r < 4; ++r) {
          float kn = kq[r] * inv;
          knl[(cg * 4 + r) * 136 + nfg * 16 + l15] = f2bf(kn);
          kr[r] += kn;
        }
      }
    }
  }
  __syncthreads();

#pragma unroll
  for (int ks = 0; ks < 4; ++ks) {
    bf16x8 af = *(const bf16x8*)(knl + l15 * 136 + ks * 32 + cg * 8);
    bf16x8 b0 = *(const bf16x8*)(Vl + (size_t)(ocb + l15) * 136 + ks * 32 + cg * 8);
    bf16x8 b1 = *(const bf16x8*)(Vl + (size_t)(ocb + 16 + l15) * 136 + ks * 32 + cg * 8);
    am[0] = __builtin_amdgcn_mfma_f32_16x16x32_bf16(af, b0, am[0], 0, 0, 0);
    am[1] = __builtin_amdgcn_mfma_f32_16x16x32_bf16(af, b1, am[1], 0, 0, 0);
  }

  float* pp = (blk < 64) ? (part1 + ((size_t)b * 64 + blk) * 2192)
                         : (part2 + ((size_t)b * 64 + (blk - 64)) * 2192);
#pragma unroll
  for (int nf2 = 0; nf2 < 2; ++nf2)
#pragma unroll
    for (int r = 0; r < 4; ++r)
      pp[(cg * 4 + r) * 128 + ocb + nf2 * 16 + l15] = am[nf2][r];
#pragma unroll
  for (int off = 1; off < 16; off <<= 1) {
#pragma unroll
    for (int mf = 0; mf < 2; ++mf)
#pragma unroll
      for (int r = 0; r < 4; ++r)
        sv[mf][r] += __shfl_xor(sv[mf][r], off);
  }
  if (l15 == 0) {
#pragma unroll
    for (int mf = 0; mf < 2; ++mf)
#pragma unroll
      for (int r = 0; r < 4; ++r) {
        int c = ocb + mf * 16 + cg * 4 + r;
        pp[2048 + c] = sv[mf][r] + 128.f * bv[c];
      }
  }
  if (wave == 2) {
#pragma unroll
    for (int off = 1; off < 16; off <<= 1) {
#pragma unroll
      for (int r = 0; r < 4; ++r)
        kr[r] += __shfl_xor(kr[r], off);
    }
    if (l15 == 0) {
#pragma unroll
      for (int r = 0; r < 4; ++r)
        pp[2048 + 128 + cg * 4 + r] = kr[r];
    }
  }
}

// ---------------- cf (fallback) ----------------
__global__ __launch_bounds__(256) void cf_kernel(const float* __restrict__ x,
                                                 const float* __restrict__ bv,
                                                 const float* __restrict__ Kbuf,
                                                 const float* __restrict__ wvt,
                                                 float* __restrict__ part) {
  __shared__ float Vl[128 * 129];
  __shared__ float knl[16 * 132];
  int t   = threadIdx.x;
  int b   = blockIdx.y;
  int blk = blockIdx.x;
  const float* Kb = Kbuf + (size_t)b * 16 * NPIX;
  const float* xb = x + (size_t)b * 128 * NPIX;

  int m_own = t & 15;
  int c0    = (t >> 4) << 3;
  int pxg   = t & 15;

  float bvr[8];
#pragma unroll
  for (int jj = 0; jj < 8; ++jj) bvr[jj] = bv[c0 + jj];

  float macc[8] = {0,0,0,0,0,0,0,0};
  float vs[8]   = {0,0,0,0,0,0,0,0};
  float ksum[16];
#pragma unroll
  for (int m = 0; m < 16; ++m) ksum[m] = 0.f;

  for (int tile = blk; tile < 128; tile += 64) {
    __syncthreads();
    int pbase = tile << 7;

    if (t < 128) {
      float kv[16]; float ss = 0.f;
#pragma unroll
      for (int m = 0; m < 16; ++m) {
        kv[m] = Kb[(size_t)m * NPIX + pbase + t];
        ss = fmaf(kv[m], kv[m], ss);
      }
      float inv = rsqrtf(ss);
#pragma unroll
      for (int m = 0; m < 16; ++m) {
        float kn = kv[m] * inv;
        knl[m * 132 + t] = kn;
        ksum[m] += kn;
      }
    }

    float v[8][8];
#pragma unroll
    for (int i = 0; i < 8; ++i)
#pragma unroll
      for (int jj = 0; jj < 8; ++jj) v[i][jj] = 0.f;
    int px0 = pbase + (pxg << 3);
    for (int k = 0; k < 128; ++k) {
      const float4* xp = (const float4*)(xb + (size_t)k * NPIX + px0);
      float4 xa = xp[0], xc4 = xp[1];
      const float4* wp = (const float4*)(wvt + k * 128 + c0);
      float4 wa = wp[0], wc4 = wp[1];
      float xv[8] = {xa.x, xa.y, xa.z, xa.w, xc4.x, xc4.y, xc4.z, xc4.w};
      float wr[8] = {wa.x, wa.y, wa.z, wa.w, wc4.x, wc4.y, wc4.z, wc4.w};
#pragma unroll
      for (int i = 0; i < 8; ++i)
#pragma unroll
        for (int jj = 0; jj < 8; ++jj)
          v[i][jj] = fmaf(wr[i], xv[jj], v[i][jj]);
    }
#pragma unroll
    for (int i = 0; i < 8; ++i)
#pragma unroll
      for (int jj = 0; jj < 8; ++jj)
        Vl[(c0 + i) * 129 + (pxg << 3) + jj] = v[i][jj] + bvr[i];
    __syncthreads();

    for (int px = 0; px < 128; ++px) {
      float knv = knl[m_own * 132 + px];
      float vv[8];
#pragma unroll
      for (int jj = 0; jj < 8; ++jj) vv[jj] = Vl[(c0 + jj) * 129 + px];
#pragma unroll
      for (int jj = 0; jj < 8; ++jj) macc[jj] = fmaf(knv, vv[jj], macc[jj]);
      if (m_own == 0) {
#pragma unroll
        for (int jj = 0; jj < 8; ++jj) vs[jj] += vv[jj];
      }
    }
  }

  int blkid = b * 64 + blk;
  float* pp = part + (size_t)blkid * 2192;
#pragma unroll
  for (int jj = 0; jj < 8; ++jj) pp[m_own * 128 + c0 + jj] = macc[jj];
  if (m_own == 0) {
#pragma unroll
    for (int jj = 0; jj < 8; ++jj) pp[2048 + c0 + jj] = vs[jj];
  }
  __syncthreads();
  if (t < 128) {
#pragma unroll
    for (int m = 0; m < 16; ++m) knl[m * 132 + t] = ksum[m];
  }
  __syncthreads();
  if (t < 16) {
    float s = 0.f;
    for (int i = 0; i < 128; ++i) s += knl[t * 132 + i];
    pp[2048 + 128 + t] = s;
  }
}

// ---------------- reduce (fallback: 64 groups) ----------------
__global__ void reduce_kernel(const float* __restrict__ part, float* __restrict__ stats) {
  int b = blockIdx.y, t = threadIdx.x;
  int e = blockIdx.x * 256 + t;
  if (e >= 2192) return;
  const float* pp = part + (size_t)b * 64 * 2192;
  float s = 0.f;
  for (int g = 0; g < 64; ++g) s += pp[(size_t)g * 2192 + e];
  stats[(size_t)b * 2192 + e] = s;
}

// ---------------- reduce2 (mfma: 64 + 64 groups) ----------------
__global__ void reduce2_kernel(const float* __restrict__ part1,
                               const float* __restrict__ part2,
                               float* __restrict__ stats) {
  int b = blockIdx.y, t = threadIdx.x;
  int e = blockIdx.x * 256 + t;
  if (e >= 2192) return;
  const float* p1 = part1 + (size_t)b * 64 * 2192;
  const float* p2 = part2 + (size_t)b * 64 * 2192;
  float s = 0.f;
  for (int g = 0; g < 64; ++g) s += p1[(size_t)g * 2192 + e];
  for (int g = 0; g < 64; ++g) s += p2[(size_t)g * 2192 + e];
  stats[(size_t)b * 2192 + e] = s;
}

// ---------------- df: fused Q + tailor + final output (1 px/thread) ----------------
__global__ __launch_bounds__(256) void df_kernel(const float* __restrict__ stats,
                                                 const float* __restrict__ wq,
                                                 const float* __restrict__ bq,
                                                 const float* __restrict__ gamma,
                                                 float* __restrict__ out) {
  __shared__ float matl[128 * 16];
  __shared__ float wql[128 * 16];
  __shared__ float vsl[128];
  __shared__ float ksl[16];
  int t = threadIdx.x;
  int b = blockIdx.y;
  const float* st = stats + (size_t)b * 2192;
  for (int i = t; i < 2048; i += 256) {
    int m = i >> 7, c = i & 127;
    matl[c * 16 + m] = st[i];
    wql[c * 16 + m]  = wq[m * 128 + c];
  }
  if (t < 128) vsl[t] = st[2048 + t];
  if (t < 16)  ksl[t] = st[2048 + 128 + t] + EPS_V;
  __syncthreads();

  int px = blockIdx.x * 256 + t;
  float* ob = out + (size_t)b * 128 * NPIX;

  float q[16];
#pragma unroll
  for (int m = 0; m < 16; ++m) q[m] = bq[m];
  for (int c = 0; c < 128; ++c) {
    float xv = ob[(size_t)c * NPIX + px];
    const float4* wp = (const float4*)(wql + c * 16);
#pragma unroll
    for (int jj = 0; jj < 4; ++jj) {
      float4 w = wp[jj];
      q[jj*4+0] = fmaf(w.x, xv, q[jj*4+0]);
      q[jj*4+1] = fmaf(w.y, xv, q[jj*4+1]);
      q[jj*4+2] = fmaf(w.z, xv, q[jj*4+2]);
      q[jj*4+3] = fmaf(w.w, xv, q[jj*4+3]);
    }
  }
  float ss = 0.f;
#pragma unroll
  for (int m = 0; m < 16; ++m) ss = fmaf(q[m], q[m], ss);
  float inv = rsqrtf(ss);
#pragma unroll
  for (int m = 0; m < 16; ++m) q[m] *= inv;
  float den = (float)NPIX;
#pragma unroll
  for (int m = 0; m < 16; ++m) den = fmaf(q[m], ksl[m], den);
  float tl = gamma[0] / den;

  for (int c = 0; c < 128; ++c) {
    float s = vsl[c];
    const float4* mp = (const float4*)(matl + c * 16);
#pragma unroll
    for (int jj = 0; jj < 4; ++jj) {
      float4 w = mp[jj];
      s = fmaf(w.x, q[jj*4+0], s);
      s = fmaf(w.y, q[jj*4+1], s);
      s = fmaf(w.z, q[jj*4+2], s);
      s = fmaf(w.w, q[jj*4+3], s);
    }
    ob[(size_t)c * NPIX + px] = tl * s;
  }
}

extern "C" void kernel_launch(void* const* d_in, const int* in_sizes, int n_in,
                              void* d_out, int out_size, void* d_ws, size_t ws_size,
                              hipStream_t stream) {
  (void)in_sizes; (void)n_in; (void)out_size;
  const float* x   = (const float*)d_in[0];
  const float* w1  = (const float*)d_in[1];
  const float* w2  = (const float*)d_in[2];
  const float* w3  = (const float*)d_in[3];
  const float* w4  = (const float*)d_in[4];
  const float* bns = (const float*)d_in[5];
  const float* bnb = (const float*)d_in[6];
  const float* bnm = (const float*)d_in[7];
  const float* bnv = (const float*)d_in[8];
  const float* wq  = (const float*)d_in[9];
  const float* bq  = (const float*)d_in[10];
  const float* wk  = (const float*)d_in[11];
  const float* bk  = (const float*)d_in[12];
  const float* wv  = (const float*)d_in[13];
  const float* bv  = (const float*)d_in[14];
  const float* gm  = (const float*)d_in[15];
  float* ws  = (float*)d_ws;
  float* out = (float*)d_out;

  float* Kbuf = ws + OFF_K;
  float* w1f  = ws + OFF_W1F;
  float* wkt  = ws + OFF_WKT;
  float* wvt  = ws + OFF_WVT;
  float* bfp  = ws + OFF_BF;
  float* part = ws + OFF_PART;
  float* stat = ws + OFF_STATS;

  prep_common_kernel<<<64, 256, 0, stream>>>(w1, bns, bnb, bnm, bnv, wk, wv,
                                             w1f, wkt, wvt, bfp);

  bool use_mfma = ws_size >= NEW_END * sizeof(float);
  if (use_mfma) {
    unsigned short* wbtr = (unsigned short*)(ws + OFF_WBT);
    unsigned short* xt   = (unsigned short*)(ws + OFF_XT);
    unsigned short* wvbr = (unsigned short*)(ws + OFF_WVB);
    unsigned short* zrow = (unsigned short*)(ws + OFF_ZROW);
    unsigned short* wxbr = (unsigned short*)(ws + OFF_K);   // first 6144 floats of K region
    float* part2 = ws + OFF_PART2;                          // K region tail (dead in mfma path)
    prep_convb_kernel<<<64, 256, 0, stream>>>(w1, w2, w3, w4, bns, bnv, wk, wv,
                                              wbtr, wvbr, wxbr, zrow);
    a0_kernel<<<dim3(256, 8), 256, 0, stream>>>(x, xt);
    a2m_kernel<<<dim3(1536), 256, 0, stream>>>(xt, zrow, wbtr, bfp, out);
    cm_kernel<<<dim3(1024), 256, 0, stream>>>(xt, wvbr, wxbr, bv, bfp, bk, out, part, part2);
    reduce2_kernel<<<dim3(9, 8), 256, 0, stream>>>(part, part2, stat);
    df_kernel<<<dim3(64, 8), 256, 0, stream>>>(stat, wq, bq, gm, out);
  } else {
    float* w24t = ws + OFF_W24T;
    prep_convf_kernel<<<64, 256, 0, stream>>>(w2, w3, w4, bns, bnv, w24t);
    a1_kernel<<<dim3(64, 8), 256, 0, stream>>>(x, w1f, wkt, bfp, bk, out, Kbuf);
    a2f_kernel<<<dim3(32, 8, 3), 256, 0, stream>>>(x, w24t, bfp, out);
    cf_kernel<<<dim3(64, 8), 256, 0, stream>>>(x, bv, Kbuf, wvt, part);
    reduce_kernel<<<dim3(9, 8), 256, 0, stream>>>(part, stat);
    df_kernel<<<dim3(64, 8), 256, 0, stream>>>(stat, wq, bq, gm, out);
  }
}

// Round 12
// 137.852 us; speedup vs baseline: 1.6450x; 1.0045x over previous
//
#include <hip/hip_runtime.h>
#include <hip/hip_bf16.h>
#include <math.h>

#define NPIX   16384
#define BATCH  8
#define BN_EPS 1e-5f
#define EPS_V  1e-6f

typedef __attribute__((ext_vector_type(8))) short bf16x8;
typedef __attribute__((ext_vector_type(4))) float f32x4;
typedef const __attribute__((address_space(1))) unsigned int* gas_ptr;
typedef __attribute__((address_space(3))) unsigned int* las_ptr;

// ---- workspace layout (float offsets) ----
// common
#define OFF_K     ((size_t)0)          // fallback: Kbuf. mfma path: wxbr + part2
#define OFF_PART2 ((size_t)8192)       // mfma: 512*2192 = 1122304 (ends 1130496 < 2097152)
#define OFF_W1F   ((size_t)2097152)    // 128*32   = 4096
#define OFF_WKT   ((size_t)2101248)    // 128*16   = 2048
#define OFF_WVT   ((size_t)2103296)    // 128*128  = 16384
#define OFF_BF    ((size_t)2119680)    // 4*32     = 128
#define OFF_PART  ((size_t)2119808)    // 512*2192 = 1122304
#define OFF_STATS ((size_t)3242112)    // 8*2192   = 17536
#define BASE_END  ((size_t)3259648)
// new (bf16-MFMA) path extras
#define OFF_WBT   BASE_END             // 3*9*4*2*64*8 ushort = 55296 floats
#define OFF_XT    ((size_t)3314976)    // 8*4*16384*32 ushort = 8388608 floats (PRE-SWIZZLED)
#define OFF_WVB   ((size_t)11703584)   // 4*8*64*8 ushort = 8192 floats
#define OFF_ZROW  ((size_t)11711776)   // 4096 ushort zero row = 2048 floats
#define NEW_END   ((size_t)11713824)
// old (fp32) fallback extras
#define OFF_W24T  BASE_END             // 3*128*9*32 = 110592

__device__ inline unsigned short f2bf(float f) {
  union { float f; unsigned int u; } v; v.f = f;
  unsigned int r = (v.u + 0x7FFFu + ((v.u >> 16) & 1u)) >> 16;
  return (unsigned short)r;
}

// ---------------- prep_common (fallback path only) ----------------
__global__ void prep_common_kernel(const float* __restrict__ w1,
                                   const float* __restrict__ bns, const float* __restrict__ bnb,
                                   const float* __restrict__ bnm, const float* __restrict__ bnv,
                                   const float* __restrict__ wk, const float* __restrict__ wv,
                                   float* __restrict__ w1f, float* __restrict__ wkt,
                                   float* __restrict__ wvt, float* __restrict__ bf) {
  int tid = blockIdx.x * blockDim.x + threadIdx.x;
  int nt  = gridDim.x * blockDim.x;
  for (int i = tid; i < 128; i += nt) {
    float inv = bns[i] * rsqrtf(bnv[i] + BN_EPS);
    bf[i] = bnb[i] - bnm[i] * inv;
  }
  for (int i = tid; i < 4096; i += nt) {          // w1f[c][o]
    int c = i >> 5, o = i & 31;
    float inv = bns[o] * rsqrtf(bnv[o] + BN_EPS);
    w1f[i] = w1[o * 128 + c] * inv;
  }
  for (int i = tid; i < 2048; i += nt) {          // wkt[c][m]
    int c = i >> 4, m = i & 15;
    wkt[i] = wk[m * 128 + c];
  }
  for (int i = tid; i < 16384; i += nt) {         // wvt[c][o]
    int c = i >> 7, o = i & 127;
    wvt[i] = wv[o * 128 + c];
  }
}

// ---------------- prep_convb: fragment-ordered bf16 weights + bf + zero row (mfma path) ----------------
__global__ void prep_convb_kernel(const float* __restrict__ w1,
                                  const float* __restrict__ w2, const float* __restrict__ w3,
                                  const float* __restrict__ w4,
                                  const float* __restrict__ bns, const float* __restrict__ bnb,
                                  const float* __restrict__ bnm, const float* __restrict__ bnv,
                                  const float* __restrict__ wk, const float* __restrict__ wv,
                                  unsigned short* __restrict__ wbtr,
                                  unsigned short* __restrict__ wvbr,
                                  unsigned short* __restrict__ wxbr,
                                  unsigned short* __restrict__ zrow,
                                  float* __restrict__ bf) {
  int tid = blockIdx.x * blockDim.x + threadIdx.x;
  int nt  = gridDim.x * blockDim.x;
  for (int i = tid; i < 128; i += nt) {           // folded BN bias
    float inv = bns[i] * rsqrtf(bnv[i] + BN_EPS);
    bf[i] = bnb[i] - bnm[i] * inv;
  }
  for (int i = tid; i < 4096; i += nt) zrow[i] = 0;
  for (int i = tid; i < 16384; i += nt) {
    int e = i & 7, lane = (i >> 3) & 63, f = (i >> 9) & 7, q = i >> 12;
    int oc = f * 16 + (lane & 15);
    int c  = q * 32 + (lane >> 4) * 8 + e;
    wvbr[i] = f2bf(wv[oc * 128 + c]);
  }
  for (int i = tid; i < 6144; i += nt) {
    int e = i & 7, lane = (i >> 3) & 63, ct = i >> 9;
    int tile = ct % 3, q = ct / 3;
    int c = q * 32 + (lane >> 4) * 8 + e;
    float val;
    if (tile < 2) {
      int oc = tile * 16 + (lane & 15);
      val = w1[oc * 128 + c] * (bns[oc] * rsqrtf(bnv[oc] + BN_EPS));
    } else {
      val = wk[(lane & 15) * 128 + c];
    }
    wxbr[i] = f2bf(val);
  }
  for (int i = tid; i < 110592; i += nt) {
    int br = i / 36864;
    int r  = i - br * 36864;
    int tap  = r >> 12;
    int r2   = r & 4095;
    int q    = r2 >> 10;
    int r3   = r2 & 1023;
    int pair = r3 >> 9;
    int r4   = r3 & 511;
    int lane = r4 >> 3, e = r4 & 7;
    int oc = pair * 16 + (lane & 15);
    int c  = q * 32 + (lane >> 4) * 8 + e;
    const float* w = (br == 0) ? w2 : ((br == 1) ? w3 : w4);
    int bo = (br + 1) * 32 + oc;
    float inv = bns[bo] * rsqrtf(bnv[bo] + BN_EPS);
    wbtr[i] = f2bf(w[(oc * 128 + c) * 9 + tap] * inv);
  }
}

// ---------------- prep_convf (fallback) ----------------
__global__ void prep_convf_kernel(const float* __restrict__ w2, const float* __restrict__ w3,
                                  const float* __restrict__ w4,
                                  const float* __restrict__ bns, const float* __restrict__ bnv,
                                  float* __restrict__ w24t) {
  int tid = blockIdx.x * blockDim.x + threadIdx.x;
  int nt  = gridDim.x * blockDim.x;
  for (int i = tid; i < 110592; i += nt) {
    int br  = i / 36864;
    int rem = i - br * 36864;
    int c   = rem / 288;
    int k   = (rem % 288) >> 5;
    int o   = rem & 31;
    const float* w = (br == 0) ? w2 : ((br == 1) ? w3 : w4);
    int bo = (br + 1) * 32 + o;
    float inv = bns[bo] * rsqrtf(bnv[bo] + BN_EPS);
    w24t[i] = w[(o * 128 + c) * 9 + k] * inv;
  }
}

// ---------------- a0: transpose x -> xt bf16, quarter-major, PRE-SWIZZLED 16B units ----------------
__global__ __launch_bounds__(256) void a0_kernel(const float* __restrict__ x,
                                                 unsigned short* __restrict__ xt) {
  __shared__ unsigned short Ts[64][132];
  int t   = threadIdx.x;
  int b   = blockIdx.y;
  int px0 = blockIdx.x * 64;
  const float* xb = x + (size_t)b * 128 * NPIX;
  int p = t & 63, cq = t >> 6;
#pragma unroll 8
  for (int i = 0; i < 32; ++i) {
    int c = cq * 32 + i;
    Ts[p][c] = f2bf(xb[(size_t)c * NPIX + px0 + p]);
  }
  __syncthreads();
  int pw = t >> 2, cg = t & 3;   // cg == quarter
  unsigned short* dst = xt + ((size_t)(b * 4 + cg) * 16384 + px0 + pw) * 32;
  int sw = (pw >> 1) & 3;
#pragma unroll
  for (int k = 0; k < 8; ++k) {
    uint2 v = *(const uint2*)(&Ts[pw][cg * 32 + k * 4]);
    int cgs = (k >> 1) ^ sw;
    *(uint2*)(dst + cgs * 8 + (k & 1) * 4) = v;
  }
}

// ---------------- a1 (fallback only) ----------------
__global__ __launch_bounds__(256) void a1_kernel(const float* __restrict__ x,
                                                 const float* __restrict__ w1f,
                                                 const float* __restrict__ wkt,
                                                 const float* __restrict__ bfp,
                                                 const float* __restrict__ bk,
                                                 float* __restrict__ out,
                                                 float* __restrict__ Kbuf) {
  __shared__ float lw1[128 * 32];
  __shared__ float lwk[128 * 16];
  __shared__ float lbf[32];
  int t = threadIdx.x;
  for (int i = t; i < 4096; i += 256) lw1[i] = w1f[i];
  for (int i = t; i < 2048; i += 256) lwk[i] = wkt[i];
  if (t < 32) lbf[t] = bfp[t];
  __syncthreads();

  int b  = blockIdx.y;
  int px = blockIdx.x * 256 + t;
  const float* xb = x + (size_t)b * 128 * NPIX;

  float acc[48];
#pragma unroll
  for (int i = 0; i < 48; ++i) acc[i] = 0.f;

  for (int c = 0; c < 128; ++c) {
    float xv = xb[(size_t)c * NPIX + px];
    const float4* w1p = (const float4*)(lw1 + c * 32);
#pragma unroll
    for (int j = 0; j < 8; ++j) {
      float4 w = w1p[j];
      acc[j*4+0] = fmaf(w.x, xv, acc[j*4+0]);
      acc[j*4+1] = fmaf(w.y, xv, acc[j*4+1]);
      acc[j*4+2] = fmaf(w.z, xv, acc[j*4+2]);
      acc[j*4+3] = fmaf(w.w, xv, acc[j*4+3]);
    }
    const float4* wkp = (const float4*)(lwk + c * 16);
#pragma unroll
    for (int j = 0; j < 4; ++j) {
      float4 w = wkp[j];
      acc[32+j*4+0] = fmaf(w.x, xv, acc[32+j*4+0]);
      acc[32+j*4+1] = fmaf(w.y, xv, acc[32+j*4+1]);
      acc[32+j*4+2] = fmaf(w.z, xv, acc[32+j*4+2]);
      acc[32+j*4+3] = fmaf(w.w, xv, acc[32+j*4+3]);
    }
  }
#pragma unroll
  for (int o = 0; o < 32; ++o)
    out[((size_t)(b * 128 + o)) * NPIX + px] = fmaxf(acc[o] + lbf[o], 0.f);
#pragma unroll
  for (int m = 0; m < 16; ++m)
    Kbuf[((size_t)(b * 16 + m)) * NPIX + px] = acc[32 + m] + bk[m];
}

// ---------------- a2m v7: 2x16KB buffers (5 blocks/CU), 1-deep pipeline, in-reg OOB zeroing ----------------
__global__ __launch_bounds__(256) void a2m_kernel(const unsigned short* __restrict__ xt,
                                                  const unsigned short* __restrict__ zrow,
                                                  const unsigned short* __restrict__ wbtr,
                                                  const float* __restrict__ bfp,
                                                  float* __restrict__ out) {
  __shared__ unsigned short sx[2 * 8192];       // exactly 32768 B -> 5 blocks/CU
  int t    = threadIdx.x;
  int wave = t >> 6, lane = t & 63;
  int l15  = lane & 15, cg = lane >> 4;
  int idx  = blockIdx.x;
  int b    = idx & 7;                           // batch -> XCD
  int rest = idx >> 3;
  int h2   = rest & 63;
  int br   = rest >> 6;
  int d    = 6 * (br + 1);
  int h0   = h2 * 2;
  int j    = wave >> 1;                         // row of the pair this wave computes/stages
  int whalf = wave & 1;                         // px half (compute) / row half (stage)
  int p0   = whalf * 64;

  const unsigned short* wb    = wbtr + (size_t)br * 36864;
  const unsigned short* slabs = xt + (size_t)b * 4 * 524288;

  f32x4 acc[2][4];
#pragma unroll
  for (int i = 0; i < 2; ++i)
#pragma unroll
    for (int n = 0; n < 4; ++n) acc[i][n] = (f32x4){0.f, 0.f, 0.f, 0.f};

  int pxb[3], xorv[3];
#pragma unroll
  for (int kw = 0; kw < 3; ++kw) {
    pxb[kw]  = p0 + l15 + (kw - 1) * d;
    xorv[kw] = (cg ^ ((pxb[kw] >> 1) & 3)) << 4;
  }

  // stage step s = q*3+kh: copy this wave's row of quarter q into buffer s&1 (4 loads/thread).
  auto STAGE = [&](int s) {
    int q = s / 3, kh = s % 3;
    int srow = h0 + j + (kh - 1) * d;
    const unsigned short* rowsrc =
        ((unsigned)srow < 128u) ? (slabs + (size_t)q * 524288 + (size_t)srow * 4096)
                                : zrow;
    const unsigned short* gsrc = rowsrc + whalf * 2048 + lane * 8;
    unsigned short* lbase = sx + (s & 1) * 8192 + j * 4096 + whalf * 2048;
#pragma unroll
    for (int k = 0; k < 4; ++k)
      __builtin_amdgcn_global_load_lds((gas_ptr)(const void*)(gsrc + k * 512),
                                       (las_ptr)(void*)(lbase + k * 512), 16, 0, 0);
  };

  auto COMPUTE = [&](int s) {
    int q = s / 3, kh = s % 3;
    int bb = (s & 1) * 16384 + j * 8192;        // byte base of this wave's row
    bf16x8 a[3][2];
#pragma unroll
    for (int kw = 0; kw < 3; ++kw) {
      int tap = kh * 3 + kw;
      const unsigned short* wt = wb + ((((size_t)tap * 4 + q) * 2) << 9);
      a[kw][0] = *(const bf16x8*)(wt + lane * 8);
      a[kw][1] = *(const bf16x8*)(wt + 512 + lane * 8);
    }
#pragma unroll
    for (int kw = 0; kw < 3; ++kw) {
      int base = bb + pxb[kw] * 64 + xorv[kw];
#pragma unroll
      for (int nf = 0; nf < 4; ++nf) {
        int px      = pxb[kw] + nf * 16;
        bool ok     = ((unsigned)px < 128u);
        int addr    = ok ? (base + nf * 1024) : bb;     // any in-buffer addr when OOB
        unsigned m  = ok ? 0xFFFFFFFFu : 0u;
        uint4 u = *(const uint4*)((const char*)sx + addr);
        u.x &= m; u.y &= m; u.z &= m; u.w &= m;         // zero OOB fragment in-register
        bf16x8 bv;
        __builtin_memcpy(&bv, &u, 16);
        acc[0][nf] = __builtin_amdgcn_mfma_f32_16x16x32_bf16(a[kw][0], bv, acc[0][nf], 0, 0, 0);
        acc[1][nf] = __builtin_amdgcn_mfma_f32_16x16x32_bf16(a[kw][1], bv, acc[1][nf], 0, 0, 0);
      }
    }
  };

  STAGE(0);
  asm volatile("s_waitcnt vmcnt(0)" ::: "memory");
  __builtin_amdgcn_s_barrier();
  __builtin_amdgcn_sched_barrier(0);
  for (int s = 0; s < 12; ++s) {
    if (s < 11) STAGE(s + 1);                   // next-step loads fly under this step's compute
    COMPUTE(s);
    if (s < 11) {
      asm volatile("s_waitcnt vmcnt(0)" ::: "memory");
      __builtin_amdgcn_s_barrier();
      __builtin_amdgcn_sched_barrier(0);        // keep next step's ds_reads below the barrier
    }
  }

  int ocb = (br + 1) * 32;
  int pxw = (h0 + j) * 128 + p0;
#pragma unroll
  for (int mf = 0; mf < 2; ++mf) {
#pragma unroll
    for (int r = 0; r < 4; ++r) {
      int oc = mf * 16 + cg * 4 + r;
      float bias = bfp[ocb + oc];
      float* op = out + ((size_t)(b * 128 + ocb + oc)) * NPIX + pxw + l15;
#pragma unroll
      for (int nf = 0; nf < 4; ++nf)
        op[nf * 16] = fmaxf(acc[mf][nf][r] + bias, 0.f);
    }
  }
}

// ---------------- a2f (fallback) ----------------
__global__ __launch_bounds__(256) void a2f_kernel(const float* __restrict__ x,
                                                  const float* __restrict__ w24t,
                                                  const float* __restrict__ bfp,
                                                  float* __restrict__ out) {
  int t  = threadIdx.x;
  int og = t & 3;
  int pg = (t >> 2) & 15;
  int r  = t >> 6;
  int br = blockIdx.z;
  int b  = blockIdx.y;
  int h  = blockIdx.x * 4 + r;
  int d  = 6 * (br + 1);

  const float* wt = w24t + (size_t)br * 36864;
  const float* bf = bfp + (br + 1) * 32;
  const float* xb = x + (size_t)b * 128 * NPIX;
  int w0 = pg << 3;

  float acc[8][8];
#pragma unroll
  for (int p = 0; p < 8; ++p)
#pragma unroll
    for (int o = 0; o < 8; ++o) acc[p][o] = 0.f;

  for (int c = 0; c < 128; ++c) {
    const float* xc = xb + (size_t)c * NPIX;
    const float* wc = wt + c * 288;
#pragma unroll
    for (int kh = 0; kh < 3; ++kh) {
      int row = h + (kh - 1) * d;
      if ((unsigned)row >= 128u) continue;
      const float* xr = xc + row * 128;
#pragma unroll
      for (int kw = 0; kw < 3; ++kw) {
        int wb = w0 + (kw - 1) * d;
        float xv[8];
        if (wb >= 0 && wb <= 120) {
          const float2* p2 = (const float2*)(xr + wb);
#pragma unroll
          for (int jj = 0; jj < 4; ++jj) {
            float2 v = p2[jj];
            xv[2*jj] = v.x; xv[2*jj+1] = v.y;
          }
        } else {
#pragma unroll
          for (int jj = 0; jj < 8; ++jj) {
            int ww = wb + jj;
            xv[jj] = ((unsigned)ww < 128u) ? xr[ww] : 0.f;
          }
        }
        const float4* wp = (const float4*)(wc + (kh * 3 + kw) * 32 + og * 8);
        float4 wa = wp[0], wbv = wp[1];
        float wr[8] = {wa.x, wa.y, wa.z, wa.w, wbv.x, wbv.y, wbv.z, wbv.w};
#pragma unroll
        for (int p = 0; p < 8; ++p)
#pragma unroll
          for (int o = 0; o < 8; ++o)
            acc[p][o] = fmaf(xv[p], wr[o], acc[p][o]);
      }
    }
  }

  int chbase = (br + 1) * 32 + og * 8;
  int n = h * 128 + w0;
#pragma unroll
  for (int o = 0; o < 8; ++o) {
    float bias = bf[og * 8 + o];
    float* op = out + ((size_t)(b * 128 + chbase + o)) * NPIX + n;
    float4 v0 = make_float4(fmaxf(acc[0][o] + bias, 0.f), fmaxf(acc[1][o] + bias, 0.f),
                            fmaxf(acc[2][o] + bias, 0.f), fmaxf(acc[3][o] + bias, 0.f));
    float4 v1 = make_float4(fmaxf(acc[4][o] + bias, 0.f), fmaxf(acc[5][o] + bias, 0.f),
                            fmaxf(acc[6][o] + bias, 0.f), fmaxf(acc[7][o] + bias, 0.f));
    ((float4*)op)[0] = v0;
    ((float4*)op)[1] = v1;
  }
}

// ---------------- cm v7: 1 tile/block, batch->XCD swizzle, swizzled-xt reads ----------------
__global__ __launch_bounds__(256) void cm_kernel(const unsigned short* __restrict__ xt,
                                                 const unsigned short* __restrict__ wvbr,
                                                 const unsigned short* __restrict__ wxbr,
                                                 const float* __restrict__ bv,
                                                 const float* __restrict__ bfp,
                                                 const float* __restrict__ bk,
                                                 float* __restrict__ out,
                                                 float* __restrict__ part1,
                                                 float* __restrict__ part2) {
  __shared__ __align__(16) unsigned short Vl[128 * 136];   // bf16 [oc][px]
  __shared__ __align__(16) unsigned short knl[16 * 136];   // bf16 [m][px]
  int t    = threadIdx.x;
  int idx  = blockIdx.x;
  int b    = idx & 7;           // batch -> XCD (1024 % 8 == 0, bijective)
  int blk  = idx >> 3;          // 0..127 == tile
  int wave = t >> 6, lane = t & 63;
  int l15  = lane & 15, cg = lane >> 4;
  int ocb  = wave * 32;
  int pbase = blk << 7;
  int cgsw = (cg ^ ((l15 >> 1) & 3)) << 3;   // swizzled-xt unit offset (ushorts)

  float bvr[2][4];
#pragma unroll
  for (int mf = 0; mf < 2; ++mf)
#pragma unroll
    for (int r = 0; r < 4; ++r) bvr[mf][r] = bv[ocb + mf * 16 + cg * 4 + r];

  float xb4[4];
#pragma unroll
  for (int r = 0; r < 4; ++r) xb4[r] = 0.f;
  if (wave == 0) {
#pragma unroll
    for (int r = 0; r < 4; ++r) xb4[r] = bfp[cg * 4 + r];
  } else if (wave == 1) {
#pragma unroll
    for (int r = 0; r < 4; ++r) xb4[r] = bfp[16 + cg * 4 + r];
  } else if (wave == 2) {
#pragma unroll
    for (int r = 0; r < 4; ++r) xb4[r] = bk[cg * 4 + r];
  }
  int xwave = (wave < 3) ? wave : 0;

  float kr[4] = {0.f, 0.f, 0.f, 0.f};
  float sv[2][4];
#pragma unroll
  for (int mf = 0; mf < 2; ++mf)
#pragma unroll
    for (int r = 0; r < 4; ++r) sv[mf][r] = 0.f;
  f32x4 am[2];
  am[0] = (f32x4){0.f,0.f,0.f,0.f};
  am[1] = (f32x4){0.f,0.f,0.f,0.f};

#pragma unroll
  for (int hf = 0; hf < 2; ++hf) {
    f32x4 vacc[2][4];
    f32x4 xacc[4];
#pragma unroll
    for (int i = 0; i < 2; ++i)
#pragma unroll
      for (int n = 0; n < 4; ++n) vacc[i][n] = (f32x4){0.f,0.f,0.f,0.f};
#pragma unroll
    for (int n = 0; n < 4; ++n) xacc[n] = (f32x4){0.f,0.f,0.f,0.f};

#pragma unroll
    for (int cc = 0; cc < 4; ++cc) {
      const unsigned short* xq = xt + ((size_t)(b * 4 + cc) * 16384 + pbase) * 32;
      bf16x8 a0 = *(const bf16x8*)(wvbr + ((cc * 8 + wave * 2 + 0) << 9) + lane * 8);
      bf16x8 a1 = *(const bf16x8*)(wvbr + ((cc * 8 + wave * 2 + 1) << 9) + lane * 8);
      bf16x8 ax = *(const bf16x8*)(wxbr + ((cc * 3 + xwave) << 9) + lane * 8);
#pragma unroll
      for (int nf = 0; nf < 4; ++nf) {
        int nfg = hf * 4 + nf;
        bf16x8 bx = *(const bf16x8*)(xq + (size_t)(nfg * 16 + l15) * 32 + cgsw);
        vacc[0][nf] = __builtin_amdgcn_mfma_f32_16x16x32_bf16(a0, bx, vacc[0][nf], 0, 0, 0);
        vacc[1][nf] = __builtin_amdgcn_mfma_f32_16x16x32_bf16(a1, bx, vacc[1][nf], 0, 0, 0);
        if (wave < 3)
          xacc[nf] = __builtin_amdgcn_mfma_f32_16x16x32_bf16(ax, bx, xacc[nf], 0, 0, 0);
      }
    }

#pragma unroll
    for (int mf = 0; mf < 2; ++mf) {
#pragma unroll
      for (int r = 0; r < 4; ++r) {
        float s = 0.f;
#pragma unroll
        for (int nf = 0; nf < 4; ++nf) s += vacc[mf][nf][r];
        sv[mf][r] += s;
        int c = ocb + mf * 16 + cg * 4 + r;
#pragma unroll
        for (int nf = 0; nf < 4; ++nf)
          Vl[c * 136 + (hf * 4 + nf) * 16 + l15] = f2bf(vacc[mf][nf][r] + bvr[mf][r]);
      }
    }

    if (wave < 2) {
#pragma unroll
      for (int r = 0; r < 4; ++r) {
        int oc = wave * 16 + cg * 4 + r;
        float* op = out + ((size_t)(b * 128 + oc)) * NPIX + pbase + l15;
#pragma unroll
        for (int nf = 0; nf < 4; ++nf)
          op[(hf * 4 + nf) * 16] = fmaxf(xacc[nf][r] + xb4[r], 0.f);
      }
    } else if (wave == 2) {
#pragma unroll
      for (int nf = 0; nf < 4; ++nf) {
        int nfg = hf * 4 + nf;
        float kq[4]; float s2 = 0.f;
#pragma unroll
        for (int r = 0; r < 4; ++r) {
          kq[r] = xacc[nf][r] + xb4[r];
          s2 = fmaf(kq[r], kq[r], s2);
        }
        s2 += __shfl_xor(s2, 16);
        s2 += __shfl_xor(s2, 32);
        float inv = rsqrtf(s2);
#pragma unroll
        for (int r = 0; r < 4; ++r) {
          float kn = kq[r] * inv;
          knl[(cg * 4 + r) * 136 + nfg * 16 + l15] = f2bf(kn);
          kr[r] += kn;
        }
      }
    }
  }
  __syncthreads();

#pragma unroll
  for (int ks = 0; ks < 4; ++ks) {
    bf16x8 af = *(const bf16x8*)(knl + l15 * 136 + ks * 32 + cg * 8);
    bf16x8 b0 = *(const bf16x8*)(Vl + (size_t)(ocb + l15) * 136 + ks * 32 + cg * 8);
    bf16x8 b1 = *(const bf16x8*)(Vl + (size_t)(ocb + 16 + l15) * 136 + ks * 32 + cg * 8);
    am[0] = __builtin_amdgcn_mfma_f32_16x16x32_bf16(af, b0, am[0], 0, 0, 0);
    am[1] = __builtin_amdgcn_mfma_f32_16x16x32_bf16(af, b1, am[1], 0, 0, 0);
  }

  float* pp = (blk < 64) ? (part1 + ((size_t)b * 64 + blk) * 2192)
                         : (part2 + ((size_t)b * 64 + (blk - 64)) * 2192);
#pragma unroll
  for (int nf2 = 0; nf2 < 2; ++nf2)
#pragma unroll
    for (int r = 0; r < 4; ++r)
      pp[(cg * 4 + r) * 128 + ocb + nf2 * 16 + l15] = am[nf2][r];
#pragma unroll
  for (int off = 1; off < 16; off <<= 1) {
#pragma unroll
    for (int mf = 0; mf < 2; ++mf)
#pragma unroll
      for (int r = 0; r < 4; ++r)
        sv[mf][r] += __shfl_xor(sv[mf][r], off);
  }
  if (l15 == 0) {
#pragma unroll
    for (int mf = 0; mf < 2; ++mf)
#pragma unroll
      for (int r = 0; r < 4; ++r) {
        int c = ocb + mf * 16 + cg * 4 + r;
        pp[2048 + c] = sv[mf][r] + 128.f * bv[c];
      }
  }
  if (wave == 2) {
#pragma unroll
    for (int off = 1; off < 16; off <<= 1) {
#pragma unroll
      for (int r = 0; r < 4; ++r)
        kr[r] += __shfl_xor(kr[r], off);
    }
    if (l15 == 0) {
#pragma unroll
      for (int r = 0; r < 4; ++r)
        pp[2048 + 128 + cg * 4 + r] = kr[r];
    }
  }
}

// ---------------- cf (fallback) ----------------
__global__ __launch_bounds__(256) void cf_kernel(const float* __restrict__ x,
                                                 const float* __restrict__ bv,
                                                 const float* __restrict__ Kbuf,
                                                 const float* __restrict__ wvt,
                                                 float* __restrict__ part) {
  __shared__ float Vl[128 * 129];
  __shared__ float knl[16 * 132];
  int t   = threadIdx.x;
  int b   = blockIdx.y;
  int blk = blockIdx.x;
  const float* Kb = Kbuf + (size_t)b * 16 * NPIX;
  const float* xb = x + (size_t)b * 128 * NPIX;

  int m_own = t & 15;
  int c0    = (t >> 4) << 3;
  int pxg   = t & 15;

  float bvr[8];
#pragma unroll
  for (int jj = 0; jj < 8; ++jj) bvr[jj] = bv[c0 + jj];

  float macc[8] = {0,0,0,0,0,0,0,0};
  float vs[8]   = {0,0,0,0,0,0,0,0};
  float ksum[16];
#pragma unroll
  for (int m = 0; m < 16; ++m) ksum[m] = 0.f;

  for (int tile = blk; tile < 128; tile += 64) {
    __syncthreads();
    int pbase = tile << 7;

    if (t < 128) {
      float kv[16]; float ss = 0.f;
#pragma unroll
      for (int m = 0; m < 16; ++m) {
        kv[m] = Kb[(size_t)m * NPIX + pbase + t];
        ss = fmaf(kv[m], kv[m], ss);
      }
      float inv = rsqrtf(ss);
#pragma unroll
      for (int m = 0; m < 16; ++m) {
        float kn = kv[m] * inv;
        knl[m * 132 + t] = kn;
        ksum[m] += kn;
      }
    }

    float v[8][8];
#pragma unroll
    for (int i = 0; i < 8; ++i)
#pragma unroll
      for (int jj = 0; jj < 8; ++jj) v[i][jj] = 0.f;
    int px0 = pbase + (pxg << 3);
    for (int k = 0; k < 128; ++k) {
      const float4* xp = (const float4*)(xb + (size_t)k * NPIX + px0);
      float4 xa = xp[0], xc4 = xp[1];
      const float4* wp = (const float4*)(wvt + k * 128 + c0);
      float4 wa = wp[0], wc4 = wp[1];
      float xv[8] = {xa.x, xa.y, xa.z, xa.w, xc4.x, xc4.y, xc4.z, xc4.w};
      float wr[8] = {wa.x, wa.y, wa.z, wa.w, wc4.x, wc4.y, wc4.z, wc4.w};
#pragma unroll
      for (int i = 0; i < 8; ++i)
#pragma unroll
        for (int jj = 0; jj < 8; ++jj)
          v[i][jj] = fmaf(wr[i], xv[jj], v[i][jj]);
    }
#pragma unroll
    for (int i = 0; i < 8; ++i)
#pragma unroll
      for (int jj = 0; jj < 8; ++jj)
        Vl[(c0 + i) * 129 + (pxg << 3) + jj] = v[i][jj] + bvr[i];
    __syncthreads();

    for (int px = 0; px < 128; ++px) {
      float knv = knl[m_own * 132 + px];
      float vv[8];
#pragma unroll
      for (int jj = 0; jj < 8; ++jj) vv[jj] = Vl[(c0 + jj) * 129 + px];
#pragma unroll
      for (int jj = 0; jj < 8; ++jj) macc[jj] = fmaf(knv, vv[jj], macc[jj]);
      if (m_own == 0) {
#pragma unroll
        for (int jj = 0; jj < 8; ++jj) vs[jj] += vv[jj];
      }
    }
  }

  int blkid = b * 64 + blk;
  float* pp = part + (size_t)blkid * 2192;
#pragma unroll
  for (int jj = 0; jj < 8; ++jj) pp[m_own * 128 + c0 + jj] = macc[jj];
  if (m_own == 0) {
#pragma unroll
    for (int jj = 0; jj < 8; ++jj) pp[2048 + c0 + jj] = vs[jj];
  }
  __syncthreads();
  if (t < 128) {
#pragma unroll
    for (int m = 0; m < 16; ++m) knl[m * 132 + t] = ksum[m];
  }
  __syncthreads();
  if (t < 16) {
    float s = 0.f;
    for (int i = 0; i < 128; ++i) s += knl[t * 132 + i];
    pp[2048 + 128 + t] = s;
  }
}

// ---------------- reduce (fallback: 64 groups) ----------------
__global__ void reduce_kernel(const float* __restrict__ part, float* __restrict__ stats) {
  int b = blockIdx.y, t = threadIdx.x;
  int e = blockIdx.x * 256 + t;
  if (e >= 2192) return;
  const float* pp = part + (size_t)b * 64 * 2192;
  float s = 0.f;
  for (int g = 0; g < 64; ++g) s += pp[(size_t)g * 2192 + e];
  stats[(size_t)b * 2192 + e] = s;
}

// ---------------- reduce2 (mfma: 64 + 64 groups) ----------------
__global__ void reduce2_kernel(const float* __restrict__ part1,
                               const float* __restrict__ part2,
                               float* __restrict__ stats) {
  int b = blockIdx.y, t = threadIdx.x;
  int e = blockIdx.x * 256 + t;
  if (e >= 2192) return;
  const float* p1 = part1 + (size_t)b * 64 * 2192;
  const float* p2 = part2 + (size_t)b * 64 * 2192;
  float s = 0.f;
  for (int g = 0; g < 64; ++g) s += p1[(size_t)g * 2192 + e];
  for (int g = 0; g < 64; ++g) s += p2[(size_t)g * 2192 + e];
  stats[(size_t)b * 2192 + e] = s;
}

// ---------------- df: fused Q + tailor + final output (1 px/thread) ----------------
__global__ __launch_bounds__(256) void df_kernel(const float* __restrict__ stats,
                                                 const float* __restrict__ wq,
                                                 const float* __restrict__ bq,
                                                 const float* __restrict__ gamma,
                                                 float* __restrict__ out) {
  __shared__ float matl[128 * 16];
  __shared__ float wql[128 * 16];
  __shared__ float vsl[128];
  __shared__ float ksl[16];
  int t = threadIdx.x;
  int b = blockIdx.y;
  const float* st = stats + (size_t)b * 2192;
  for (int i = t; i < 2048; i += 256) {
    int m = i >> 7, c = i & 127;
    matl[c * 16 + m] = st[i];
    wql[c * 16 + m]  = wq[m * 128 + c];
  }
  if (t < 128) vsl[t] = st[2048 + t];
  if (t < 16)  ksl[t] = st[2048 + 128 + t] + EPS_V;
  __syncthreads();

  int px = blockIdx.x * 256 + t;
  float* ob = out + (size_t)b * 128 * NPIX;

  float q[16];
#pragma unroll
  for (int m = 0; m < 16; ++m) q[m] = bq[m];
  for (int c = 0; c < 128; ++c) {
    float xv = ob[(size_t)c * NPIX + px];
    const float4* wp = (const float4*)(wql + c * 16);
#pragma unroll
    for (int jj = 0; jj < 4; ++jj) {
      float4 w = wp[jj];
      q[jj*4+0] = fmaf(w.x, xv, q[jj*4+0]);
      q[jj*4+1] = fmaf(w.y, xv, q[jj*4+1]);
      q[jj*4+2] = fmaf(w.z, xv, q[jj*4+2]);
      q[jj*4+3] = fmaf(w.w, xv, q[jj*4+3]);
    }
  }
  float ss = 0.f;
#pragma unroll
  for (int m = 0; m < 16; ++m) ss = fmaf(q[m], q[m], ss);
  float inv = rsqrtf(ss);
#pragma unroll
  for (int m = 0; m < 16; ++m) q[m] *= inv;
  float den = (float)NPIX;
#pragma unroll
  for (int m = 0; m < 16; ++m) den = fmaf(q[m], ksl[m], den);
  float tl = gamma[0] / den;

  for (int c = 0; c < 128; ++c) {
    float s = vsl[c];
    const float4* mp = (const float4*)(matl + c * 16);
#pragma unroll
    for (int jj = 0; jj < 4; ++jj) {
      float4 w = mp[jj];
      s = fmaf(w.x, q[jj*4+0], s);
      s = fmaf(w.y, q[jj*4+1], s);
      s = fmaf(w.z, q[jj*4+2], s);
      s = fmaf(w.w, q[jj*4+3], s);
    }
    ob[(size_t)c * NPIX + px] = tl * s;
  }
}

extern "C" void kernel_launch(void* const* d_in, const int* in_sizes, int n_in,
                              void* d_out, int out_size, void* d_ws, size_t ws_size,
                              hipStream_t stream) {
  (void)in_sizes; (void)n_in; (void)out_size;
  const float* x   = (const float*)d_in[0];
  const float* w1  = (const float*)d_in[1];
  const float* w2  = (const float*)d_in[2];
  const float* w3  = (const float*)d_in[3];
  const float* w4  = (const float*)d_in[4];
  const float* bns = (const float*)d_in[5];
  const float* bnb = (const float*)d_in[6];
  const float* bnm = (const float*)d_in[7];
  const float* bnv = (const float*)d_in[8];
  const float* wq  = (const float*)d_in[9];
  const float* bq  = (const float*)d_in[10];
  const float* wk  = (const float*)d_in[11];
  const float* bk  = (const float*)d_in[12];
  const float* wv  = (const float*)d_in[13];
  const float* bv  = (const float*)d_in[14];
  const float* gm  = (const float*)d_in[15];
  float* ws  = (float*)d_ws;
  float* out = (float*)d_out;

  float* Kbuf = ws + OFF_K;
  float* w1f  = ws + OFF_W1F;
  float* wkt  = ws + OFF_WKT;
  float* wvt  = ws + OFF_WVT;
  float* bfp  = ws + OFF_BF;
  float* part = ws + OFF_PART;
  float* stat = ws + OFF_STATS;

  bool use_mfma = ws_size >= NEW_END * sizeof(float);
  if (use_mfma) {
    unsigned short* wbtr = (unsigned short*)(ws + OFF_WBT);
    unsigned short* xt   = (unsigned short*)(ws + OFF_XT);
    unsigned short* wvbr = (unsigned short*)(ws + OFF_WVB);
    unsigned short* zrow = (unsigned short*)(ws + OFF_ZROW);
    unsigned short* wxbr = (unsigned short*)(ws + OFF_K);   // first 6144 floats of K region
    float* part2 = ws + OFF_PART2;                          // K region tail (dead in mfma path)
    prep_convb_kernel<<<64, 256, 0, stream>>>(w1, w2, w3, w4, bns, bnb, bnm, bnv, wk, wv,
                                              wbtr, wvbr, wxbr, zrow, bfp);
    a0_kernel<<<dim3(256, 8), 256, 0, stream>>>(x, xt);
    a2m_kernel<<<dim3(1536), 256, 0, stream>>>(xt, zrow, wbtr, bfp, out);
    cm_kernel<<<dim3(1024), 256, 0, stream>>>(xt, wvbr, wxbr, bv, bfp, bk, out, part, part2);
    reduce2_kernel<<<dim3(9, 8), 256, 0, stream>>>(part, part2, stat);
    df_kernel<<<dim3(64, 8), 256, 0, stream>>>(stat, wq, bq, gm, out);
  } else {
    float* w24t = ws + OFF_W24T;
    prep_common_kernel<<<64, 256, 0, stream>>>(w1, bns, bnb, bnm, bnv, wk, wv,
                                               w1f, wkt, wvt, bfp);
    prep_convf_kernel<<<64, 256, 0, stream>>>(w2, w3, w4, bns, bnv, w24t);
    a1_kernel<<<dim3(64, 8), 256, 0, stream>>>(x, w1f, wkt, bfp, bk, out, Kbuf);
    a2f_kernel<<<dim3(32, 8, 3), 256, 0, stream>>>(x, w24t, bfp, out);
    cf_kernel<<<dim3(64, 8), 256, 0, stream>>>(x, bv, Kbuf, wvt, part);
    reduce_kernel<<<dim3(9, 8), 256, 0, stream>>>(part, stat);
    df_kernel<<<dim3(64, 8), 256, 0, stream>>>(stat, wq, bq, gm, out);
  }
}